// Round 3
// baseline (516.700 us; speedup 1.0000x reference)
//
#include <hip/hip_runtime.h>
#include <hip/hip_bf16.h>
#include <cstddef>

#define Bb 8
#define Tt 512
#define NM 128
#define DM 512
#define DI 1024
#define DS 32
#define DR 32
#define DC 4
#define NC 100
#define BT (Bb*Tt)     // 4096
#define NCH 8          // scan chunks
#define CL  64         // chunk length
#define NLANE (Bb*DI*DS)  // 262144

__device__ __forceinline__ float softplus_f(float x) {
    return fmaxf(x, 0.f) + log1pf(expf(-fabsf(x)));
}
__device__ __forceinline__ float silu_fast(float x) {
    return __fdividef(x, 1.f + __expf(-x));
}

// ---------------- generic 64x64 tiled fp32 GEMM: C = epi(A@B) -----------------
// EPI: 0 none, 1 +bias[n], 2 softplus(+bias[n]), 3 +add[m*N+n]
// TSTORE: 0 -> C[m*N+n]; 1 -> C[((m/Tt)*N + n)*Tt + m%Tt]
template<int EPI, int TSTORE>
__global__ __launch_bounds__(256) void gemm64(
    const float* __restrict__ A, int lda,
    const float* __restrict__ B,
    const float* __restrict__ bias,
    const float* __restrict__ add,
    float* __restrict__ C,
    int M, int N, int K)
{
    __shared__ float As[16][68];
    __shared__ float Bs[16][64];
    const int tid = threadIdx.x;
    const int bm = blockIdx.y * 64;
    const int bn = blockIdx.x * 64;
    const int tx = tid & 15;
    const int ty = tid >> 4;
    const int la_m = tid >> 2;
    const int la_k = (tid & 3) << 2;
    const int lb_k = tid >> 4;
    const int lb_n = (tid & 15) << 2;

    float acc[4][4] = {};
    for (int k0 = 0; k0 < K; k0 += 16) {
        float4 av = *(const float4*)(A + (size_t)(bm + la_m) * lda + k0 + la_k);
        As[la_k + 0][la_m] = av.x;
        As[la_k + 1][la_m] = av.y;
        As[la_k + 2][la_m] = av.z;
        As[la_k + 3][la_m] = av.w;
        const int gn = bn + lb_n;
        const float* bp = B + (size_t)(k0 + lb_k) * N + gn;
        float4 bv;
        if (gn + 3 < N) {
            bv = *(const float4*)bp;
        } else {
            bv.x = (gn + 0 < N) ? bp[0] : 0.f;
            bv.y = (gn + 1 < N) ? bp[1] : 0.f;
            bv.z = (gn + 2 < N) ? bp[2] : 0.f;
            bv.w = (gn + 3 < N) ? bp[3] : 0.f;
        }
        *(float4*)&Bs[lb_k][lb_n] = bv;
        __syncthreads();
        #pragma unroll
        for (int k = 0; k < 16; ++k) {
            float4 a = *(const float4*)&As[k][ty << 2];
            float4 b = *(const float4*)&Bs[k][tx << 2];
            float ar[4] = {a.x, a.y, a.z, a.w};
            float br[4] = {b.x, b.y, b.z, b.w};
            #pragma unroll
            for (int i = 0; i < 4; ++i)
                #pragma unroll
                for (int j = 0; j < 4; ++j)
                    acc[i][j] = fmaf(ar[i], br[j], acc[i][j]);
        }
        __syncthreads();
    }
    if (TSTORE == 0) {
        #pragma unroll
        for (int i = 0; i < 4; ++i) {
            const int gm = bm + (ty << 2) + i;
            #pragma unroll
            for (int j = 0; j < 4; ++j) {
                const int gn = bn + (tx << 2) + j;
                if (gn < N) {
                    float v = acc[i][j];
                    if (EPI == 1) v += bias[gn];
                    else if (EPI == 2) v = softplus_f(v + bias[gn]);
                    else if (EPI == 3) v += add[(size_t)gm * N + gn];
                    C[(size_t)gm * N + gn] = v;
                }
            }
        }
    } else {
        const int bq = bm >> 9;
        const int tt0 = (bm & (Tt - 1)) + (ty << 2);
        #pragma unroll
        for (int j = 0; j < 4; ++j) {
            const int gn = bn + (tx << 2) + j;
            if (gn < N) {
                float4 v;
                float* vv = (float*)&v;
                #pragma unroll
                for (int i = 0; i < 4; ++i) {
                    float t = acc[i][j];
                    if (EPI == 2) t = softplus_f(t + bias[gn]);
                    vv[i] = t;
                }
                *(float4*)(C + ((size_t)bq * N + gn) * Tt + tt0) = v;
            }
        }
    }
}

// ---------------- 128x128x16 fp32 GEMM (no epilogue), dims must divide --------
__global__ __launch_bounds__(256) void gemm128(
    const float* __restrict__ A, int lda,
    const float* __restrict__ B,
    float* __restrict__ C,
    int N, int K)
{
    __shared__ float As[16][132];   // [k][m]
    __shared__ float Bs[16][128];   // [k][n]
    const int tid = threadIdx.x;
    const int bm = blockIdx.y * 128;
    const int bn = blockIdx.x * 128;
    const int tx = tid & 15;          // n octet
    const int ty = tid >> 4;          // m octet
    const int la_m = tid >> 1;        // 0..127
    const int la_k = (tid & 1) << 3;  // 0 or 8
    const int lb_k = tid >> 4;        // 0..15
    const int lb_n = (tid & 15) << 3; // 0..120

    float acc[8][8] = {};
    for (int k0 = 0; k0 < K; k0 += 16) {
        const float* ap = A + (size_t)(bm + la_m) * lda + k0 + la_k;
        float4 a0 = *(const float4*)ap;
        float4 a1 = *(const float4*)(ap + 4);
        As[la_k + 0][la_m] = a0.x;
        As[la_k + 1][la_m] = a0.y;
        As[la_k + 2][la_m] = a0.z;
        As[la_k + 3][la_m] = a0.w;
        As[la_k + 4][la_m] = a1.x;
        As[la_k + 5][la_m] = a1.y;
        As[la_k + 6][la_m] = a1.z;
        As[la_k + 7][la_m] = a1.w;
        const float* bp = B + (size_t)(k0 + lb_k) * N + bn + lb_n;
        *(float4*)&Bs[lb_k][lb_n]     = *(const float4*)bp;
        *(float4*)&Bs[lb_k][lb_n + 4] = *(const float4*)(bp + 4);
        __syncthreads();
        #pragma unroll
        for (int k = 0; k < 16; ++k) {
            float ar[8], br[8];
            *(float4*)&ar[0] = *(const float4*)&As[k][ty << 3];
            *(float4*)&ar[4] = *(const float4*)&As[k][(ty << 3) + 4];
            *(float4*)&br[0] = *(const float4*)&Bs[k][tx << 3];
            *(float4*)&br[4] = *(const float4*)&Bs[k][(tx << 3) + 4];
            #pragma unroll
            for (int i = 0; i < 8; ++i)
                #pragma unroll
                for (int j = 0; j < 8; ++j)
                    acc[i][j] = fmaf(ar[i], br[j], acc[i][j]);
        }
        __syncthreads();
    }
    #pragma unroll
    for (int i = 0; i < 8; ++i) {
        float* cp = C + (size_t)(bm + (ty << 3) + i) * N + bn + (tx << 3);
        *(float4*)cp       = *(float4*)&acc[i][0];
        *(float4*)(cp + 4) = *(float4*)&acc[i][4];
    }
}

// --------- GEMM with per-batch-transposed A: A_T layout (b, K, Tt) ------------
template<int EPI>
__global__ __launch_bounds__(256) void gemm_at(
    const float* __restrict__ A_T,
    const float* __restrict__ B,
    const float* __restrict__ add,
    float* __restrict__ C,
    int M, int N, int K)
{
    __shared__ float As[16][68];
    __shared__ float Bs[16][64];
    const int tid = threadIdx.x;
    const int bm = blockIdx.y * 64;
    const int bn = blockIdx.x * 64;
    const int tx = tid & 15;
    const int ty = tid >> 4;
    const int lb_k = tid >> 4;
    const int lb_n = (tid & 15) << 2;
    const int bq = bm >> 9;
    const int tt0 = bm & (Tt - 1);

    float acc[4][4] = {};
    for (int k0 = 0; k0 < K; k0 += 16) {
        float4 av = *(const float4*)(A_T + ((size_t)bq * K + k0 + lb_k) * Tt + tt0 + lb_n);
        *(float4*)&As[lb_k][lb_n] = av;
        const int gn = bn + lb_n;
        const float* bp = B + (size_t)(k0 + lb_k) * N + gn;
        float4 bv;
        if (gn + 3 < N) {
            bv = *(const float4*)bp;
        } else {
            bv.x = (gn + 0 < N) ? bp[0] : 0.f;
            bv.y = (gn + 1 < N) ? bp[1] : 0.f;
            bv.z = (gn + 2 < N) ? bp[2] : 0.f;
            bv.w = (gn + 3 < N) ? bp[3] : 0.f;
        }
        *(float4*)&Bs[lb_k][lb_n] = bv;
        __syncthreads();
        #pragma unroll
        for (int k = 0; k < 16; ++k) {
            float4 a = *(const float4*)&As[k][ty << 2];
            float4 b = *(const float4*)&Bs[k][tx << 2];
            float ar[4] = {a.x, a.y, a.z, a.w};
            float br[4] = {b.x, b.y, b.z, b.w};
            #pragma unroll
            for (int i = 0; i < 4; ++i)
                #pragma unroll
                for (int j = 0; j < 4; ++j)
                    acc[i][j] = fmaf(ar[i], br[j], acc[i][j]);
        }
        __syncthreads();
    }
    #pragma unroll
    for (int i = 0; i < 4; ++i) {
        const int gm = bm + (ty << 2) + i;
        #pragma unroll
        for (int j = 0; j < 4; ++j) {
            const int gn = bn + (tx << 2) + j;
            if (gn < N) {
                float v = acc[i][j];
                if (EPI == 3) v += add[(size_t)gm * N + gn];
                C[(size_t)gm * N + gn] = v;
            }
        }
    }
}

// ---------------- RMSNorm over DM=512, one block per row ----------------------
__global__ __launch_bounds__(256) void rms_kernel(
    const float* __restrict__ h0, const float* __restrict__ w, float* __restrict__ xn)
{
    const int row = blockIdx.x;
    const float* p = h0 + (size_t)row * DM;
    const int tid = threadIdx.x;
    float v0 = p[tid], v1 = p[tid + 256];
    float ss = v0 * v0 + v1 * v1;
    #pragma unroll
    for (int m = 32; m; m >>= 1) ss += __shfl_xor(ss, m);
    __shared__ float wsum[4];
    if ((tid & 63) == 0) wsum[tid >> 6] = ss;
    __syncthreads();
    const float tot = wsum[0] + wsum[1] + wsum[2] + wsum[3];
    const float scale = rsqrtf(tot * (1.0f / DM) + 1e-5f);
    xn[(size_t)row * DM + tid]       = v0 * scale * w[tid];
    xn[(size_t)row * DM + tid + 256] = v1 * scale * w[tid + 256];
}

// -------- causal depthwise conv (DC=4) + SiLU, outputs TRANSPOSED (b,di,t) ----
__global__ __launch_bounds__(256) void conv_tr_kernel(
    const float* __restrict__ xr, const float* __restrict__ cw,
    const float* __restrict__ cb, float* __restrict__ xpT, float* __restrict__ resT)
{
    __shared__ float tp[64][65];
    __shared__ float tr[64][65];
    const int di0 = blockIdx.x * 64;
    const int t0  = blockIdx.y * 64;
    const int b   = blockIdx.z;
    const int c  = threadIdx.x & 63;
    const int r4 = threadIdx.x >> 6;
    const int di = di0 + c;
    const float bias = cb[di];
    float w0 = cw[di * DC + 0], w1 = cw[di * DC + 1],
          w2 = cw[di * DC + 2], w3 = cw[di * DC + 3];
    #pragma unroll
    for (int rr = 0; rr < 64; rr += 4) {
        const int t = t0 + rr + r4;
        const int bt = b * Tt + t;
        float acc = bias;
        if (t >= 3) {
            acc = fmaf(w0, xr[(size_t)(bt - 3) * (2 * DI) + di], acc);
            acc = fmaf(w1, xr[(size_t)(bt - 2) * (2 * DI) + di], acc);
            acc = fmaf(w2, xr[(size_t)(bt - 1) * (2 * DI) + di], acc);
        } else {
            if (t >= 1) acc = fmaf(w2, xr[(size_t)(bt - 1) * (2 * DI) + di], acc);
            if (t >= 2) acc = fmaf(w1, xr[(size_t)(bt - 2) * (2 * DI) + di], acc);
        }
        acc = fmaf(w3, xr[(size_t)bt * (2 * DI) + di], acc);
        tp[rr + r4][c] = silu_fast(acc);
        tr[rr + r4][c] = xr[(size_t)bt * (2 * DI) + DI + di];
    }
    __syncthreads();
    #pragma unroll
    for (int dd = 0; dd < 64; dd += 4) {
        const int dw = dd + r4;
        const size_t o = ((size_t)b * DI + di0 + dw) * Tt + t0 + c;
        xpT[o]  = tp[c][dw];
        resT[o] = tr[c][dw];
    }
}

// ============= chunked selective scan ==========================================
// Pass A: per chunk, from h=0: local h_end and decay product P = exp(Ads*sum dt)
__global__ __launch_bounds__(256) void scan_passA(
    const float* __restrict__ deltaT, const float* __restrict__ xdbl,
    const float* __restrict__ xpT, const float* __restrict__ A_log,
    float* __restrict__ hE, float* __restrict__ Pp)
{
    const int g = threadIdx.x >> 5;
    const int s = threadIdx.x & 31;
    const int c = blockIdx.x & (NCH - 1);
    const int cg = blockIdx.x >> 3;          // 0..1023
    const int b = cg >> 7;
    const int di = ((cg & 127) << 3) + g;
    const int ch = b * DI + di;
    const float Ads = -expf(A_log[di * DS + s]);
    const float* dp = deltaT + (size_t)ch * Tt + c * CL;
    const float* up = xpT + (size_t)ch * Tt + c * CL;
    const float* xd = xdbl + ((size_t)b * Tt + c * CL) * 96;
    float h = 0.f, dts = 0.f;
    #pragma unroll
    for (int tq = 0; tq < CL / 4; ++tq) {
        float4 d4 = *(const float4*)(dp + tq * 4);
        float4 u4 = *(const float4*)(up + tq * 4);
        float dv[4] = {d4.x, d4.y, d4.z, d4.w};
        float uv[4] = {u4.x, u4.y, u4.z, u4.w};
        #pragma unroll
        for (int q = 0; q < 4; ++q) {
            const int t = tq * 4 + q;
            const float Btv = xd[t * 96 + DR + s];
            const float a = __expf(dv[q] * Ads);
            h = fmaf(a, h, dv[q] * uv[q] * Btv);
            dts += dv[q];
        }
    }
    const int lane = ch * DS + s;
    hE[(size_t)c * NLANE + lane] = h;
    Pp[(size_t)c * NLANE + lane] = __expf(Ads * dts);
}

// Pass B: carry propagation; hE[c][lane] is overwritten with h_start(c)
__global__ __launch_bounds__(256) void scan_passB(
    float* __restrict__ hE, const float* __restrict__ Pp)
{
    const int lane = blockIdx.x * 256 + threadIdx.x;
    float h = 0.f;
    #pragma unroll
    for (int c = 0; c < NCH; ++c) {
        const float he = hE[(size_t)c * NLANE + lane];
        const float p  = Pp[(size_t)c * NLANE + lane];
        hE[(size_t)c * NLANE + lane] = h;
        h = fmaf(p, h, he);
    }
}

// Pass C: recompute with correct h_start; y reduction + D-skip + silu gate
__global__ __launch_bounds__(256) void scan_passC(
    const float* __restrict__ deltaT, const float* __restrict__ xdbl,
    const float* __restrict__ xpT, const float* __restrict__ resT,
    const float* __restrict__ A_log, const float* __restrict__ Dvec,
    const float* __restrict__ hE, float* __restrict__ yT)
{
    const int g = threadIdx.x >> 5;
    const int s = threadIdx.x & 31;
    const int c = blockIdx.x & (NCH - 1);
    const int cg = blockIdx.x >> 3;
    const int b = cg >> 7;
    const int di = ((cg & 127) << 3) + g;
    const int ch = b * DI + di;
    const float Ads = -expf(A_log[di * DS + s]);
    const float Dv = Dvec[di];
    const float* dp = deltaT + (size_t)ch * Tt + c * CL;
    const float* up = xpT + (size_t)ch * Tt + c * CL;
    const float* rp = resT + (size_t)ch * Tt + c * CL;
    const float* xd = xdbl + ((size_t)b * Tt + c * CL) * 96;
    float* yp = yT + (size_t)ch * Tt + c * CL;
    float h = hE[(size_t)c * NLANE + ch * DS + s];
    for (int t0 = 0; t0 < CL; t0 += 32) {
        float yreg = 0.f;
        #pragma unroll
        for (int tq = 0; tq < 8; ++tq) {
            const int tb = t0 + tq * 4;
            float4 d4 = *(const float4*)(dp + tb);
            float4 u4 = *(const float4*)(up + tb);
            float dv[4] = {d4.x, d4.y, d4.z, d4.w};
            float uv[4] = {u4.x, u4.y, u4.z, u4.w};
            #pragma unroll
            for (int q = 0; q < 4; ++q) {
                const int tloc = tq * 4 + q;
                const float dt = dv[q];
                const float u  = uv[q];
                const float Btv = xd[(tb + q) * 96 + DR + s];
                const float Ctv = xd[(tb + q) * 96 + DR + DS + s];
                const float dA = __expf(dt * Ads);
                h = fmaf(dA, h, dt * u * Btv);
                float ps = h * Ctv;
                ps += __shfl_xor(ps, 16);
                ps += __shfl_xor(ps, 8);
                ps += __shfl_xor(ps, 4);
                ps += __shfl_xor(ps, 2);
                ps += __shfl_xor(ps, 1);
                const float yv = fmaf(u, Dv, ps);
                if (tloc == s) yreg = yv;
            }
        }
        yp[t0 + s] = yreg * silu_fast(rp[t0 + s]);
    }
}

// ---------------- mean-pool over DM, one wave per row -------------------------
__global__ __launch_bounds__(256) void pool_kernel(
    const float* __restrict__ enc, float* __restrict__ pooled)
{
    const int row = blockIdx.x * 4 + (threadIdx.x >> 6);
    const int lane = threadIdx.x & 63;
    const float* p = enc + (size_t)row * DM;
    float sacc = 0.f;
    #pragma unroll
    for (int i = 0; i < DM / 64; ++i) sacc += p[lane + 64 * i];
    #pragma unroll
    for (int m = 32; m; m >>= 1) sacc += __shfl_xor(sacc, m);
    if (lane == 0) pooled[row] = sacc * (1.0f / DM);
}

// ---------------- classifier ---------------------------------------------------
__global__ __launch_bounds__(256) void cls_kernel(
    const float* __restrict__ pooled, const float* __restrict__ w_cls,
    const float* __restrict__ b_cls, float* __restrict__ out)
{
    const int idx = blockIdx.x * 256 + threadIdx.x;
    if (idx >= Bb * NC) return;
    const int b = idx / NC, c = idx % NC;
    float acc = b_cls[c];
    for (int t = 0; t < DM; ++t)
        acc = fmaf(pooled[b * DM + t], w_cls[t * NC + c], acc);
    out[idx] = acc;
}

extern "C" void kernel_launch(void* const* d_in, const int* in_sizes, int n_in,
                              void* d_out, int out_size, void* d_ws, size_t ws_size,
                              hipStream_t stream) {
    const float* x      = (const float*)d_in[0];
    const float* w_proj = (const float*)d_in[1];
    const float* b_proj = (const float*)d_in[2];
    const float* rms_w  = (const float*)d_in[3];
    const float* w_in   = (const float*)d_in[4];
    const float* conv_w = (const float*)d_in[5];
    const float* conv_b = (const float*)d_in[6];
    const float* w_xprj = (const float*)d_in[7];
    const float* w_dt   = (const float*)d_in[8];
    const float* b_dt   = (const float*)d_in[9];
    const float* A_log  = (const float*)d_in[10];
    const float* Dvec   = (const float*)d_in[11];
    const float* w_out  = (const float*)d_in[12];
    const float* w_cls  = (const float*)d_in[13];
    const float* b_cls  = (const float*)d_in[14];
    float* out = (float*)d_out;

    float* ws = (float*)d_ws;
    float* h0     = ws;
    float* xn     = h0 + (size_t)BT * DM;
    float* xr     = xn + (size_t)BT * DM;
    float* xpT    = xr + (size_t)BT * 2 * DI;
    float* resT   = xpT + (size_t)Bb * DI * Tt;
    float* xdbl   = resT + (size_t)Bb * DI * Tt;
    float* pooled = xdbl + (size_t)BT * 96;
    float* hE     = pooled + 4096;
    float* Pp     = hE + (size_t)NCH * NLANE;
    float* deltaT = xr;                           // alias: xr dead after conv_tr
    float* yT     = xr + (size_t)Bb * DI * Tt;    // alias: upper half of xr
    float* enc    = xn;                           // alias: xn dead after gemm3

    // 1) h0 = x @ w_proj + b_proj
    gemm64<1,0><<<dim3(DM / 64, BT / 64), 256, 0, stream>>>(
        x, NM, w_proj, b_proj, nullptr, h0, BT, DM, NM);
    // 2) xn = rmsnorm(h0) * rms_w
    rms_kernel<<<BT, 256, 0, stream>>>(h0, rms_w, xn);
    // 3) xr = xn @ w_in    (128x128 tile)
    gemm128<<<dim3(2 * DI / 128, BT / 128), 256, 0, stream>>>(
        xn, DM, w_in, xr, 2 * DI, DM);
    // 4) xpT = silu(causal_dwconv(xr[:, :DI]))^T ; resT = xr[:, DI:]^T
    conv_tr_kernel<<<dim3(DI / 64, Tt / 64, Bb), 256, 0, stream>>>(
        xr, conv_w, conv_b, xpT, resT);
    // 5) xdbl = xp @ w_xproj   (A read transposed)
    gemm_at<0><<<dim3((96 + 63) / 64, BT / 64), 256, 0, stream>>>(
        xpT, w_xprj, nullptr, xdbl, BT, 96, DI);
    // 6) deltaT = softplus(dt @ w_dt + b_dt)^T
    gemm64<2,1><<<dim3(DI / 64, BT / 64), 256, 0, stream>>>(
        xdbl, 96, w_dt, b_dt, nullptr, deltaT, BT, DI, DR);
    // 7) chunked selective scan
    scan_passA<<<Bb * (DI / 8) * NCH, 256, 0, stream>>>(
        deltaT, xdbl, xpT, A_log, hE, Pp);
    scan_passB<<<NLANE / 256, 256, 0, stream>>>(hE, Pp);
    scan_passC<<<Bb * (DI / 8) * NCH, 256, 0, stream>>>(
        deltaT, xdbl, xpT, resT, A_log, Dvec, hE, yT);
    // 8) enc = h0 + y @ w_out  (A read transposed)
    gemm_at<3><<<dim3(DM / 64, BT / 64), 256, 0, stream>>>(
        yT, w_out, h0, enc, BT, DM, DI);
    // 9) pooled = mean(enc, axis=-1)
    pool_kernel<<<BT / 4, 256, 0, stream>>>(enc, pooled);
    // 10) out = pooled @ w_cls + b_cls
    cls_kernel<<<(Bb * NC + 255) / 256, 256, 0, stream>>>(pooled, w_cls, b_cls, out);
}

// Round 4
// 500.856 us; speedup vs baseline: 1.0316x; 1.0316x over previous
//
#include <hip/hip_runtime.h>
#include <hip/hip_bf16.h>
#include <cstddef>

#define Bb 8
#define Tt 512
#define NM 128
#define DM 512
#define DI 1024
#define DS 32
#define DR 32
#define DC 4
#define NC 100
#define BT (Bb*Tt)     // 4096
#define NCH 8          // scan chunks
#define CL  64         // chunk length
#define NLANE (Bb*DI*DS)  // 262144

__device__ __forceinline__ float softplus_f(float x) {
    return fmaxf(x, 0.f) + log1pf(expf(-fabsf(x)));
}
__device__ __forceinline__ float silu_fast(float x) {
    return __fdividef(x, 1.f + __expf(-x));
}

// ---------------- generic 64x64 tiled fp32 GEMM: C = epi(A@B) -----------------
// EPI: 0 none, 1 +bias[n], 2 softplus(+bias[n]), 3 +add[m*N+n]
// TSTORE: 0 -> C[m*N+n]; 1 -> C[((m/Tt)*N + n)*Tt + m%Tt]
template<int EPI, int TSTORE>
__global__ __launch_bounds__(256) void gemm64(
    const float* __restrict__ A, int lda,
    const float* __restrict__ B,
    const float* __restrict__ bias,
    const float* __restrict__ add,
    float* __restrict__ C,
    int M, int N, int K)
{
    __shared__ float As[16][68];
    __shared__ float Bs[16][64];
    const int tid = threadIdx.x;
    const int bm = blockIdx.y * 64;
    const int bn = blockIdx.x * 64;
    const int tx = tid & 15;
    const int ty = tid >> 4;
    const int la_m = tid >> 2;
    const int la_k = (tid & 3) << 2;
    const int lb_k = tid >> 4;
    const int lb_n = (tid & 15) << 2;

    float acc[4][4] = {};
    for (int k0 = 0; k0 < K; k0 += 16) {
        float4 av = *(const float4*)(A + (size_t)(bm + la_m) * lda + k0 + la_k);
        As[la_k + 0][la_m] = av.x;
        As[la_k + 1][la_m] = av.y;
        As[la_k + 2][la_m] = av.z;
        As[la_k + 3][la_m] = av.w;
        const int gn = bn + lb_n;
        const float* bp = B + (size_t)(k0 + lb_k) * N + gn;
        float4 bv;
        if (gn + 3 < N) {
            bv = *(const float4*)bp;
        } else {
            bv.x = (gn + 0 < N) ? bp[0] : 0.f;
            bv.y = (gn + 1 < N) ? bp[1] : 0.f;
            bv.z = (gn + 2 < N) ? bp[2] : 0.f;
            bv.w = (gn + 3 < N) ? bp[3] : 0.f;
        }
        *(float4*)&Bs[lb_k][lb_n] = bv;
        __syncthreads();
        #pragma unroll
        for (int k = 0; k < 16; ++k) {
            float4 a = *(const float4*)&As[k][ty << 2];
            float4 b = *(const float4*)&Bs[k][tx << 2];
            float ar[4] = {a.x, a.y, a.z, a.w};
            float br[4] = {b.x, b.y, b.z, b.w};
            #pragma unroll
            for (int i = 0; i < 4; ++i)
                #pragma unroll
                for (int j = 0; j < 4; ++j)
                    acc[i][j] = fmaf(ar[i], br[j], acc[i][j]);
        }
        __syncthreads();
    }
    if (TSTORE == 0) {
        #pragma unroll
        for (int i = 0; i < 4; ++i) {
            const int gm = bm + (ty << 2) + i;
            #pragma unroll
            for (int j = 0; j < 4; ++j) {
                const int gn = bn + (tx << 2) + j;
                if (gn < N) {
                    float v = acc[i][j];
                    if (EPI == 1) v += bias[gn];
                    else if (EPI == 2) v = softplus_f(v + bias[gn]);
                    else if (EPI == 3) v += add[(size_t)gm * N + gn];
                    C[(size_t)gm * N + gn] = v;
                }
            }
        }
    } else {
        const int bq = bm >> 9;
        const int tt0 = (bm & (Tt - 1)) + (ty << 2);
        #pragma unroll
        for (int j = 0; j < 4; ++j) {
            const int gn = bn + (tx << 2) + j;
            if (gn < N) {
                float4 v;
                float* vv = (float*)&v;
                #pragma unroll
                for (int i = 0; i < 4; ++i) {
                    float t = acc[i][j];
                    if (EPI == 2) t = softplus_f(t + bias[gn]);
                    vv[i] = t;
                }
                *(float4*)(C + ((size_t)bq * N + gn) * Tt + tt0) = v;
            }
        }
    }
}

// ---------------- 128x128x16 fp32 GEMM (no epilogue), dims must divide --------
__global__ __launch_bounds__(256) void gemm128(
    const float* __restrict__ A, int lda,
    const float* __restrict__ B,
    float* __restrict__ C,
    int N, int K)
{
    __shared__ float As[16][132];   // [k][m]
    __shared__ float Bs[16][128];   // [k][n]
    const int tid = threadIdx.x;
    const int bm = blockIdx.y * 128;
    const int bn = blockIdx.x * 128;
    const int tx = tid & 15;          // n octet
    const int ty = tid >> 4;          // m octet
    const int la_m = tid >> 1;        // 0..127
    const int la_k = (tid & 1) << 3;  // 0 or 8
    const int lb_k = tid >> 4;        // 0..15
    const int lb_n = (tid & 15) << 3; // 0..120

    float acc[8][8] = {};
    for (int k0 = 0; k0 < K; k0 += 16) {
        const float* ap = A + (size_t)(bm + la_m) * lda + k0 + la_k;
        float4 a0 = *(const float4*)ap;
        float4 a1 = *(const float4*)(ap + 4);
        As[la_k + 0][la_m] = a0.x;
        As[la_k + 1][la_m] = a0.y;
        As[la_k + 2][la_m] = a0.z;
        As[la_k + 3][la_m] = a0.w;
        As[la_k + 4][la_m] = a1.x;
        As[la_k + 5][la_m] = a1.y;
        As[la_k + 6][la_m] = a1.z;
        As[la_k + 7][la_m] = a1.w;
        const float* bp = B + (size_t)(k0 + lb_k) * N + bn + lb_n;
        *(float4*)&Bs[lb_k][lb_n]     = *(const float4*)bp;
        *(float4*)&Bs[lb_k][lb_n + 4] = *(const float4*)(bp + 4);
        __syncthreads();
        #pragma unroll
        for (int k = 0; k < 16; ++k) {
            float ar[8], br[8];
            *(float4*)&ar[0] = *(const float4*)&As[k][ty << 3];
            *(float4*)&ar[4] = *(const float4*)&As[k][(ty << 3) + 4];
            *(float4*)&br[0] = *(const float4*)&Bs[k][tx << 3];
            *(float4*)&br[4] = *(const float4*)&Bs[k][(tx << 3) + 4];
            #pragma unroll
            for (int i = 0; i < 8; ++i)
                #pragma unroll
                for (int j = 0; j < 8; ++j)
                    acc[i][j] = fmaf(ar[i], br[j], acc[i][j]);
        }
        __syncthreads();
    }
    #pragma unroll
    for (int i = 0; i < 8; ++i) {
        float* cp = C + (size_t)(bm + (ty << 3) + i) * N + bn + (tx << 3);
        *(float4*)cp       = *(float4*)&acc[i][0];
        *(float4*)(cp + 4) = *(float4*)&acc[i][4];
    }
}

// --------- GEMM with per-batch-transposed A: A_T layout (b, K, Tt) ------------
template<int EPI>
__global__ __launch_bounds__(256) void gemm_at(
    const float* __restrict__ A_T,
    const float* __restrict__ B,
    const float* __restrict__ add,
    float* __restrict__ C,
    int M, int N, int K)
{
    __shared__ float As[16][68];
    __shared__ float Bs[16][64];
    const int tid = threadIdx.x;
    const int bm = blockIdx.y * 64;
    const int bn = blockIdx.x * 64;
    const int tx = tid & 15;
    const int ty = tid >> 4;
    const int lb_k = tid >> 4;
    const int lb_n = (tid & 15) << 2;
    const int bq = bm >> 9;
    const int tt0 = bm & (Tt - 1);

    float acc[4][4] = {};
    for (int k0 = 0; k0 < K; k0 += 16) {
        float4 av = *(const float4*)(A_T + ((size_t)bq * K + k0 + lb_k) * Tt + tt0 + lb_n);
        *(float4*)&As[lb_k][lb_n] = av;
        const int gn = bn + lb_n;
        const float* bp = B + (size_t)(k0 + lb_k) * N + gn;
        float4 bv;
        if (gn + 3 < N) {
            bv = *(const float4*)bp;
        } else {
            bv.x = (gn + 0 < N) ? bp[0] : 0.f;
            bv.y = (gn + 1 < N) ? bp[1] : 0.f;
            bv.z = (gn + 2 < N) ? bp[2] : 0.f;
            bv.w = (gn + 3 < N) ? bp[3] : 0.f;
        }
        *(float4*)&Bs[lb_k][lb_n] = bv;
        __syncthreads();
        #pragma unroll
        for (int k = 0; k < 16; ++k) {
            float4 a = *(const float4*)&As[k][ty << 2];
            float4 b = *(const float4*)&Bs[k][tx << 2];
            float ar[4] = {a.x, a.y, a.z, a.w};
            float br[4] = {b.x, b.y, b.z, b.w};
            #pragma unroll
            for (int i = 0; i < 4; ++i)
                #pragma unroll
                for (int j = 0; j < 4; ++j)
                    acc[i][j] = fmaf(ar[i], br[j], acc[i][j]);
        }
        __syncthreads();
    }
    #pragma unroll
    for (int i = 0; i < 4; ++i) {
        const int gm = bm + (ty << 2) + i;
        #pragma unroll
        for (int j = 0; j < 4; ++j) {
            const int gn = bn + (tx << 2) + j;
            if (gn < N) {
                float v = acc[i][j];
                if (EPI == 3) v += add[(size_t)gm * N + gn];
                C[(size_t)gm * N + gn] = v;
            }
        }
    }
}

// ---------------- RMSNorm over DM=512, one block per row ----------------------
__global__ __launch_bounds__(256) void rms_kernel(
    const float* __restrict__ h0, const float* __restrict__ w, float* __restrict__ xn)
{
    const int row = blockIdx.x;
    const float* p = h0 + (size_t)row * DM;
    const int tid = threadIdx.x;
    float v0 = p[tid], v1 = p[tid + 256];
    float ss = v0 * v0 + v1 * v1;
    #pragma unroll
    for (int m = 32; m; m >>= 1) ss += __shfl_xor(ss, m);
    __shared__ float wsum[4];
    if ((tid & 63) == 0) wsum[tid >> 6] = ss;
    __syncthreads();
    const float tot = wsum[0] + wsum[1] + wsum[2] + wsum[3];
    const float scale = rsqrtf(tot * (1.0f / DM) + 1e-5f);
    xn[(size_t)row * DM + tid]       = v0 * scale * w[tid];
    xn[(size_t)row * DM + tid + 256] = v1 * scale * w[tid + 256];
}

// -------- causal depthwise conv (DC=4) + SiLU, outputs TRANSPOSED (b,di,t) ----
__global__ __launch_bounds__(256) void conv_tr_kernel(
    const float* __restrict__ xr, const float* __restrict__ cw,
    const float* __restrict__ cb, float* __restrict__ xpT, float* __restrict__ resT)
{
    __shared__ float tp[64][65];
    __shared__ float tr[64][65];
    const int di0 = blockIdx.x * 64;
    const int t0  = blockIdx.y * 64;
    const int b   = blockIdx.z;
    const int c  = threadIdx.x & 63;
    const int r4 = threadIdx.x >> 6;
    const int di = di0 + c;
    const float bias = cb[di];
    float w0 = cw[di * DC + 0], w1 = cw[di * DC + 1],
          w2 = cw[di * DC + 2], w3 = cw[di * DC + 3];
    #pragma unroll
    for (int rr = 0; rr < 64; rr += 4) {
        const int t = t0 + rr + r4;
        const int bt = b * Tt + t;
        float acc = bias;
        if (t >= 3) {
            acc = fmaf(w0, xr[(size_t)(bt - 3) * (2 * DI) + di], acc);
            acc = fmaf(w1, xr[(size_t)(bt - 2) * (2 * DI) + di], acc);
            acc = fmaf(w2, xr[(size_t)(bt - 1) * (2 * DI) + di], acc);
        } else {
            if (t >= 1) acc = fmaf(w2, xr[(size_t)(bt - 1) * (2 * DI) + di], acc);
            if (t >= 2) acc = fmaf(w1, xr[(size_t)(bt - 2) * (2 * DI) + di], acc);
        }
        acc = fmaf(w3, xr[(size_t)bt * (2 * DI) + di], acc);
        tp[rr + r4][c] = silu_fast(acc);
        tr[rr + r4][c] = xr[(size_t)bt * (2 * DI) + DI + di];
    }
    __syncthreads();
    #pragma unroll
    for (int dd = 0; dd < 64; dd += 4) {
        const int dw = dd + r4;
        const size_t o = ((size_t)b * DI + di0 + dw) * Tt + t0 + c;
        xpT[o]  = tp[c][dw];
        resT[o] = tr[c][dw];
    }
}

// ============= chunked selective scan ==========================================
// Transposed butterfly reduce: buf[i] holds pair-sums (s,s^16) for t = s4*16+i.
// 4 stages of exchange+rename; result for t = s lands on lane s.
__device__ __forceinline__ float xpose_reduce16(float* buf, int s) {
    #pragma unroll
    for (int i = 0; i < 16; ++i) buf[i] += __shfl_xor(buf[i], 8);
    const bool b3 = (s & 8) != 0;
    float r[8];
    #pragma unroll
    for (int i = 0; i < 8; ++i) r[i] = b3 ? buf[i + 8] : buf[i];
    #pragma unroll
    for (int i = 0; i < 8; ++i) r[i] += __shfl_xor(r[i], 4);
    const bool b2 = (s & 4) != 0;
    float w[4];
    #pragma unroll
    for (int i = 0; i < 4; ++i) w[i] = b2 ? r[i + 4] : r[i];
    #pragma unroll
    for (int i = 0; i < 4; ++i) w[i] += __shfl_xor(w[i], 2);
    const bool b1 = (s & 2) != 0;
    float v0 = b1 ? w[2] : w[0];
    float v1 = b1 ? w[3] : w[1];
    v0 += __shfl_xor(v0, 1);
    v1 += __shfl_xor(v1, 1);
    return (s & 1) ? v1 : v0;
}

// Pass A: per chunk, from h=0: local h_end and decay product P = exp(Ads*sum dt)
__global__ __launch_bounds__(256) void scan_passA(
    const float* __restrict__ deltaT, const float* __restrict__ xdbl,
    const float* __restrict__ xpT, const float* __restrict__ A_log,
    float* __restrict__ hE, float* __restrict__ Pp)
{
    __shared__ float sB[CL][32];
    const int tid = threadIdx.x;
    const int g = tid >> 5;
    const int s = tid & 31;
    const int c = blockIdx.x & (NCH - 1);
    const int cg = blockIdx.x >> 3;
    const int b = cg >> 7;
    const int di = ((cg & 127) << 3) + g;
    const int ch = b * DI + di;
    {   // stage B columns (xdbl cols 32..64) for the whole chunk
        const int row0 = tid >> 3;          // 0..31
        const int col  = (tid & 7) << 2;    // 0..28
        const float* src = xdbl + ((size_t)b * Tt + c * CL) * 96 + 32;
        #pragma unroll
        for (int r0 = 0; r0 < CL; r0 += 32)
            *(float4*)&sB[r0 + row0][col] = *(const float4*)(src + (size_t)(r0 + row0) * 96 + col);
    }
    __syncthreads();
    const float Ads2 = -expf(A_log[di * DS + s]) * 1.44269504f;
    const float* dp = deltaT + (size_t)ch * Tt + c * CL;
    const float* up = xpT + (size_t)ch * Tt + c * CL;
    float h = 0.f, dts = 0.f;
    #pragma unroll
    for (int tq = 0; tq < CL / 4; ++tq) {
        float4 d4 = *(const float4*)(dp + tq * 4);
        float4 u4 = *(const float4*)(up + tq * 4);
        const float dv[4] = {d4.x, d4.y, d4.z, d4.w};
        const float uv[4] = {u4.x, u4.y, u4.z, u4.w};
        #pragma unroll
        for (int q = 0; q < 4; ++q) {
            const int t = tq * 4 + q;
            const float dA = __builtin_amdgcn_exp2f(dv[q] * Ads2);
            h = fmaf(dA, h, dv[q] * uv[q] * sB[t][s]);
            dts += dv[q];
        }
    }
    const int lane = ch * DS + s;
    hE[(size_t)c * NLANE + lane] = h;
    Pp[(size_t)c * NLANE + lane] = __builtin_amdgcn_exp2f(Ads2 * dts);
}

// Pass B: carry propagation; hE[c][lane] is overwritten with h_start(c)
__global__ __launch_bounds__(256) void scan_passB(
    float* __restrict__ hE, const float* __restrict__ Pp)
{
    const int lane = blockIdx.x * 256 + threadIdx.x;
    float h = 0.f;
    #pragma unroll
    for (int c = 0; c < NCH; ++c) {
        const float he = hE[(size_t)c * NLANE + lane];
        const float p  = Pp[(size_t)c * NLANE + lane];
        hE[(size_t)c * NLANE + lane] = h;
        h = fmaf(p, h, he);
    }
}

// Pass C: recompute with correct h_start; butterfly-transposed y reduction
__global__ __launch_bounds__(256) void scan_passC(
    const float* __restrict__ deltaT, const float* __restrict__ xdbl,
    const float* __restrict__ xpT, const float* __restrict__ resT,
    const float* __restrict__ A_log, const float* __restrict__ Dvec,
    const float* __restrict__ hE, float* __restrict__ yT)
{
    __shared__ float sBC[CL][64];   // [t][0:32)=B, [32:64)=C ; read bank = s, conflict-free
    const int tid = threadIdx.x;
    const int g = tid >> 5;
    const int s = tid & 31;
    const int c = blockIdx.x & (NCH - 1);
    const int cg = blockIdx.x >> 3;
    const int b = cg >> 7;
    const int di = ((cg & 127) << 3) + g;
    const int ch = b * DI + di;
    {   // stage B and C (xdbl cols 32..96) for the whole chunk
        const int row0 = tid >> 4;          // 0..15
        const int col  = (tid & 15) << 2;   // 0..60
        const float* src = xdbl + ((size_t)b * Tt + c * CL) * 96 + 32;
        #pragma unroll
        for (int r0 = 0; r0 < CL; r0 += 16)
            *(float4*)&sBC[r0 + row0][col] = *(const float4*)(src + (size_t)(r0 + row0) * 96 + col);
    }
    __syncthreads();
    const float Ads2 = -expf(A_log[di * DS + s]) * 1.44269504f;
    const float Dv = Dvec[di];
    const float* dp = deltaT + (size_t)ch * Tt + c * CL;
    const float* up = xpT + (size_t)ch * Tt + c * CL;
    const float* rp = resT + (size_t)ch * Tt + c * CL;
    float* yp = yT + (size_t)ch * Tt + c * CL;
    float h = hE[(size_t)c * NLANE + ch * DS + s];
    const bool b4 = (s & 16) != 0;
    for (int t0 = 0; t0 < CL; t0 += 32) {
        float buf[16] = {};
        #pragma unroll
        for (int tq = 0; tq < 8; ++tq) {
            const int tb = t0 + tq * 4;
            float4 d4 = *(const float4*)(dp + tb);
            float4 u4 = *(const float4*)(up + tb);
            const float dv[4] = {d4.x, d4.y, d4.z, d4.w};
            const float uv[4] = {u4.x, u4.y, u4.z, u4.w};
            #pragma unroll
            for (int q = 0; q < 4; ++q) {
                const int t  = tb + q;          // within chunk
                const int tl = tq * 4 + q;      // 0..31 within 32-block
                const float dA = __builtin_amdgcn_exp2f(dv[q] * Ads2);
                h = fmaf(dA, h, dv[q] * uv[q] * sBC[t][s]);
                const float ps = h * sBC[t][32 + s];
                const float pr = ps + __shfl_xor(ps, 16);
                const bool keep = (tl & 16) ? b4 : !b4;
                buf[tl & 15] = keep ? pr : buf[tl & 15];
            }
        }
        const float y = xpose_reduce16(buf, s);
        const float uend = up[t0 + s];
        const float rend = rp[t0 + s];
        yp[t0 + s] = fmaf(uend, Dv, y) * silu_fast(rend);
    }
}

// ---------------- mean-pool over DM, one wave per row -------------------------
__global__ __launch_bounds__(256) void pool_kernel(
    const float* __restrict__ enc, float* __restrict__ pooled)
{
    const int row = blockIdx.x * 4 + (threadIdx.x >> 6);
    const int lane = threadIdx.x & 63;
    const float* p = enc + (size_t)row * DM;
    float sacc = 0.f;
    #pragma unroll
    for (int i = 0; i < DM / 64; ++i) sacc += p[lane + 64 * i];
    #pragma unroll
    for (int m = 32; m; m >>= 1) sacc += __shfl_xor(sacc, m);
    if (lane == 0) pooled[row] = sacc * (1.0f / DM);
}

// ---------------- classifier ---------------------------------------------------
__global__ __launch_bounds__(256) void cls_kernel(
    const float* __restrict__ pooled, const float* __restrict__ w_cls,
    const float* __restrict__ b_cls, float* __restrict__ out)
{
    const int idx = blockIdx.x * 256 + threadIdx.x;
    if (idx >= Bb * NC) return;
    const int b = idx / NC, c = idx % NC;
    float acc = b_cls[c];
    for (int t = 0; t < DM; ++t)
        acc = fmaf(pooled[b * DM + t], w_cls[t * NC + c], acc);
    out[idx] = acc;
}

extern "C" void kernel_launch(void* const* d_in, const int* in_sizes, int n_in,
                              void* d_out, int out_size, void* d_ws, size_t ws_size,
                              hipStream_t stream) {
    const float* x      = (const float*)d_in[0];
    const float* w_proj = (const float*)d_in[1];
    const float* b_proj = (const float*)d_in[2];
    const float* rms_w  = (const float*)d_in[3];
    const float* w_in   = (const float*)d_in[4];
    const float* conv_w = (const float*)d_in[5];
    const float* conv_b = (const float*)d_in[6];
    const float* w_xprj = (const float*)d_in[7];
    const float* w_dt   = (const float*)d_in[8];
    const float* b_dt   = (const float*)d_in[9];
    const float* A_log  = (const float*)d_in[10];
    const float* Dvec   = (const float*)d_in[11];
    const float* w_out  = (const float*)d_in[12];
    const float* w_cls  = (const float*)d_in[13];
    const float* b_cls  = (const float*)d_in[14];
    float* out = (float*)d_out;

    float* ws = (float*)d_ws;
    float* h0     = ws;
    float* xn     = h0 + (size_t)BT * DM;
    float* xr     = xn + (size_t)BT * DM;
    float* xpT    = xr + (size_t)BT * 2 * DI;
    float* resT   = xpT + (size_t)Bb * DI * Tt;
    float* xdbl   = resT + (size_t)Bb * DI * Tt;
    float* pooled = xdbl + (size_t)BT * 96;
    float* hE     = pooled + 4096;
    float* Pp     = hE + (size_t)NCH * NLANE;
    float* deltaT = xr;                           // alias: xr dead after conv_tr
    float* yT     = xr + (size_t)Bb * DI * Tt;    // alias: upper half of xr
    float* enc    = xn;                           // alias: xn dead after gemm3

    // 1) h0 = x @ w_proj + b_proj
    gemm64<1,0><<<dim3(DM / 64, BT / 64), 256, 0, stream>>>(
        x, NM, w_proj, b_proj, nullptr, h0, BT, DM, NM);
    // 2) xn = rmsnorm(h0) * rms_w
    rms_kernel<<<BT, 256, 0, stream>>>(h0, rms_w, xn);
    // 3) xr = xn @ w_in    (128x128 tile)
    gemm128<<<dim3(2 * DI / 128, BT / 128), 256, 0, stream>>>(
        xn, DM, w_in, xr, 2 * DI, DM);
    // 4) xpT = silu(causal_dwconv(xr[:, :DI]))^T ; resT = xr[:, DI:]^T
    conv_tr_kernel<<<dim3(DI / 64, Tt / 64, Bb), 256, 0, stream>>>(
        xr, conv_w, conv_b, xpT, resT);
    // 5) xdbl = xp @ w_xproj   (A read transposed)
    gemm_at<0><<<dim3((96 + 63) / 64, BT / 64), 256, 0, stream>>>(
        xpT, w_xprj, nullptr, xdbl, BT, 96, DI);
    // 6) deltaT = softplus(dt @ w_dt + b_dt)^T
    gemm64<2,1><<<dim3(DI / 64, BT / 64), 256, 0, stream>>>(
        xdbl, 96, w_dt, b_dt, nullptr, deltaT, BT, DI, DR);
    // 7) chunked selective scan
    scan_passA<<<Bb * (DI / 8) * NCH, 256, 0, stream>>>(
        deltaT, xdbl, xpT, A_log, hE, Pp);
    scan_passB<<<NLANE / 256, 256, 0, stream>>>(hE, Pp);
    scan_passC<<<Bb * (DI / 8) * NCH, 256, 0, stream>>>(
        deltaT, xdbl, xpT, resT, A_log, Dvec, hE, yT);
    // 8) enc = h0 + y @ w_out  (A read transposed)
    gemm_at<3><<<dim3(DM / 64, BT / 64), 256, 0, stream>>>(
        yT, w_out, h0, enc, BT, DM, DI);
    // 9) pooled = mean(enc, axis=-1)
    pool_kernel<<<BT / 4, 256, 0, stream>>>(enc, pooled);
    // 10) out = pooled @ w_cls + b_cls
    cls_kernel<<<(Bb * NC + 255) / 256, 256, 0, stream>>>(pooled, w_cls, b_cls, out);
}

// Round 5
// 399.477 us; speedup vs baseline: 1.2934x; 1.2538x over previous
//
#include <hip/hip_runtime.h>
#include <hip/hip_bf16.h>
#include <cstddef>

#define Bb 8
#define Tt 512
#define NM 128
#define DM 512
#define DI 1024
#define DS 32
#define DR 32
#define DC 4
#define NC 100
#define BT (Bb*Tt)     // 4096
#define NCH 8          // scan chunks
#define CL  64         // chunk length
#define NLANE (Bb*DI*DS)  // 262144

typedef unsigned short ushort_t;
typedef unsigned int uint_t;
typedef __attribute__((ext_vector_type(8))) short bf8;    // 8 bf16 in 4 VGPRs
typedef __attribute__((ext_vector_type(4))) float f4;

__device__ __forceinline__ float softplus_f(float x) {
    return fmaxf(x, 0.f) + log1pf(expf(-fabsf(x)));
}
__device__ __forceinline__ float silu_fast(float x) {
    return __fdividef(x, 1.f + __expf(-x));
}
__device__ __forceinline__ ushort_t bf16_rne(float x) {
    uint_t u = __float_as_uint(x);
    uint_t r = u + 0x7FFFu + ((u >> 16) & 1u);
    return (ushort_t)(r >> 16);
}
__device__ __forceinline__ float bf16_tof(ushort_t h) {
    return __uint_as_float(((uint_t)h) << 16);
}

// ---- split fp32 (K,N) row-major into bf16 hi/lo, TRANSPOSED to (N,K) --------
__global__ __launch_bounds__(256) void split_tr_kernel(
    const float* __restrict__ src, ushort_t* __restrict__ hi,
    ushort_t* __restrict__ lo, int K, int N)
{
    __shared__ ushort_t th[32][34], tl[32][34];
    const int k0 = blockIdx.y * 32, n0 = blockIdx.x * 32;
    #pragma unroll
    for (int it = 0; it < 4; ++it) {
        const int idx = it * 256 + threadIdx.x;
        const int r = idx >> 5, c = idx & 31;
        const float v = src[(size_t)(k0 + r) * N + n0 + c];
        const ushort_t h = bf16_rne(v);
        th[c][r] = h;
        tl[c][r] = bf16_rne(v - bf16_tof(h));
    }
    __syncthreads();
    #pragma unroll
    for (int it = 0; it < 4; ++it) {
        const int idx = it * 256 + threadIdx.x;
        const int r = idx >> 5, c = idx & 31;
        hi[(size_t)(n0 + r) * K + k0 + c] = th[r][c];
        lo[(size_t)(n0 + r) * K + k0 + c] = tl[r][c];
    }
}

// ---- split-bf16 MFMA GEMM: C = A@B (+add), A fp32 (M,K) lda, B pre-split ----
// B given as hi/lo bf16 arrays in (N,K) layout (k-contiguous).
// EPI: 0 none, 3 +add[m*N+n]. 256 thr = 4 waves (2x2), wave tile (BM/2)x(BN/2).
template<int BM, int BN, int EPI>
__global__ __launch_bounds__(256) void gemm_mfma(
    const float* __restrict__ A, int lda,
    const ushort_t* __restrict__ Bhi, const ushort_t* __restrict__ Blo,
    const float* __restrict__ add, float* __restrict__ C,
    int N, int K)
{
    constexpr int FM = BM / 32, FN = BN / 32;
    constexpr int AIT = BM * 32 / 1024;   // float4 loads/thread
    constexpr int BIT = BN * 32 / 2048;   // ushort8 loads/thread per half
    __shared__ ushort_t sA[2][BM][40];
    __shared__ ushort_t sB[2][BN][40];
    const int tid = threadIdx.x;
    const int wid = tid >> 6, l = tid & 63, l15 = l & 15, g = l >> 4;
    const int wm = (wid >> 1) * (BM / 2), wn = (wid & 1) * (BN / 2);
    const int bm0 = blockIdx.y * BM, bn0 = blockIdx.x * BN;

    f4 acc[FM][FN] = {};
    float4 aR[AIT];
    uint4 bRh[BIT], bRl[BIT];

    auto loadG = [&](int k0) {
        #pragma unroll
        for (int r = 0; r < AIT; ++r) {
            const int idx = r * 1024 + tid * 4;
            const int m = idx >> 5, k = idx & 31;
            aR[r] = *(const float4*)(A + (size_t)(bm0 + m) * lda + k0 + k);
        }
        #pragma unroll
        for (int r = 0; r < BIT; ++r) {
            const int idx = r * 2048 + tid * 8;
            const int n = idx >> 5, k = idx & 31;
            const size_t o = (size_t)(bn0 + n) * K + k0 + k;
            bRh[r] = *(const uint4*)(Bhi + o);
            bRl[r] = *(const uint4*)(Blo + o);
        }
    };
    auto stoL = [&]() {
        #pragma unroll
        for (int r = 0; r < AIT; ++r) {
            const int idx = r * 1024 + tid * 4;
            const int m = idx >> 5, k = idx & 31;
            const float vv[4] = {aR[r].x, aR[r].y, aR[r].z, aR[r].w};
            ushort_t h[4], lo_[4];
            #pragma unroll
            for (int q = 0; q < 4; ++q) {
                h[q] = bf16_rne(vv[q]);
                lo_[q] = bf16_rne(vv[q] - bf16_tof(h[q]));
            }
            uint2 uh, ul;
            uh.x = (uint_t)h[0] | ((uint_t)h[1] << 16);
            uh.y = (uint_t)h[2] | ((uint_t)h[3] << 16);
            ul.x = (uint_t)lo_[0] | ((uint_t)lo_[1] << 16);
            ul.y = (uint_t)lo_[2] | ((uint_t)lo_[3] << 16);
            *(uint2*)&sA[0][m][k] = uh;
            *(uint2*)&sA[1][m][k] = ul;
        }
        #pragma unroll
        for (int r = 0; r < BIT; ++r) {
            const int idx = r * 2048 + tid * 8;
            const int n = idx >> 5, k = idx & 31;
            *(uint4*)&sB[0][n][k] = bRh[r];
            *(uint4*)&sB[1][n][k] = bRl[r];
        }
    };

    loadG(0);
    for (int k0 = 0; k0 < K; k0 += 32) {
        stoL();
        __syncthreads();
        if (k0 + 32 < K) loadG(k0 + 32);
        bf8 ah[FM], al_[FM], bh[FN], bl_[FN];
        #pragma unroll
        for (int i = 0; i < FM; ++i) {
            ah[i]  = *(bf8*)&sA[0][wm + i * 16 + l15][g * 8];
            al_[i] = *(bf8*)&sA[1][wm + i * 16 + l15][g * 8];
        }
        #pragma unroll
        for (int j = 0; j < FN; ++j) {
            bh[j]  = *(bf8*)&sB[0][wn + j * 16 + l15][g * 8];
            bl_[j] = *(bf8*)&sB[1][wn + j * 16 + l15][g * 8];
        }
        #pragma unroll
        for (int i = 0; i < FM; ++i)
            #pragma unroll
            for (int j = 0; j < FN; ++j)
                acc[i][j] = __builtin_amdgcn_mfma_f32_16x16x32_bf16(ah[i], bh[j], acc[i][j], 0, 0, 0);
        #pragma unroll
        for (int i = 0; i < FM; ++i)
            #pragma unroll
            for (int j = 0; j < FN; ++j)
                acc[i][j] = __builtin_amdgcn_mfma_f32_16x16x32_bf16(al_[i], bh[j], acc[i][j], 0, 0, 0);
        #pragma unroll
        for (int i = 0; i < FM; ++i)
            #pragma unroll
            for (int j = 0; j < FN; ++j)
                acc[i][j] = __builtin_amdgcn_mfma_f32_16x16x32_bf16(ah[i], bl_[j], acc[i][j], 0, 0, 0);
        __syncthreads();
    }
    #pragma unroll
    for (int i = 0; i < FM; ++i)
        #pragma unroll
        for (int j = 0; j < FN; ++j)
            #pragma unroll
            for (int r = 0; r < 4; ++r) {
                const int m = bm0 + wm + i * 16 + g * 4 + r;
                const int n = bn0 + wn + j * 16 + l15;
                float v = acc[i][j][r];
                if (EPI == 3) v += add[(size_t)m * N + n];
                C[(size_t)m * N + n] = v;
            }
}

// ---------------- generic 64x64 tiled fp32 GEMM: C = epi(A@B) -----------------
// EPI: 0 none, 1 +bias[n], 2 softplus(+bias[n]), 3 +add[m*N+n]
// TSTORE: 0 -> C[m*N+n]; 1 -> C[((m/Tt)*N + n)*Tt + m%Tt]
template<int EPI, int TSTORE>
__global__ __launch_bounds__(256) void gemm64(
    const float* __restrict__ A, int lda,
    const float* __restrict__ B,
    const float* __restrict__ bias,
    const float* __restrict__ add,
    float* __restrict__ C,
    int M, int N, int K)
{
    __shared__ float As[16][68];
    __shared__ float Bs[16][64];
    const int tid = threadIdx.x;
    const int bm = blockIdx.y * 64;
    const int bn = blockIdx.x * 64;
    const int tx = tid & 15;
    const int ty = tid >> 4;
    const int la_m = tid >> 2;
    const int la_k = (tid & 3) << 2;
    const int lb_k = tid >> 4;
    const int lb_n = (tid & 15) << 2;

    float acc[4][4] = {};
    for (int k0 = 0; k0 < K; k0 += 16) {
        float4 av = *(const float4*)(A + (size_t)(bm + la_m) * lda + k0 + la_k);
        As[la_k + 0][la_m] = av.x;
        As[la_k + 1][la_m] = av.y;
        As[la_k + 2][la_m] = av.z;
        As[la_k + 3][la_m] = av.w;
        const int gn = bn + lb_n;
        const float* bp = B + (size_t)(k0 + lb_k) * N + gn;
        float4 bv;
        if (gn + 3 < N) {
            bv = *(const float4*)bp;
        } else {
            bv.x = (gn + 0 < N) ? bp[0] : 0.f;
            bv.y = (gn + 1 < N) ? bp[1] : 0.f;
            bv.z = (gn + 2 < N) ? bp[2] : 0.f;
            bv.w = (gn + 3 < N) ? bp[3] : 0.f;
        }
        *(float4*)&Bs[lb_k][lb_n] = bv;
        __syncthreads();
        #pragma unroll
        for (int k = 0; k < 16; ++k) {
            float4 a = *(const float4*)&As[k][ty << 2];
            float4 b = *(const float4*)&Bs[k][tx << 2];
            float ar[4] = {a.x, a.y, a.z, a.w};
            float br[4] = {b.x, b.y, b.z, b.w};
            #pragma unroll
            for (int i = 0; i < 4; ++i)
                #pragma unroll
                for (int j = 0; j < 4; ++j)
                    acc[i][j] = fmaf(ar[i], br[j], acc[i][j]);
        }
        __syncthreads();
    }
    if (TSTORE == 0) {
        #pragma unroll
        for (int i = 0; i < 4; ++i) {
            const int gm = bm + (ty << 2) + i;
            #pragma unroll
            for (int j = 0; j < 4; ++j) {
                const int gn = bn + (tx << 2) + j;
                if (gn < N) {
                    float v = acc[i][j];
                    if (EPI == 1) v += bias[gn];
                    else if (EPI == 2) v = softplus_f(v + bias[gn]);
                    else if (EPI == 3) v += add[(size_t)gm * N + gn];
                    C[(size_t)gm * N + gn] = v;
                }
            }
        }
    } else {
        const int bq = bm >> 9;
        const int tt0 = (bm & (Tt - 1)) + (ty << 2);
        #pragma unroll
        for (int j = 0; j < 4; ++j) {
            const int gn = bn + (tx << 2) + j;
            if (gn < N) {
                float4 v;
                float* vv = (float*)&v;
                #pragma unroll
                for (int i = 0; i < 4; ++i) {
                    float t = acc[i][j];
                    if (EPI == 2) t = softplus_f(t + bias[gn]);
                    vv[i] = t;
                }
                *(float4*)(C + ((size_t)bq * N + gn) * Tt + tt0) = v;
            }
        }
    }
}

// --------- GEMM with per-batch-transposed A: A_T layout (b, K, Tt) ------------
template<int EPI>
__global__ __launch_bounds__(256) void gemm_at(
    const float* __restrict__ A_T,
    const float* __restrict__ B,
    const float* __restrict__ add,
    float* __restrict__ C,
    int M, int N, int K)
{
    __shared__ float As[16][68];
    __shared__ float Bs[16][64];
    const int tid = threadIdx.x;
    const int bm = blockIdx.y * 64;
    const int bn = blockIdx.x * 64;
    const int tx = tid & 15;
    const int ty = tid >> 4;
    const int lb_k = tid >> 4;
    const int lb_n = (tid & 15) << 2;
    const int bq = bm >> 9;
    const int tt0 = bm & (Tt - 1);

    float acc[4][4] = {};
    for (int k0 = 0; k0 < K; k0 += 16) {
        float4 av = *(const float4*)(A_T + ((size_t)bq * K + k0 + lb_k) * Tt + tt0 + lb_n);
        *(float4*)&As[lb_k][lb_n] = av;
        const int gn = bn + lb_n;
        const float* bp = B + (size_t)(k0 + lb_k) * N + gn;
        float4 bv;
        if (gn + 3 < N) {
            bv = *(const float4*)bp;
        } else {
            bv.x = (gn + 0 < N) ? bp[0] : 0.f;
            bv.y = (gn + 1 < N) ? bp[1] : 0.f;
            bv.z = (gn + 2 < N) ? bp[2] : 0.f;
            bv.w = (gn + 3 < N) ? bp[3] : 0.f;
        }
        *(float4*)&Bs[lb_k][lb_n] = bv;
        __syncthreads();
        #pragma unroll
        for (int k = 0; k < 16; ++k) {
            float4 a = *(const float4*)&As[k][ty << 2];
            float4 b = *(const float4*)&Bs[k][tx << 2];
            float ar[4] = {a.x, a.y, a.z, a.w};
            float br[4] = {b.x, b.y, b.z, b.w};
            #pragma unroll
            for (int i = 0; i < 4; ++i)
                #pragma unroll
                for (int j = 0; j < 4; ++j)
                    acc[i][j] = fmaf(ar[i], br[j], acc[i][j]);
        }
        __syncthreads();
    }
    #pragma unroll
    for (int i = 0; i < 4; ++i) {
        const int gm = bm + (ty << 2) + i;
        #pragma unroll
        for (int j = 0; j < 4; ++j) {
            const int gn = bn + (tx << 2) + j;
            if (gn < N) {
                float v = acc[i][j];
                if (EPI == 3) v += add[(size_t)gm * N + gn];
                C[(size_t)gm * N + gn] = v;
            }
        }
    }
}

// ---------------- RMSNorm over DM=512, one block per row ----------------------
__global__ __launch_bounds__(256) void rms_kernel(
    const float* __restrict__ h0, const float* __restrict__ w, float* __restrict__ xn)
{
    const int row = blockIdx.x;
    const float* p = h0 + (size_t)row * DM;
    const int tid = threadIdx.x;
    float v0 = p[tid], v1 = p[tid + 256];
    float ss = v0 * v0 + v1 * v1;
    #pragma unroll
    for (int m = 32; m; m >>= 1) ss += __shfl_xor(ss, m);
    __shared__ float wsum[4];
    if ((tid & 63) == 0) wsum[tid >> 6] = ss;
    __syncthreads();
    const float tot = wsum[0] + wsum[1] + wsum[2] + wsum[3];
    const float scale = rsqrtf(tot * (1.0f / DM) + 1e-5f);
    xn[(size_t)row * DM + tid]       = v0 * scale * w[tid];
    xn[(size_t)row * DM + tid + 256] = v1 * scale * w[tid + 256];
}

// -------- causal depthwise conv (DC=4) + SiLU, outputs TRANSPOSED (b,di,t) ----
__global__ __launch_bounds__(256) void conv_tr_kernel(
    const float* __restrict__ xr, const float* __restrict__ cw,
    const float* __restrict__ cb, float* __restrict__ xpT, float* __restrict__ resT)
{
    __shared__ float tp[64][65];
    __shared__ float tr[64][65];
    const int di0 = blockIdx.x * 64;
    const int t0  = blockIdx.y * 64;
    const int b   = blockIdx.z;
    const int c  = threadIdx.x & 63;
    const int r4 = threadIdx.x >> 6;
    const int di = di0 + c;
    const float bias = cb[di];
    float w0 = cw[di * DC + 0], w1 = cw[di * DC + 1],
          w2 = cw[di * DC + 2], w3 = cw[di * DC + 3];
    #pragma unroll
    for (int rr = 0; rr < 64; rr += 4) {
        const int t = t0 + rr + r4;
        const int bt = b * Tt + t;
        float acc = bias;
        if (t >= 3) {
            acc = fmaf(w0, xr[(size_t)(bt - 3) * (2 * DI) + di], acc);
            acc = fmaf(w1, xr[(size_t)(bt - 2) * (2 * DI) + di], acc);
            acc = fmaf(w2, xr[(size_t)(bt - 1) * (2 * DI) + di], acc);
        } else {
            if (t >= 1) acc = fmaf(w2, xr[(size_t)(bt - 1) * (2 * DI) + di], acc);
            if (t >= 2) acc = fmaf(w1, xr[(size_t)(bt - 2) * (2 * DI) + di], acc);
        }
        acc = fmaf(w3, xr[(size_t)bt * (2 * DI) + di], acc);
        tp[rr + r4][c] = silu_fast(acc);
        tr[rr + r4][c] = xr[(size_t)bt * (2 * DI) + DI + di];
    }
    __syncthreads();
    #pragma unroll
    for (int dd = 0; dd < 64; dd += 4) {
        const int dw = dd + r4;
        const size_t o = ((size_t)b * DI + di0 + dw) * Tt + t0 + c;
        xpT[o]  = tp[c][dw];
        resT[o] = tr[c][dw];
    }
}

// ============= chunked selective scan ==========================================
__device__ __forceinline__ float xpose_reduce16(float* buf, int s) {
    #pragma unroll
    for (int i = 0; i < 16; ++i) buf[i] += __shfl_xor(buf[i], 8);
    const bool b3 = (s & 8) != 0;
    float r[8];
    #pragma unroll
    for (int i = 0; i < 8; ++i) r[i] = b3 ? buf[i + 8] : buf[i];
    #pragma unroll
    for (int i = 0; i < 8; ++i) r[i] += __shfl_xor(r[i], 4);
    const bool b2 = (s & 4) != 0;
    float w[4];
    #pragma unroll
    for (int i = 0; i < 4; ++i) w[i] = b2 ? r[i + 4] : r[i];
    #pragma unroll
    for (int i = 0; i < 4; ++i) w[i] += __shfl_xor(w[i], 2);
    const bool b1 = (s & 2) != 0;
    float v0 = b1 ? w[2] : w[0];
    float v1 = b1 ? w[3] : w[1];
    v0 += __shfl_xor(v0, 1);
    v1 += __shfl_xor(v1, 1);
    return (s & 1) ? v1 : v0;
}

// Pass A: per chunk, from h=0: local h_end and decay product P = exp(Ads*sum dt)
__global__ __launch_bounds__(256) void scan_passA(
    const float* __restrict__ deltaT, const float* __restrict__ xdbl,
    const float* __restrict__ xpT, const float* __restrict__ A_log,
    float* __restrict__ hE, float* __restrict__ Pp)
{
    __shared__ float sB[CL][32];
    const int tid = threadIdx.x;
    const int g = tid >> 5;
    const int s = tid & 31;
    const int c = blockIdx.x & (NCH - 1);
    const int cg = blockIdx.x >> 3;
    const int b = cg >> 7;
    const int di = ((cg & 127) << 3) + g;
    const int ch = b * DI + di;
    {
        const int row0 = tid >> 3;
        const int col  = (tid & 7) << 2;
        const float* src = xdbl + ((size_t)b * Tt + c * CL) * 96 + 32;
        #pragma unroll
        for (int r0 = 0; r0 < CL; r0 += 32)
            *(float4*)&sB[r0 + row0][col] = *(const float4*)(src + (size_t)(r0 + row0) * 96 + col);
    }
    __syncthreads();
    const float Ads2 = -expf(A_log[di * DS + s]) * 1.44269504f;
    const float* dp = deltaT + (size_t)ch * Tt + c * CL;
    const float* up = xpT + (size_t)ch * Tt + c * CL;
    float h = 0.f, dts = 0.f;
    #pragma unroll
    for (int tq = 0; tq < CL / 4; ++tq) {
        float4 d4 = *(const float4*)(dp + tq * 4);
        float4 u4 = *(const float4*)(up + tq * 4);
        const float dv[4] = {d4.x, d4.y, d4.z, d4.w};
        const float uv[4] = {u4.x, u4.y, u4.z, u4.w};
        #pragma unroll
        for (int q = 0; q < 4; ++q) {
            const int t = tq * 4 + q;
            const float dA = __builtin_amdgcn_exp2f(dv[q] * Ads2);
            h = fmaf(dA, h, dv[q] * uv[q] * sB[t][s]);
            dts += dv[q];
        }
    }
    const int lane = ch * DS + s;
    hE[(size_t)c * NLANE + lane] = h;
    Pp[(size_t)c * NLANE + lane] = __builtin_amdgcn_exp2f(Ads2 * dts);
}

// Pass B: carry propagation; hE[c][lane] is overwritten with h_start(c)
__global__ __launch_bounds__(256) void scan_passB(
    float* __restrict__ hE, const float* __restrict__ Pp)
{
    const int lane = blockIdx.x * 256 + threadIdx.x;
    float h = 0.f;
    #pragma unroll
    for (int c = 0; c < NCH; ++c) {
        const float he = hE[(size_t)c * NLANE + lane];
        const float p  = Pp[(size_t)c * NLANE + lane];
        hE[(size_t)c * NLANE + lane] = h;
        h = fmaf(p, h, he);
    }
}

// Pass C: recompute with correct h_start; writes y ROW-MAJOR (BT, DI)
__global__ __launch_bounds__(256) void scan_passC(
    const float* __restrict__ deltaT, const float* __restrict__ xdbl,
    const float* __restrict__ xpT, const float* __restrict__ resT,
    const float* __restrict__ A_log, const float* __restrict__ Dvec,
    const float* __restrict__ hE, float* __restrict__ y)
{
    __shared__ float sBC[CL][64];
    __shared__ float ylds[CL][9];
    const int tid = threadIdx.x;
    const int g = tid >> 5;
    const int s = tid & 31;
    const int c = blockIdx.x & (NCH - 1);
    const int cg = blockIdx.x >> 3;
    const int b = cg >> 7;
    const int di0 = (cg & 127) << 3;
    const int di = di0 + g;
    const int ch = b * DI + di;
    {
        const int row0 = tid >> 4;
        const int col  = (tid & 15) << 2;
        const float* src = xdbl + ((size_t)b * Tt + c * CL) * 96 + 32;
        #pragma unroll
        for (int r0 = 0; r0 < CL; r0 += 16)
            *(float4*)&sBC[r0 + row0][col] = *(const float4*)(src + (size_t)(r0 + row0) * 96 + col);
    }
    __syncthreads();
    const float Ads2 = -expf(A_log[di * DS + s]) * 1.44269504f;
    const float Dv = Dvec[di];
    const float* dp = deltaT + (size_t)ch * Tt + c * CL;
    const float* up = xpT + (size_t)ch * Tt + c * CL;
    const float* rp = resT + (size_t)ch * Tt + c * CL;
    float h = hE[(size_t)c * NLANE + ch * DS + s];
    const bool b4 = (s & 16) != 0;
    for (int t0 = 0; t0 < CL; t0 += 32) {
        float buf[16] = {};
        #pragma unroll
        for (int tq = 0; tq < 8; ++tq) {
            const int tb = t0 + tq * 4;
            float4 d4 = *(const float4*)(dp + tb);
            float4 u4 = *(const float4*)(up + tb);
            const float dv[4] = {d4.x, d4.y, d4.z, d4.w};
            const float uv[4] = {u4.x, u4.y, u4.z, u4.w};
            #pragma unroll
            for (int q = 0; q < 4; ++q) {
                const int t  = tb + q;
                const int tl = tq * 4 + q;
                const float dA = __builtin_amdgcn_exp2f(dv[q] * Ads2);
                h = fmaf(dA, h, dv[q] * uv[q] * sBC[t][s]);
                const float ps = h * sBC[t][32 + s];
                const float pr = ps + __shfl_xor(ps, 16);
                const bool keep = (tl & 16) ? b4 : !b4;
                buf[tl & 15] = keep ? pr : buf[tl & 15];
            }
        }
        const float yr = xpose_reduce16(buf, s);
        const float uend = up[t0 + s];
        const float rend = rp[t0 + s];
        ylds[t0 + s][g] = fmaf(uend, Dv, yr) * silu_fast(rend);
    }
    __syncthreads();
    const int rr = tid >> 2;
    const int qq = (tid & 3) << 1;
    float2 v;
    v.x = ylds[rr][qq];
    v.y = ylds[rr][qq + 1];
    *(float2*)(y + ((size_t)b * Tt + c * CL + rr) * DI + di0 + qq) = v;
}

// ---------------- mean-pool over DM, one wave per row -------------------------
__global__ __launch_bounds__(256) void pool_kernel(
    const float* __restrict__ enc, float* __restrict__ pooled)
{
    const int row = blockIdx.x * 4 + (threadIdx.x >> 6);
    const int lane = threadIdx.x & 63;
    const float* p = enc + (size_t)row * DM;
    float sacc = 0.f;
    #pragma unroll
    for (int i = 0; i < DM / 64; ++i) sacc += p[lane + 64 * i];
    #pragma unroll
    for (int m = 32; m; m >>= 1) sacc += __shfl_xor(sacc, m);
    if (lane == 0) pooled[row] = sacc * (1.0f / DM);
}

// ---------------- classifier ---------------------------------------------------
__global__ __launch_bounds__(256) void cls_kernel(
    const float* __restrict__ pooled, const float* __restrict__ w_cls,
    const float* __restrict__ b_cls, float* __restrict__ out)
{
    const int idx = blockIdx.x * 256 + threadIdx.x;
    if (idx >= Bb * NC) return;
    const int b = idx / NC, c = idx % NC;
    float acc = b_cls[c];
    for (int t = 0; t < DM; ++t)
        acc = fmaf(pooled[b * DM + t], w_cls[t * NC + c], acc);
    out[idx] = acc;
}

extern "C" void kernel_launch(void* const* d_in, const int* in_sizes, int n_in,
                              void* d_out, int out_size, void* d_ws, size_t ws_size,
                              hipStream_t stream) {
    const float* x      = (const float*)d_in[0];
    const float* w_proj = (const float*)d_in[1];
    const float* b_proj = (const float*)d_in[2];
    const float* rms_w  = (const float*)d_in[3];
    const float* w_in   = (const float*)d_in[4];
    const float* conv_w = (const float*)d_in[5];
    const float* conv_b = (const float*)d_in[6];
    const float* w_xprj = (const float*)d_in[7];
    const float* w_dt   = (const float*)d_in[8];
    const float* b_dt   = (const float*)d_in[9];
    const float* A_log  = (const float*)d_in[10];
    const float* Dvec   = (const float*)d_in[11];
    const float* w_out  = (const float*)d_in[12];
    const float* w_cls  = (const float*)d_in[13];
    const float* b_cls  = (const float*)d_in[14];
    float* out = (float*)d_out;

    float* ws = (float*)d_ws;
    float* h0     = ws;
    float* xn     = h0 + (size_t)BT * DM;
    float* xr     = xn + (size_t)BT * DM;
    float* xpT    = xr + (size_t)BT * 2 * DI;
    float* resT   = xpT + (size_t)Bb * DI * Tt;
    float* xdbl   = resT + (size_t)Bb * DI * Tt;
    float* pooled = xdbl + (size_t)BT * 96;
    float* hE     = pooled + 4096;
    float* Pp     = hE + (size_t)NCH * NLANE;
    float* deltaT = xr;                           // alias: xr dead after conv_tr
    float* y      = xr + (size_t)Bb * DI * Tt;    // alias: upper half of xr (row-major now)
    float* enc    = xn;                           // alias: xn dead after gemm3

    // weight splits (bf16 hi/lo, transposed to [n][k]):
    ushort_t* w_in_hi  = (ushort_t*)Pp;           // Pp written only in scanA (after gemm3)
    ushort_t* w_in_lo  = w_in_hi + (size_t)(2 * DI) * DM;
    ushort_t* w_out_hi = (ushort_t*)deltaT;       // written after scanC (deltaT dead)
    ushort_t* w_out_lo = w_out_hi + (size_t)DM * DI;

    // 0) split+transpose w_in (512,2048) -> [2048][512] bf16 hi/lo
    split_tr_kernel<<<dim3(2 * DI / 32, DM / 32), 256, 0, stream>>>(
        w_in, w_in_hi, w_in_lo, DM, 2 * DI);
    // 1) h0 = x @ w_proj + b_proj
    gemm64<1,0><<<dim3(DM / 64, BT / 64), 256, 0, stream>>>(
        x, NM, w_proj, b_proj, nullptr, h0, BT, DM, NM);
    // 2) xn = rmsnorm(h0) * rms_w
    rms_kernel<<<BT, 256, 0, stream>>>(h0, rms_w, xn);
    // 3) xr = xn @ w_in    (split-bf16 MFMA)
    gemm_mfma<128,128,0><<<dim3(2 * DI / 128, BT / 128), 256, 0, stream>>>(
        xn, DM, w_in_hi, w_in_lo, nullptr, xr, 2 * DI, DM);
    // 4) xpT = silu(causal_dwconv(xr[:, :DI]))^T ; resT = xr[:, DI:]^T
    conv_tr_kernel<<<dim3(DI / 64, Tt / 64, Bb), 256, 0, stream>>>(
        xr, conv_w, conv_b, xpT, resT);
    // 5) xdbl = xp @ w_xproj   (A read transposed)
    gemm_at<0><<<dim3((96 + 63) / 64, BT / 64), 256, 0, stream>>>(
        xpT, w_xprj, nullptr, xdbl, BT, 96, DI);
    // 6) deltaT = softplus(dt @ w_dt + b_dt)^T
    gemm64<2,1><<<dim3(DI / 64, BT / 64), 256, 0, stream>>>(
        xdbl, 96, w_dt, b_dt, nullptr, deltaT, BT, DI, DR);
    // 7) chunked selective scan (writes y row-major)
    scan_passA<<<Bb * (DI / 8) * NCH, 256, 0, stream>>>(
        deltaT, xdbl, xpT, A_log, hE, Pp);
    scan_passB<<<NLANE / 256, 256, 0, stream>>>(hE, Pp);
    scan_passC<<<Bb * (DI / 8) * NCH, 256, 0, stream>>>(
        deltaT, xdbl, xpT, resT, A_log, Dvec, hE, y);
    // 7b) split+transpose w_out (1024,512) -> [512][1024] bf16 hi/lo
    split_tr_kernel<<<dim3(DM / 32, DI / 32), 256, 0, stream>>>(
        w_out, w_out_hi, w_out_lo, DI, DM);
    // 8) enc = h0 + y @ w_out   (split-bf16 MFMA)
    gemm_mfma<64,64,3><<<dim3(DM / 64, BT / 64), 256, 0, stream>>>(
        y, DI, w_out_hi, w_out_lo, h0, enc, DM, DI);
    // 9) pooled = mean(enc, axis=-1)
    pool_kernel<<<BT / 4, 256, 0, stream>>>(enc, pooled);
    // 10) out = pooled @ w_cls + b_cls
    cls_kernel<<<(Bb * NC + 255) / 256, 256, 0, stream>>>(pooled, w_cls, b_cls, out);
}

// Round 6
// 365.080 us; speedup vs baseline: 1.4153x; 1.0942x over previous
//
#include <hip/hip_runtime.h>
#include <hip/hip_bf16.h>
#include <cstddef>

#define Bb 8
#define Tt 512
#define NM 128
#define DM 512
#define DI 1024
#define DS 32
#define DR 32
#define DC 4
#define NC 100
#define BT (Bb*Tt)     // 4096
#define NCH 8          // scan chunks
#define CL  64         // chunk length
#define NLANE (Bb*DI*DS)  // 262144

typedef unsigned short ushort_t;
typedef unsigned int uint_t;
typedef __attribute__((ext_vector_type(8))) short bf8;    // 8 bf16 in 4 VGPRs
typedef __attribute__((ext_vector_type(4))) float f4;

__device__ __forceinline__ float softplus_f(float x) {
    return fmaxf(x, 0.f) + log1pf(expf(-fabsf(x)));
}
__device__ __forceinline__ float silu_fast(float x) {
    return __fdividef(x, 1.f + __expf(-x));
}
__device__ __forceinline__ ushort_t bf16_rne(float x) {
    uint_t u = __float_as_uint(x);
    uint_t r = u + 0x7FFFu + ((u >> 16) & 1u);
    return (ushort_t)(r >> 16);
}
__device__ __forceinline__ float bf16_tof(ushort_t h) {
    return __uint_as_float(((uint_t)h) << 16);
}
// pack fp32 -> {hi bf16 in [31:16], lo bf16 in [15:0]}
__device__ __forceinline__ uint_t packf(float v) {
    ushort_t h = bf16_rne(v);
    ushort_t l = bf16_rne(v - bf16_tof(h));
    return ((uint_t)h << 16) | (uint_t)l;
}
// cross-lane: quad_perm DPP (VALU pipe) and ds_swizzle (DS pipe)
template<int CTRL>
__device__ __forceinline__ float qperm(float x) {
    return __int_as_float(__builtin_amdgcn_mov_dpp(__float_as_int(x), CTRL, 0xF, 0xF, true));
}
template<int PAT>
__device__ __forceinline__ float swz(float x) {
    return __int_as_float(__builtin_amdgcn_ds_swizzle(__float_as_int(x), PAT));
}

// ---------------- zero-init (xdbl + pooled region) ----------------------------
__global__ __launch_bounds__(256) void zero4_kernel(float4* __restrict__ p, int n4)
{
    const int i = blockIdx.x * 256 + threadIdx.x;
    if (i < n4) p[i] = make_float4(0.f, 0.f, 0.f, 0.f);
}

// ---- split fp32 (K,N) row-major into bf16 hi/lo, TRANSPOSED to (N,K) --------
__global__ __launch_bounds__(256) void split_tr_kernel(
    const float* __restrict__ src, ushort_t* __restrict__ hi,
    ushort_t* __restrict__ lo, int K, int N)
{
    __shared__ ushort_t th[32][34], tl[32][34];
    const int k0 = blockIdx.y * 32, n0 = blockIdx.x * 32;
    #pragma unroll
    for (int it = 0; it < 4; ++it) {
        const int idx = it * 256 + threadIdx.x;
        const int r = idx >> 5, c = idx & 31;
        const float v = src[(size_t)(k0 + r) * N + n0 + c];
        const ushort_t h = bf16_rne(v);
        th[c][r] = h;
        tl[c][r] = bf16_rne(v - bf16_tof(h));
    }
    __syncthreads();
    #pragma unroll
    for (int it = 0; it < 4; ++it) {
        const int idx = it * 256 + threadIdx.x;
        const int r = idx >> 5, c = idx & 31;
        hi[(size_t)(n0 + r) * K + k0 + c] = th[r][c];
        lo[(size_t)(n0 + r) * K + k0 + c] = tl[r][c];
    }
}

// ---- split-bf16 MFMA GEMM, A pre-packed {hi,lo} uint (M,K), B pre-split -----
// POOL=0: C[m*N+n] = acc. POOL=1: no C write; atomicAdd row-sums*pscale into pooled.
template<int BM, int BN, int POOL>
__global__ __launch_bounds__(256) void gemm_mfma_pk(
    const uint_t* __restrict__ Apk, int lda,
    const ushort_t* __restrict__ Bhi, const ushort_t* __restrict__ Blo,
    float* __restrict__ C, float* __restrict__ pooled, float pscale,
    int N, int K)
{
    constexpr int FM = BM / 32, FN = BN / 32;
    constexpr int AIT = BM * 32 / 1024;   // uint4 A loads/thread
    constexpr int BIT = BN * 32 / 2048;   // uint4 loads/thread per B plane
    __shared__ ushort_t sA[2][BM][40];
    __shared__ ushort_t sB[2][BN][40];
    const int tid = threadIdx.x;
    const int wid = tid >> 6, l = tid & 63, l15 = l & 15, g = l >> 4;
    const int wm = (wid >> 1) * (BM / 2), wn = (wid & 1) * (BN / 2);
    const int bm0 = blockIdx.y * BM, bn0 = blockIdx.x * BN;

    f4 acc[FM][FN] = {};
    uint4 aR[AIT], bRh[BIT], bRl[BIT];

    auto loadG = [&](int k0) {
        #pragma unroll
        for (int r = 0; r < AIT; ++r) {
            const int idx = r * 1024 + tid * 4;
            const int m = idx >> 5, k = idx & 31;
            aR[r] = *(const uint4*)(Apk + (size_t)(bm0 + m) * lda + k0 + k);
        }
        #pragma unroll
        for (int r = 0; r < BIT; ++r) {
            const int idx = r * 2048 + tid * 8;
            const int n = idx >> 5, k = idx & 31;
            const size_t o = (size_t)(bn0 + n) * K + k0 + k;
            bRh[r] = *(const uint4*)(Bhi + o);
            bRl[r] = *(const uint4*)(Blo + o);
        }
    };
    auto stoL = [&]() {
        #pragma unroll
        for (int r = 0; r < AIT; ++r) {
            const int idx = r * 1024 + tid * 4;
            const int m = idx >> 5, k = idx & 31;
            const uint_t u0 = aR[r].x, u1 = aR[r].y, u2 = aR[r].z, u3 = aR[r].w;
            uint2 hh, ll;
            hh.x = (u0 >> 16) | (u1 & 0xFFFF0000u);
            hh.y = (u2 >> 16) | (u3 & 0xFFFF0000u);
            ll.x = (u0 & 0xFFFFu) | (u1 << 16);
            ll.y = (u2 & 0xFFFFu) | (u3 << 16);
            *(uint2*)&sA[0][m][k] = hh;
            *(uint2*)&sA[1][m][k] = ll;
        }
        #pragma unroll
        for (int r = 0; r < BIT; ++r) {
            const int idx = r * 2048 + tid * 8;
            const int n = idx >> 5, k = idx & 31;
            *(uint4*)&sB[0][n][k] = bRh[r];
            *(uint4*)&sB[1][n][k] = bRl[r];
        }
    };

    loadG(0);
    for (int k0 = 0; k0 < K; k0 += 32) {
        stoL();
        __syncthreads();
        if (k0 + 32 < K) loadG(k0 + 32);
        bf8 ah[FM], al_[FM], bh[FN], bl_[FN];
        #pragma unroll
        for (int i = 0; i < FM; ++i) {
            ah[i]  = *(bf8*)&sA[0][wm + i * 16 + l15][g * 8];
            al_[i] = *(bf8*)&sA[1][wm + i * 16 + l15][g * 8];
        }
        #pragma unroll
        for (int j = 0; j < FN; ++j) {
            bh[j]  = *(bf8*)&sB[0][wn + j * 16 + l15][g * 8];
            bl_[j] = *(bf8*)&sB[1][wn + j * 16 + l15][g * 8];
        }
        #pragma unroll
        for (int i = 0; i < FM; ++i)
            #pragma unroll
            for (int j = 0; j < FN; ++j)
                acc[i][j] = __builtin_amdgcn_mfma_f32_16x16x32_bf16(ah[i], bh[j], acc[i][j], 0, 0, 0);
        #pragma unroll
        for (int i = 0; i < FM; ++i)
            #pragma unroll
            for (int j = 0; j < FN; ++j)
                acc[i][j] = __builtin_amdgcn_mfma_f32_16x16x32_bf16(al_[i], bh[j], acc[i][j], 0, 0, 0);
        #pragma unroll
        for (int i = 0; i < FM; ++i)
            #pragma unroll
            for (int j = 0; j < FN; ++j)
                acc[i][j] = __builtin_amdgcn_mfma_f32_16x16x32_bf16(ah[i], bl_[j], acc[i][j], 0, 0, 0);
        __syncthreads();
    }
    if (POOL == 0) {
        #pragma unroll
        for (int i = 0; i < FM; ++i)
            #pragma unroll
            for (int j = 0; j < FN; ++j)
                #pragma unroll
                for (int r = 0; r < 4; ++r) {
                    const int m = bm0 + wm + i * 16 + g * 4 + r;
                    const int n = bn0 + wn + j * 16 + l15;
                    C[(size_t)m * N + n] = acc[i][j][r];
                }
    } else {
        #pragma unroll
        for (int i = 0; i < FM; ++i)
            #pragma unroll
            for (int r = 0; r < 4; ++r) {
                float sum = acc[i][0][r];
                #pragma unroll
                for (int j = 1; j < FN; ++j) sum += acc[i][j][r];
                sum += __shfl_xor(sum, 1);
                sum += __shfl_xor(sum, 2);
                sum += __shfl_xor(sum, 4);
                sum += __shfl_xor(sum, 8);
                if (l15 == 0)
                    unsafeAtomicAdd(pooled + bm0 + wm + i * 16 + g * 4 + r, sum * pscale);
            }
    }
}

// ---------------- generic 64x64 tiled fp32 GEMM: C = epi(A@B) -----------------
// EPI: 1 +bias[n], 2 softplus(+bias[n]). TSTORE: 0 normal; 1 per-batch transposed.
template<int EPI, int TSTORE>
__global__ __launch_bounds__(256) void gemm64(
    const float* __restrict__ A, int lda,
    const float* __restrict__ B,
    const float* __restrict__ bias,
    float* __restrict__ C,
    int M, int N, int K)
{
    __shared__ float As[16][68];
    __shared__ float Bs[16][64];
    const int tid = threadIdx.x;
    const int bm = blockIdx.y * 64;
    const int bn = blockIdx.x * 64;
    const int tx = tid & 15;
    const int ty = tid >> 4;
    const int la_m = tid >> 2;
    const int la_k = (tid & 3) << 2;
    const int lb_k = tid >> 4;
    const int lb_n = (tid & 15) << 2;

    float acc[4][4] = {};
    for (int k0 = 0; k0 < K; k0 += 16) {
        float4 av = *(const float4*)(A + (size_t)(bm + la_m) * lda + k0 + la_k);
        As[la_k + 0][la_m] = av.x;
        As[la_k + 1][la_m] = av.y;
        As[la_k + 2][la_m] = av.z;
        As[la_k + 3][la_m] = av.w;
        const int gn = bn + lb_n;
        const float* bp = B + (size_t)(k0 + lb_k) * N + gn;
        float4 bv = *(const float4*)bp;
        *(float4*)&Bs[lb_k][lb_n] = bv;
        __syncthreads();
        #pragma unroll
        for (int k = 0; k < 16; ++k) {
            float4 a = *(const float4*)&As[k][ty << 2];
            float4 b = *(const float4*)&Bs[k][tx << 2];
            float ar[4] = {a.x, a.y, a.z, a.w};
            float br[4] = {b.x, b.y, b.z, b.w};
            #pragma unroll
            for (int i = 0; i < 4; ++i)
                #pragma unroll
                for (int j = 0; j < 4; ++j)
                    acc[i][j] = fmaf(ar[i], br[j], acc[i][j]);
        }
        __syncthreads();
    }
    if (TSTORE == 0) {
        #pragma unroll
        for (int i = 0; i < 4; ++i) {
            const int gm = bm + (ty << 2) + i;
            #pragma unroll
            for (int j = 0; j < 4; ++j) {
                const int gn = bn + (tx << 2) + j;
                float v = acc[i][j];
                if (EPI == 1) v += bias[gn];
                else if (EPI == 2) v = softplus_f(v + bias[gn]);
                C[(size_t)gm * N + gn] = v;
            }
        }
    } else {
        const int bq = bm >> 9;
        const int tt0 = (bm & (Tt - 1)) + (ty << 2);
        #pragma unroll
        for (int j = 0; j < 4; ++j) {
            const int gn = bn + (tx << 2) + j;
            float4 v;
            float* vv = (float*)&v;
            #pragma unroll
            for (int i = 0; i < 4; ++i) {
                float t = acc[i][j];
                if (EPI == 2) t = softplus_f(t + bias[gn]);
                vv[i] = t;
            }
            *(float4*)(C + ((size_t)bq * N + gn) * Tt + tt0) = v;
        }
    }
}

// --------- split-K GEMM, per-batch-transposed A, atomic accumulate ------------
template<int KS>
__global__ __launch_bounds__(256) void gemm_at_sk(
    const float* __restrict__ A_T,
    const float* __restrict__ B,
    float* __restrict__ C,
    int N, int K)
{
    __shared__ float As[16][68];
    __shared__ float Bs[16][64];
    const int tid = threadIdx.x;
    const int bm = blockIdx.y * 64;
    const int bn = blockIdx.x * 64;
    const int tx = tid & 15;
    const int ty = tid >> 4;
    const int lb_k = tid >> 4;
    const int lb_n = (tid & 15) << 2;
    const int bq = bm >> 9;
    const int tt0 = bm & (Tt - 1);
    const int kseg = K / KS;
    const int kbeg = blockIdx.z * kseg;

    float acc[4][4] = {};
    for (int k0 = kbeg; k0 < kbeg + kseg; k0 += 16) {
        float4 av = *(const float4*)(A_T + ((size_t)bq * K + k0 + lb_k) * Tt + tt0 + lb_n);
        *(float4*)&As[lb_k][lb_n] = av;
        const int gn = bn + lb_n;
        const float* bp = B + (size_t)(k0 + lb_k) * N + gn;
        float4 bv;
        if (gn + 3 < N) {
            bv = *(const float4*)bp;
        } else {
            bv.x = (gn + 0 < N) ? bp[0] : 0.f;
            bv.y = (gn + 1 < N) ? bp[1] : 0.f;
            bv.z = (gn + 2 < N) ? bp[2] : 0.f;
            bv.w = (gn + 3 < N) ? bp[3] : 0.f;
        }
        *(float4*)&Bs[lb_k][lb_n] = bv;
        __syncthreads();
        #pragma unroll
        for (int k = 0; k < 16; ++k) {
            float4 a = *(const float4*)&As[k][ty << 2];
            float4 b = *(const float4*)&Bs[k][tx << 2];
            float ar[4] = {a.x, a.y, a.z, a.w};
            float br[4] = {b.x, b.y, b.z, b.w};
            #pragma unroll
            for (int i = 0; i < 4; ++i)
                #pragma unroll
                for (int j = 0; j < 4; ++j)
                    acc[i][j] = fmaf(ar[i], br[j], acc[i][j]);
        }
        __syncthreads();
    }
    #pragma unroll
    for (int i = 0; i < 4; ++i) {
        const int gm = bm + (ty << 2) + i;
        #pragma unroll
        for (int j = 0; j < 4; ++j) {
            const int gn = bn + (tx << 2) + j;
            if (gn < N)
                unsafeAtomicAdd(&C[(size_t)gm * N + gn], acc[i][j]);
        }
    }
}

// ------- RMSNorm: writes packed hi/lo bf16 xn; adds h0 row-sums to pooled -----
__global__ __launch_bounds__(256) void rms_kernel(
    const float* __restrict__ h0, const float* __restrict__ w,
    uint_t* __restrict__ xn_pk, float* __restrict__ pooled)
{
    const int row = blockIdx.x;
    const float* p = h0 + (size_t)row * DM;
    const int tid = threadIdx.x;
    float v0 = p[tid], v1 = p[tid + 256];
    float ss = v0 * v0 + v1 * v1;
    float sm = v0 + v1;
    #pragma unroll
    for (int m = 32; m; m >>= 1) {
        ss += __shfl_xor(ss, m);
        sm += __shfl_xor(sm, m);
    }
    __shared__ float wss[4], wsm[4];
    if ((tid & 63) == 0) { wss[tid >> 6] = ss; wsm[tid >> 6] = sm; }
    __syncthreads();
    const float tot = wss[0] + wss[1] + wss[2] + wss[3];
    if (tid == 0)
        unsafeAtomicAdd(pooled + row, (wsm[0] + wsm[1] + wsm[2] + wsm[3]) * (1.0f / DM));
    const float scale = rsqrtf(tot * (1.0f / DM) + 1e-5f);
    xn_pk[(size_t)row * DM + tid]       = packf(v0 * scale * w[tid]);
    xn_pk[(size_t)row * DM + tid + 256] = packf(v1 * scale * w[tid + 256]);
}

// -------- causal depthwise conv (DC=4) + SiLU, outputs TRANSPOSED (b,di,t) ----
__global__ __launch_bounds__(256) void conv_tr_kernel(
    const float* __restrict__ xr, const float* __restrict__ cw,
    const float* __restrict__ cb, float* __restrict__ xpT, float* __restrict__ resT)
{
    __shared__ float tp[64][65];
    __shared__ float tr[64][65];
    const int di0 = blockIdx.x * 64;
    const int t0  = blockIdx.y * 64;
    const int b   = blockIdx.z;
    const int c  = threadIdx.x & 63;
    const int r4 = threadIdx.x >> 6;
    const int di = di0 + c;
    const float bias = cb[di];
    float w0 = cw[di * DC + 0], w1 = cw[di * DC + 1],
          w2 = cw[di * DC + 2], w3 = cw[di * DC + 3];
    #pragma unroll
    for (int rr = 0; rr < 64; rr += 4) {
        const int t = t0 + rr + r4;
        const int bt = b * Tt + t;
        float acc = bias;
        if (t >= 3) {
            acc = fmaf(w0, xr[(size_t)(bt - 3) * (2 * DI) + di], acc);
            acc = fmaf(w1, xr[(size_t)(bt - 2) * (2 * DI) + di], acc);
            acc = fmaf(w2, xr[(size_t)(bt - 1) * (2 * DI) + di], acc);
        } else {
            if (t >= 1) acc = fmaf(w2, xr[(size_t)(bt - 1) * (2 * DI) + di], acc);
            if (t >= 2) acc = fmaf(w1, xr[(size_t)(bt - 2) * (2 * DI) + di], acc);
        }
        acc = fmaf(w3, xr[(size_t)bt * (2 * DI) + di], acc);
        tp[rr + r4][c] = silu_fast(acc);
        tr[rr + r4][c] = xr[(size_t)bt * (2 * DI) + DI + di];
    }
    __syncthreads();
    #pragma unroll
    for (int dd = 0; dd < 64; dd += 4) {
        const int dw = dd + r4;
        const size_t o = ((size_t)b * DI + di0 + dw) * Tt + t0 + c;
        xpT[o]  = tp[c][dw];
        resT[o] = tr[c][dw];
    }
}

// ============= chunked selective scan ==========================================
// Pass A: per chunk from h=0: local h_end and decay product. 16 di / block.
__global__ __launch_bounds__(256) void scan_passA(
    const float* __restrict__ deltaT, const float* __restrict__ xdbl,
    const float* __restrict__ xpT, const float* __restrict__ A_log,
    float* __restrict__ hE, float* __restrict__ Pp)
{
    __shared__ float sB2[CL / 2][66];   // B[t][s] at [t>>1][2s + (t&1)]
    const int tid = threadIdx.x;
    const int g = tid >> 5;
    const int s = tid & 31;
    const int c = blockIdx.x & (NCH - 1);
    const int cg = blockIdx.x >> 3;
    const int b = cg >> 6;
    const int di0 = (cg & 63) << 4;
    {
        const float* src = xdbl + ((size_t)b * Tt + c * CL) * 96 + 32;
        #pragma unroll
        for (int it = 0; it < 2; ++it) {
            const int idx = it * 1024 + tid * 4;
            const int t = idx >> 5;
            const int col = idx & 31;
            float4 v = *(const float4*)(src + (size_t)t * 96 + col);
            const float vv[4] = {v.x, v.y, v.z, v.w};
            #pragma unroll
            for (int j = 0; j < 4; ++j)
                sB2[t >> 1][((col + j) << 1) | (t & 1)] = vv[j];
        }
    }
    __syncthreads();
    #pragma unroll 1
    for (int p = 0; p < 2; ++p) {
        const int di = di0 + p * 8 + g;
        const int ch = b * DI + di;
        const float Ads2 = -expf(A_log[di * DS + s]) * 1.44269504f;
        const float* dp = deltaT + (size_t)ch * Tt + c * CL;
        const float* up = xpT + (size_t)ch * Tt + c * CL;
        float h = 0.f, dts = 0.f;
        #pragma unroll
        for (int tq = 0; tq < 16; ++tq) {
            float4 d4 = *(const float4*)(dp + tq * 4);
            float4 u4 = *(const float4*)(up + tq * 4);
            const float2 b01 = *(const float2*)&sB2[tq * 2][2 * s];
            const float2 b23 = *(const float2*)&sB2[tq * 2 + 1][2 * s];
            const float dv[4] = {d4.x, d4.y, d4.z, d4.w};
            const float uv[4] = {u4.x, u4.y, u4.z, u4.w};
            const float Bv[4] = {b01.x, b01.y, b23.x, b23.y};
            #pragma unroll
            for (int q = 0; q < 4; ++q) {
                const float dA = __builtin_amdgcn_exp2f(dv[q] * Ads2);
                h = fmaf(dA, h, dv[q] * uv[q] * Bv[q]);
                dts += dv[q];
            }
        }
        const size_t lane = (size_t)c * NLANE + (size_t)ch * DS + s;
        hE[lane] = h;
        Pp[lane] = __builtin_amdgcn_exp2f(Ads2 * dts);
    }
}

// Pass B: carry propagation; hE[c][lane] is overwritten with h_start(c)
__global__ __launch_bounds__(256) void scan_passB(
    float* __restrict__ hE, const float* __restrict__ Pp)
{
    const int lane = blockIdx.x * 256 + threadIdx.x;
    float h = 0.f;
    #pragma unroll
    for (int c = 0; c < NCH; ++c) {
        const float he = hE[(size_t)c * NLANE + lane];
        const float p  = Pp[(size_t)c * NLANE + lane];
        hE[(size_t)c * NLANE + lane] = h;
        h = fmaf(p, h, he);
    }
}

// Pass C: recompute with correct h_start. 16 di/block, DPP-based reduction,
// writes y packed {hi,lo} bf16, row-major (BT, DI), full 64B lines.
__global__ __launch_bounds__(256) void scan_passC(
    const float* __restrict__ deltaT, const float* __restrict__ xdbl,
    const float* __restrict__ xpT, const float* __restrict__ resT,
    const float* __restrict__ A_log, const float* __restrict__ Dvec,
    const float* __restrict__ hE, uint_t* __restrict__ y_pk)
{
    __shared__ float sBC[CL][66];    // {B,C} interleaved: B at [t][2s], C at [t][2s+1]
    __shared__ float ylds[CL][17];
    const int tid = threadIdx.x;
    const int g = tid >> 5;
    const int l5 = tid & 31;
    const int s = ((l5 & 1) << 4) | (l5 >> 1);   // lane remap: s^16 <-> l^1 (quad DPP)
    const int c = blockIdx.x & (NCH - 1);
    const int cg = blockIdx.x >> 3;
    const int b = cg >> 6;
    const int di0 = (cg & 63) << 4;
    {
        const float* src = xdbl + ((size_t)b * Tt + c * CL) * 96 + 32;
        #pragma unroll
        for (int it = 0; it < 4; ++it) {
            const int t = (tid >> 4) + it * 16;
            const int col = (tid & 15) << 2;
            float4 v = *(const float4*)(src + (size_t)t * 96 + col);
            const float vv[4] = {v.x, v.y, v.z, v.w};
            #pragma unroll
            for (int j = 0; j < 4; ++j) {
                const int cc = col + j;
                sBC[t][((cc & 31) << 1) | (cc >> 5)] = vv[j];
            }
        }
    }
    __syncthreads();
    const bool s4b = (l5 & 1) != 0;    // s bit4
    const bool s0b = (l5 & 2) != 0;    // s bit0
    const bool s1b = (l5 & 4) != 0;    // s bit1
    const bool s2b = (l5 & 8) != 0;    // s bit2
    const bool s3b = (l5 & 16) != 0;   // s bit3
    #pragma unroll 1
    for (int p = 0; p < 2; ++p) {
        const int di = di0 + p * 8 + g;
        const int ch = b * DI + di;
        const float Ads2 = -expf(A_log[di * DS + s]) * 1.44269504f;
        const float Dv = Dvec[di];
        const float* dp = deltaT + (size_t)ch * Tt + c * CL;
        const float* up = xpT + (size_t)ch * Tt + c * CL;
        const float* rp = resT + (size_t)ch * Tt + c * CL;
        float h = hE[(size_t)c * NLANE + (size_t)ch * DS + s];
        #pragma unroll 1
        for (int t0 = 0; t0 < CL; t0 += 32) {
            float buf[16] = {};
            #pragma unroll
            for (int tq = 0; tq < 8; ++tq) {
                const int tb = t0 + tq * 4;
                float4 d4 = *(const float4*)(dp + tb);
                float4 u4 = *(const float4*)(up + tb);
                const float dv[4] = {d4.x, d4.y, d4.z, d4.w};
                const float uv[4] = {u4.x, u4.y, u4.z, u4.w};
                #pragma unroll
                for (int q = 0; q < 4; ++q) {
                    const int t  = tb + q;
                    const int tl = tq * 4 + q;
                    const float2 bc = *(const float2*)&sBC[t][2 * s];
                    const float dA = __builtin_amdgcn_exp2f(dv[q] * Ads2);
                    h = fmaf(dA, h, dv[q] * uv[q] * bc.x);
                    const float ps = h * bc.y;
                    const float pr = ps + qperm<0xB1>(ps);       // s^16 pair-sum, VALU
                    const bool keep = ((tl & 16) != 0) == s4b;
                    buf[tl & 15] = keep ? pr : buf[tl & 15];
                }
            }
            // transposed butterfly; stage order s^1 (quad DPP), s^2, s^4, s^8
            #pragma unroll
            for (int i = 0; i < 16; ++i) buf[i] += qperm<0x4E>(buf[i]);
            float r8[8];
            #pragma unroll
            for (int i = 0; i < 8; ++i) r8[i] = s0b ? buf[2 * i + 1] : buf[2 * i];
            #pragma unroll
            for (int i = 0; i < 8; ++i) r8[i] += swz<0x101F>(r8[i]);
            float w4[4];
            #pragma unroll
            for (int i = 0; i < 4; ++i) w4[i] = s1b ? r8[2 * i + 1] : r8[2 * i];
            #pragma unroll
            for (int i = 0; i < 4; ++i) w4[i] += swz<0x201F>(w4[i]);
            float v2[2];
            v2[0] = s2b ? w4[1] : w4[0];
            v2[1] = s2b ? w4[3] : w4[2];
            v2[0] += swz<0x401F>(v2[0]);
            v2[1] += swz<0x401F>(v2[1]);
            const float yv = s3b ? v2[1] : v2[0];
            const float uD = up[t0 + s];
            const float re = rp[t0 + s];
            ylds[t0 + s][p * 8 + g] = fmaf(uD, Dv, yv) * silu_fast(re);
        }
    }
    __syncthreads();
    const int row = tid >> 2;
    const int q4 = (tid & 3) << 2;
    uint4 o;
    o.x = packf(ylds[row][q4 + 0]);
    o.y = packf(ylds[row][q4 + 1]);
    o.z = packf(ylds[row][q4 + 2]);
    o.w = packf(ylds[row][q4 + 3]);
    *(uint4*)(y_pk + ((size_t)b * Tt + c * CL + row) * DI + di0 + q4) = o;
}

// ---------------- classifier ---------------------------------------------------
__global__ __launch_bounds__(256) void cls_kernel(
    const float* __restrict__ pooled, const float* __restrict__ w_cls,
    const float* __restrict__ b_cls, float* __restrict__ out)
{
    const int idx = blockIdx.x * 256 + threadIdx.x;
    if (idx >= Bb * NC) return;
    const int b = idx / NC, c = idx % NC;
    float acc = b_cls[c];
    for (int t = 0; t < DM; ++t)
        acc = fmaf(pooled[b * DM + t], w_cls[t * NC + c], acc);
    out[idx] = acc;
}

extern "C" void kernel_launch(void* const* d_in, const int* in_sizes, int n_in,
                              void* d_out, int out_size, void* d_ws, size_t ws_size,
                              hipStream_t stream) {
    const float* x      = (const float*)d_in[0];
    const float* w_proj = (const float*)d_in[1];
    const float* b_proj = (const float*)d_in[2];
    const float* rms_w  = (const float*)d_in[3];
    const float* w_in   = (const float*)d_in[4];
    const float* conv_w = (const float*)d_in[5];
    const float* conv_b = (const float*)d_in[6];
    const float* w_xprj = (const float*)d_in[7];
    const float* w_dt   = (const float*)d_in[8];
    const float* b_dt   = (const float*)d_in[9];
    const float* A_log  = (const float*)d_in[10];
    const float* Dvec   = (const float*)d_in[11];
    const float* w_out  = (const float*)d_in[12];
    const float* w_cls  = (const float*)d_in[13];
    const float* b_cls  = (const float*)d_in[14];
    float* out = (float*)d_out;

    float* ws = (float*)d_ws;
    float* h0     = ws;
    float* xn     = h0 + (size_t)BT * DM;          // holds xn_pk (uint)
    float* xr     = xn + (size_t)BT * DM;
    float* xpT    = xr + (size_t)BT * 2 * DI;
    float* resT   = xpT + (size_t)Bb * DI * Tt;
    float* xdbl   = resT + (size_t)Bb * DI * Tt;
    float* pooled = xdbl + (size_t)BT * 96;
    float* hE     = pooled + 4096;
    float* Pp     = hE + (size_t)NCH * NLANE;
    float* deltaT = xr;                            // alias: xr dead after conv_tr
    uint_t* y_pk  = (uint_t*)(xr + (size_t)Bb * DI * Tt);  // upper half of xr
    uint_t* xn_pk = (uint_t*)xn;

    // weight splits (bf16 hi/lo, transposed to [n][k]):
    ushort_t* w_in_hi  = (ushort_t*)Pp;            // Pp written only in passA (after gemm3)
    ushort_t* w_in_lo  = w_in_hi + (size_t)(2 * DI) * DM;
    ushort_t* w_out_hi = (ushort_t*)deltaT;        // written after passC (deltaT dead)
    ushort_t* w_out_lo = w_out_hi + (size_t)DM * DI;

    // 0) zero xdbl (split-K atomics) + pooled (atomic row sums) — contiguous
    zero4_kernel<<<(BT * 96 + 4096) / 1024, 256, 0, stream>>>(
        (float4*)xdbl, (BT * 96 + 4096) / 4);
    // 0b) split+transpose w_in (512,2048) -> [2048][512] bf16 hi/lo
    split_tr_kernel<<<dim3(2 * DI / 32, DM / 32), 256, 0, stream>>>(
        w_in, w_in_hi, w_in_lo, DM, 2 * DI);
    // 1) h0 = x @ w_proj + b_proj
    gemm64<1,0><<<dim3(DM / 64, BT / 64), 256, 0, stream>>>(
        x, NM, w_proj, b_proj, h0, BT, DM, NM);
    // 2) xn_pk = pack(rmsnorm(h0) * rms_w); pooled += rowsum(h0)/DM
    rms_kernel<<<BT, 256, 0, stream>>>(h0, rms_w, xn_pk, pooled);
    // 3) xr = xn @ w_in    (split-bf16 MFMA, packed A)
    gemm_mfma_pk<128,128,0><<<dim3(2 * DI / 128, BT / 128), 256, 0, stream>>>(
        xn_pk, DM, w_in_hi, w_in_lo, xr, nullptr, 0.f, 2 * DI, DM);
    // 4) xpT = silu(causal_dwconv(xr[:, :DI]))^T ; resT = xr[:, DI:]^T
    conv_tr_kernel<<<dim3(DI / 64, Tt / 64, Bb), 256, 0, stream>>>(
        xr, conv_w, conv_b, xpT, resT);
    // 5) xdbl += xp @ w_xproj   (split-K=4, atomic accumulate)
    gemm_at_sk<4><<<dim3(2, BT / 64, 4), 256, 0, stream>>>(
        xpT, w_xprj, xdbl, 96, DI);
    // 6) deltaT = softplus(dt @ w_dt + b_dt)^T
    gemm64<2,1><<<dim3(DI / 64, BT / 64), 256, 0, stream>>>(
        xdbl, 96, w_dt, b_dt, deltaT, BT, DI, DR);
    // 7) chunked selective scan
    scan_passA<<<Bb * (DI / 16) * NCH, 256, 0, stream>>>(
        deltaT, xdbl, xpT, A_log, hE, Pp);
    scan_passB<<<NLANE / 256, 256, 0, stream>>>(hE, Pp);
    scan_passC<<<Bb * (DI / 16) * NCH, 256, 0, stream>>>(
        deltaT, xdbl, xpT, resT, A_log, Dvec, hE, y_pk);
    // 7b) split+transpose w_out (1024,512) -> [512][1024] bf16 hi/lo
    split_tr_kernel<<<dim3(DM / 32, DI / 32), 256, 0, stream>>>(
        w_out, w_out_hi, w_out_lo, DI, DM);
    // 8) pooled += rowsum(y @ w_out)/DM   (MFMA + fused mean-pool, no C write)
    gemm_mfma_pk<64,64,1><<<dim3(DM / 64, BT / 64), 256, 0, stream>>>(
        y_pk, DI, w_out_hi, w_out_lo, nullptr, pooled, 1.0f / DM, DM, DI);
    // 9) out = pooled @ w_cls + b_cls
    cls_kernel<<<(Bb * NC + 255) / 256, 256, 0, stream>>>(pooled, w_cls, b_cls, out);
}

// Round 7
// 364.074 us; speedup vs baseline: 1.4192x; 1.0028x over previous
//
#include <hip/hip_runtime.h>
#include <hip/hip_bf16.h>
#include <cstddef>

#define Bb 8
#define Tt 512
#define NM 128
#define DM 512
#define DI 1024
#define DS 32
#define DR 32
#define DC 4
#define NC 100
#define BT (Bb*Tt)     // 4096
#define NCH 8          // scan chunks
#define CL  64         // chunk length
#define NLANE (Bb*DI*DS)  // 262144

typedef unsigned short ushort_t;
typedef unsigned int uint_t;
typedef __attribute__((ext_vector_type(8))) short bf8;    // 8 bf16 in 4 VGPRs
typedef __attribute__((ext_vector_type(4))) float f4;

__device__ __forceinline__ float softplus_f(float x) {
    return fmaxf(x, 0.f) + log1pf(expf(-fabsf(x)));
}
__device__ __forceinline__ float silu_fast(float x) {
    return __fdividef(x, 1.f + __expf(-x));
}
__device__ __forceinline__ ushort_t bf16_rne(float x) {
    uint_t u = __float_as_uint(x);
    uint_t r = u + 0x7FFFu + ((u >> 16) & 1u);
    return (ushort_t)(r >> 16);
}
__device__ __forceinline__ float bf16_tof(ushort_t h) {
    return __uint_as_float(((uint_t)h) << 16);
}
// pack fp32 -> {hi bf16 in [31:16], lo bf16 in [15:0]}
__device__ __forceinline__ uint_t packf(float v) {
    ushort_t h = bf16_rne(v);
    ushort_t l = bf16_rne(v - bf16_tof(h));
    return ((uint_t)h << 16) | (uint_t)l;
}
// cross-lane: quad_perm DPP (VALU pipe) and ds_swizzle (DS pipe)
template<int CTRL>
__device__ __forceinline__ float qperm(float x) {
    return __int_as_float(__builtin_amdgcn_mov_dpp(__float_as_int(x), CTRL, 0xF, 0xF, true));
}
template<int PAT>
__device__ __forceinline__ float swz(float x) {
    return __int_as_float(__builtin_amdgcn_ds_swizzle(__float_as_int(x), PAT));
}

// ---------------- zero-init (xdbl + pooled region) ----------------------------
__global__ __launch_bounds__(256) void zero4_kernel(float4* __restrict__ p, int n4)
{
    const int i = blockIdx.x * 256 + threadIdx.x;
    if (i < n4) p[i] = make_float4(0.f, 0.f, 0.f, 0.f);
}

// ---- split fp32 (K,N) row-major into bf16 hi/lo, TRANSPOSED to (N,K) --------
__global__ __launch_bounds__(256) void split_tr_kernel(
    const float* __restrict__ src, ushort_t* __restrict__ hi,
    ushort_t* __restrict__ lo, int K, int N)
{
    __shared__ ushort_t th[32][34], tl[32][34];
    const int k0 = blockIdx.y * 32, n0 = blockIdx.x * 32;
    #pragma unroll
    for (int it = 0; it < 4; ++it) {
        const int idx = it * 256 + threadIdx.x;
        const int r = idx >> 5, c = idx & 31;
        const float v = src[(size_t)(k0 + r) * N + n0 + c];
        const ushort_t h = bf16_rne(v);
        th[c][r] = h;
        tl[c][r] = bf16_rne(v - bf16_tof(h));
    }
    __syncthreads();
    #pragma unroll
    for (int it = 0; it < 4; ++it) {
        const int idx = it * 256 + threadIdx.x;
        const int r = idx >> 5, c = idx & 31;
        hi[(size_t)(n0 + r) * K + k0 + c] = th[r][c];
        lo[(size_t)(n0 + r) * K + k0 + c] = tl[r][c];
    }
}

// ---- split-bf16 MFMA GEMM, A pre-packed {hi,lo} uint (M,K), B pre-split -----
// POOL=0: C[m*N+n] = acc. POOL=1: no C write; atomicAdd row-sums*pscale into pooled.
template<int BM, int BN, int POOL>
__global__ __launch_bounds__(256) void gemm_mfma_pk(
    const uint_t* __restrict__ Apk, int lda,
    const ushort_t* __restrict__ Bhi, const ushort_t* __restrict__ Blo,
    float* __restrict__ C, float* __restrict__ pooled, float pscale,
    int N, int K)
{
    constexpr int FM = BM / 32, FN = BN / 32;
    constexpr int AIT = BM * 32 / 1024;   // uint4 A loads/thread
    constexpr int BIT = BN * 32 / 2048;   // uint4 loads/thread per B plane
    __shared__ ushort_t sA[2][BM][40];
    __shared__ ushort_t sB[2][BN][40];
    const int tid = threadIdx.x;
    const int wid = tid >> 6, l = tid & 63, l15 = l & 15, g = l >> 4;
    const int wm = (wid >> 1) * (BM / 2), wn = (wid & 1) * (BN / 2);
    const int bm0 = blockIdx.y * BM, bn0 = blockIdx.x * BN;

    f4 acc[FM][FN] = {};
    uint4 aR[AIT], bRh[BIT], bRl[BIT];

    auto loadG = [&](int k0) {
        #pragma unroll
        for (int r = 0; r < AIT; ++r) {
            const int idx = r * 1024 + tid * 4;
            const int m = idx >> 5, k = idx & 31;
            aR[r] = *(const uint4*)(Apk + (size_t)(bm0 + m) * lda + k0 + k);
        }
        #pragma unroll
        for (int r = 0; r < BIT; ++r) {
            const int idx = r * 2048 + tid * 8;
            const int n = idx >> 5, k = idx & 31;
            const size_t o = (size_t)(bn0 + n) * K + k0 + k;
            bRh[r] = *(const uint4*)(Bhi + o);
            bRl[r] = *(const uint4*)(Blo + o);
        }
    };
    auto stoL = [&]() {
        #pragma unroll
        for (int r = 0; r < AIT; ++r) {
            const int idx = r * 1024 + tid * 4;
            const int m = idx >> 5, k = idx & 31;
            const uint_t u0 = aR[r].x, u1 = aR[r].y, u2 = aR[r].z, u3 = aR[r].w;
            uint2 hh, ll;
            hh.x = (u0 >> 16) | (u1 & 0xFFFF0000u);
            hh.y = (u2 >> 16) | (u3 & 0xFFFF0000u);
            ll.x = (u0 & 0xFFFFu) | (u1 << 16);
            ll.y = (u2 & 0xFFFFu) | (u3 << 16);
            *(uint2*)&sA[0][m][k] = hh;
            *(uint2*)&sA[1][m][k] = ll;
        }
        #pragma unroll
        for (int r = 0; r < BIT; ++r) {
            const int idx = r * 2048 + tid * 8;
            const int n = idx >> 5, k = idx & 31;
            *(uint4*)&sB[0][n][k] = bRh[r];
            *(uint4*)&sB[1][n][k] = bRl[r];
        }
    };

    loadG(0);
    for (int k0 = 0; k0 < K; k0 += 32) {
        stoL();
        __syncthreads();
        if (k0 + 32 < K) loadG(k0 + 32);
        bf8 ah[FM], al_[FM], bh[FN], bl_[FN];
        #pragma unroll
        for (int i = 0; i < FM; ++i) {
            ah[i]  = *(bf8*)&sA[0][wm + i * 16 + l15][g * 8];
            al_[i] = *(bf8*)&sA[1][wm + i * 16 + l15][g * 8];
        }
        #pragma unroll
        for (int j = 0; j < FN; ++j) {
            bh[j]  = *(bf8*)&sB[0][wn + j * 16 + l15][g * 8];
            bl_[j] = *(bf8*)&sB[1][wn + j * 16 + l15][g * 8];
        }
        #pragma unroll
        for (int i = 0; i < FM; ++i)
            #pragma unroll
            for (int j = 0; j < FN; ++j)
                acc[i][j] = __builtin_amdgcn_mfma_f32_16x16x32_bf16(ah[i], bh[j], acc[i][j], 0, 0, 0);
        #pragma unroll
        for (int i = 0; i < FM; ++i)
            #pragma unroll
            for (int j = 0; j < FN; ++j)
                acc[i][j] = __builtin_amdgcn_mfma_f32_16x16x32_bf16(al_[i], bh[j], acc[i][j], 0, 0, 0);
        #pragma unroll
        for (int i = 0; i < FM; ++i)
            #pragma unroll
            for (int j = 0; j < FN; ++j)
                acc[i][j] = __builtin_amdgcn_mfma_f32_16x16x32_bf16(ah[i], bl_[j], acc[i][j], 0, 0, 0);
        __syncthreads();
    }
    if (POOL == 0) {
        #pragma unroll
        for (int i = 0; i < FM; ++i)
            #pragma unroll
            for (int j = 0; j < FN; ++j)
                #pragma unroll
                for (int r = 0; r < 4; ++r) {
                    const int m = bm0 + wm + i * 16 + g * 4 + r;
                    const int n = bn0 + wn + j * 16 + l15;
                    C[(size_t)m * N + n] = acc[i][j][r];
                }
    } else {
        #pragma unroll
        for (int i = 0; i < FM; ++i)
            #pragma unroll
            for (int r = 0; r < 4; ++r) {
                float sum = acc[i][0][r];
                #pragma unroll
                for (int j = 1; j < FN; ++j) sum += acc[i][j][r];
                sum += __shfl_xor(sum, 1);
                sum += __shfl_xor(sum, 2);
                sum += __shfl_xor(sum, 4);
                sum += __shfl_xor(sum, 8);
                if (l15 == 0)
                    unsafeAtomicAdd(pooled + bm0 + wm + i * 16 + g * 4 + r, sum * pscale);
            }
    }
}

// ---------------- generic 64x64 tiled fp32 GEMM: C = epi(A@B) -----------------
// EPI: 1 +bias[n], 2 softplus(+bias[n]). TSTORE: 0 normal; 1 per-batch transposed.
template<int EPI, int TSTORE>
__global__ __launch_bounds__(256) void gemm64(
    const float* __restrict__ A, int lda,
    const float* __restrict__ B,
    const float* __restrict__ bias,
    float* __restrict__ C,
    int M, int N, int K)
{
    __shared__ float As[16][68];
    __shared__ float Bs[16][64];
    const int tid = threadIdx.x;
    const int bm = blockIdx.y * 64;
    const int bn = blockIdx.x * 64;
    const int tx = tid & 15;
    const int ty = tid >> 4;
    const int la_m = tid >> 2;
    const int la_k = (tid & 3) << 2;
    const int lb_k = tid >> 4;
    const int lb_n = (tid & 15) << 2;

    float acc[4][4] = {};
    for (int k0 = 0; k0 < K; k0 += 16) {
        float4 av = *(const float4*)(A + (size_t)(bm + la_m) * lda + k0 + la_k);
        As[la_k + 0][la_m] = av.x;
        As[la_k + 1][la_m] = av.y;
        As[la_k + 2][la_m] = av.z;
        As[la_k + 3][la_m] = av.w;
        const int gn = bn + lb_n;
        const float* bp = B + (size_t)(k0 + lb_k) * N + gn;
        float4 bv = *(const float4*)bp;
        *(float4*)&Bs[lb_k][lb_n] = bv;
        __syncthreads();
        #pragma unroll
        for (int k = 0; k < 16; ++k) {
            float4 a = *(const float4*)&As[k][ty << 2];
            float4 b = *(const float4*)&Bs[k][tx << 2];
            float ar[4] = {a.x, a.y, a.z, a.w};
            float br[4] = {b.x, b.y, b.z, b.w};
            #pragma unroll
            for (int i = 0; i < 4; ++i)
                #pragma unroll
                for (int j = 0; j < 4; ++j)
                    acc[i][j] = fmaf(ar[i], br[j], acc[i][j]);
        }
        __syncthreads();
    }
    if (TSTORE == 0) {
        #pragma unroll
        for (int i = 0; i < 4; ++i) {
            const int gm = bm + (ty << 2) + i;
            #pragma unroll
            for (int j = 0; j < 4; ++j) {
                const int gn = bn + (tx << 2) + j;
                float v = acc[i][j];
                if (EPI == 1) v += bias[gn];
                else if (EPI == 2) v = softplus_f(v + bias[gn]);
                C[(size_t)gm * N + gn] = v;
            }
        }
    } else {
        const int bq = bm >> 9;
        const int tt0 = (bm & (Tt - 1)) + (ty << 2);
        #pragma unroll
        for (int j = 0; j < 4; ++j) {
            const int gn = bn + (tx << 2) + j;
            float4 v;
            float* vv = (float*)&v;
            #pragma unroll
            for (int i = 0; i < 4; ++i) {
                float t = acc[i][j];
                if (EPI == 2) t = softplus_f(t + bias[gn]);
                vv[i] = t;
            }
            *(float4*)(C + ((size_t)bq * N + gn) * Tt + tt0) = v;
        }
    }
}

// --------- split-K GEMM, per-batch-transposed A, atomic accumulate ------------
template<int KS>
__global__ __launch_bounds__(256) void gemm_at_sk(
    const float* __restrict__ A_T,
    const float* __restrict__ B,
    float* __restrict__ C,
    int N, int K)
{
    __shared__ float As[16][68];
    __shared__ float Bs[16][64];
    const int tid = threadIdx.x;
    const int bm = blockIdx.y * 64;
    const int bn = blockIdx.x * 64;
    const int tx = tid & 15;
    const int ty = tid >> 4;
    const int lb_k = tid >> 4;
    const int lb_n = (tid & 15) << 2;
    const int bq = bm >> 9;
    const int tt0 = bm & (Tt - 1);
    const int kseg = K / KS;
    const int kbeg = blockIdx.z * kseg;

    float acc[4][4] = {};
    for (int k0 = kbeg; k0 < kbeg + kseg; k0 += 16) {
        float4 av = *(const float4*)(A_T + ((size_t)bq * K + k0 + lb_k) * Tt + tt0 + lb_n);
        *(float4*)&As[lb_k][lb_n] = av;
        const int gn = bn + lb_n;
        const float* bp = B + (size_t)(k0 + lb_k) * N + gn;
        float4 bv;
        if (gn + 3 < N) {
            bv = *(const float4*)bp;
        } else {
            bv.x = (gn + 0 < N) ? bp[0] : 0.f;
            bv.y = (gn + 1 < N) ? bp[1] : 0.f;
            bv.z = (gn + 2 < N) ? bp[2] : 0.f;
            bv.w = (gn + 3 < N) ? bp[3] : 0.f;
        }
        *(float4*)&Bs[lb_k][lb_n] = bv;
        __syncthreads();
        #pragma unroll
        for (int k = 0; k < 16; ++k) {
            float4 a = *(const float4*)&As[k][ty << 2];
            float4 b = *(const float4*)&Bs[k][tx << 2];
            float ar[4] = {a.x, a.y, a.z, a.w};
            float br[4] = {b.x, b.y, b.z, b.w};
            #pragma unroll
            for (int i = 0; i < 4; ++i)
                #pragma unroll
                for (int j = 0; j < 4; ++j)
                    acc[i][j] = fmaf(ar[i], br[j], acc[i][j]);
        }
        __syncthreads();
    }
    #pragma unroll
    for (int i = 0; i < 4; ++i) {
        const int gm = bm + (ty << 2) + i;
        #pragma unroll
        for (int j = 0; j < 4; ++j) {
            const int gn = bn + (tx << 2) + j;
            if (gn < N)
                unsafeAtomicAdd(&C[(size_t)gm * N + gn], acc[i][j]);
        }
    }
}

// ------- RMSNorm: writes packed hi/lo bf16 xn; adds h0 row-sums to pooled -----
__global__ __launch_bounds__(256) void rms_kernel(
    const float* __restrict__ h0, const float* __restrict__ w,
    uint_t* __restrict__ xn_pk, float* __restrict__ pooled)
{
    const int row = blockIdx.x;
    const float* p = h0 + (size_t)row * DM;
    const int tid = threadIdx.x;
    float v0 = p[tid], v1 = p[tid + 256];
    float ss = v0 * v0 + v1 * v1;
    float sm = v0 + v1;
    #pragma unroll
    for (int m = 32; m; m >>= 1) {
        ss += __shfl_xor(ss, m);
        sm += __shfl_xor(sm, m);
    }
    __shared__ float wss[4], wsm[4];
    if ((tid & 63) == 0) { wss[tid >> 6] = ss; wsm[tid >> 6] = sm; }
    __syncthreads();
    const float tot = wss[0] + wss[1] + wss[2] + wss[3];
    if (tid == 0)
        unsafeAtomicAdd(pooled + row, (wsm[0] + wsm[1] + wsm[2] + wsm[3]) * (1.0f / DM));
    const float scale = rsqrtf(tot * (1.0f / DM) + 1e-5f);
    xn_pk[(size_t)row * DM + tid]       = packf(v0 * scale * w[tid]);
    xn_pk[(size_t)row * DM + tid + 256] = packf(v1 * scale * w[tid + 256]);
}

// -------- causal depthwise conv (DC=4) + SiLU, outputs TRANSPOSED (b,di,t) ----
__global__ __launch_bounds__(256) void conv_tr_kernel(
    const float* __restrict__ xr, const float* __restrict__ cw,
    const float* __restrict__ cb, float* __restrict__ xpT, float* __restrict__ resT)
{
    __shared__ float tp[64][65];
    __shared__ float tr[64][65];
    const int di0 = blockIdx.x * 64;
    const int t0  = blockIdx.y * 64;
    const int b   = blockIdx.z;
    const int c  = threadIdx.x & 63;
    const int r4 = threadIdx.x >> 6;
    const int di = di0 + c;
    const float bias = cb[di];
    float w0 = cw[di * DC + 0], w1 = cw[di * DC + 1],
          w2 = cw[di * DC + 2], w3 = cw[di * DC + 3];
    #pragma unroll
    for (int rr = 0; rr < 64; rr += 4) {
        const int t = t0 + rr + r4;
        const int bt = b * Tt + t;
        float acc = bias;
        if (t >= 3) {
            acc = fmaf(w0, xr[(size_t)(bt - 3) * (2 * DI) + di], acc);
            acc = fmaf(w1, xr[(size_t)(bt - 2) * (2 * DI) + di], acc);
            acc = fmaf(w2, xr[(size_t)(bt - 1) * (2 * DI) + di], acc);
        } else {
            if (t >= 1) acc = fmaf(w2, xr[(size_t)(bt - 1) * (2 * DI) + di], acc);
            if (t >= 2) acc = fmaf(w1, xr[(size_t)(bt - 2) * (2 * DI) + di], acc);
        }
        acc = fmaf(w3, xr[(size_t)bt * (2 * DI) + di], acc);
        tp[rr + r4][c] = silu_fast(acc);
        tr[rr + r4][c] = xr[(size_t)bt * (2 * DI) + DI + di];
    }
    __syncthreads();
    #pragma unroll
    for (int dd = 0; dd < 64; dd += 4) {
        const int dw = dd + r4;
        const size_t o = ((size_t)b * DI + di0 + dw) * Tt + t0 + c;
        xpT[o]  = tp[c][dw];
        resT[o] = tr[c][dw];
    }
}

// ============= chunked selective scan ==========================================
// Pass A: per chunk from h=0: local h_end and decay product. 16 di / block,
// two di-chains (diA, diB) interleaved per lane sharing one LDS B read.
__global__ __launch_bounds__(256) void scan_passA(
    const float* __restrict__ deltaT, const float* __restrict__ xdbl,
    const float* __restrict__ xpT, const float* __restrict__ A_log,
    float* __restrict__ hE, float* __restrict__ Pp)
{
    __shared__ float sB[CL][33];
    const int tid = threadIdx.x;
    const int g = tid >> 5;
    const int s = tid & 31;
    const int c = blockIdx.x & (NCH - 1);
    const int cg = blockIdx.x >> 3;
    const int b = cg >> 6;
    const int di0 = (cg & 63) << 4;
    {
        const float* src = xdbl + ((size_t)b * Tt + c * CL) * 96 + 32;
        #pragma unroll
        for (int it = 0; it < 2; ++it) {
            const int t = (tid >> 3) + it * 32;
            const int col = (tid & 7) << 2;
            float4 v = *(const float4*)(src + (size_t)t * 96 + col);
            sB[t][col + 0] = v.x;
            sB[t][col + 1] = v.y;
            sB[t][col + 2] = v.z;
            sB[t][col + 3] = v.w;
        }
    }
    __syncthreads();
    const int diA = di0 + g, diB = di0 + 8 + g;
    const int chA = b * DI + diA, chB = b * DI + diB;
    const float Ads2A = -expf(A_log[diA * DS + s]) * 1.44269504f;
    const float Ads2B = -expf(A_log[diB * DS + s]) * 1.44269504f;
    const float* dpA = deltaT + (size_t)chA * Tt + c * CL;
    const float* upA = xpT + (size_t)chA * Tt + c * CL;
    const float* dpB = deltaT + (size_t)chB * Tt + c * CL;
    const float* upB = xpT + (size_t)chB * Tt + c * CL;
    float hA = 0.f, dtsA = 0.f, hB = 0.f, dtsB = 0.f;
    #pragma unroll
    for (int tq = 0; tq < 16; ++tq) {
        float4 dA4 = *(const float4*)(dpA + tq * 4);
        float4 uA4 = *(const float4*)(upA + tq * 4);
        float4 dB4 = *(const float4*)(dpB + tq * 4);
        float4 uB4 = *(const float4*)(upB + tq * 4);
        const float dvA[4] = {dA4.x, dA4.y, dA4.z, dA4.w};
        const float uvA[4] = {uA4.x, uA4.y, uA4.z, uA4.w};
        const float dvB[4] = {dB4.x, dB4.y, dB4.z, dB4.w};
        const float uvB[4] = {uB4.x, uB4.y, uB4.z, uB4.w};
        #pragma unroll
        for (int q = 0; q < 4; ++q) {
            const float Bv = sB[tq * 4 + q][s];
            hA = fmaf(__builtin_amdgcn_exp2f(dvA[q] * Ads2A), hA, dvA[q] * uvA[q] * Bv);
            dtsA += dvA[q];
            hB = fmaf(__builtin_amdgcn_exp2f(dvB[q] * Ads2B), hB, dvB[q] * uvB[q] * Bv);
            dtsB += dvB[q];
        }
    }
    const size_t laneA = (size_t)c * NLANE + (size_t)chA * DS + s;
    const size_t laneB = (size_t)c * NLANE + (size_t)chB * DS + s;
    hE[laneA] = hA;
    Pp[laneA] = __builtin_amdgcn_exp2f(Ads2A * dtsA);
    hE[laneB] = hB;
    Pp[laneB] = __builtin_amdgcn_exp2f(Ads2B * dtsB);
}

// Pass B: carry propagation; hE[c][lane] is overwritten with h_start(c)
__global__ __launch_bounds__(256) void scan_passB(
    float* __restrict__ hE, const float* __restrict__ Pp)
{
    const int lane = blockIdx.x * 256 + threadIdx.x;
    float h = 0.f;
    #pragma unroll
    for (int c = 0; c < NCH; ++c) {
        const float he = hE[(size_t)c * NLANE + lane];
        const float p  = Pp[(size_t)c * NLANE + lane];
        hE[(size_t)c * NLANE + lane] = h;
        h = fmaf(p, h, he);
    }
}

// Pass C: recompute with correct h_start. 16 di/block, two interleaved
// di-chains sharing conflict-free LDS B/C reads; DPP butterfly reduction;
// writes y packed {hi,lo} bf16 row-major (BT, DI), full 64B lines.
__global__ __launch_bounds__(256) void scan_passC(
    const float* __restrict__ deltaT, const float* __restrict__ xdbl,
    const float* __restrict__ xpT, const float* __restrict__ resT,
    const float* __restrict__ A_log, const float* __restrict__ Dvec,
    const float* __restrict__ hE, uint_t* __restrict__ y_pk)
{
    __shared__ float sB[CL][33], sC[CL][33];
    __shared__ float ylds[CL][17];
    const int tid = threadIdx.x;
    const int g = tid >> 5;
    const int l5 = tid & 31;
    const int s = ((l5 & 1) << 4) | (l5 >> 1);   // lane remap: s^16 <-> l^1 (quad DPP)
    const int c = blockIdx.x & (NCH - 1);
    const int cg = blockIdx.x >> 3;
    const int b = cg >> 6;
    const int di0 = (cg & 63) << 4;
    {
        const float* src = xdbl + ((size_t)b * Tt + c * CL) * 96 + 32;
        #pragma unroll
        for (int it = 0; it < 4; ++it) {
            const int t = (tid >> 4) + it * 16;
            const int col = (tid & 15) << 2;
            float4 v = *(const float4*)(src + (size_t)t * 96 + col);
            const float vv[4] = {v.x, v.y, v.z, v.w};
            #pragma unroll
            for (int j = 0; j < 4; ++j) {
                const int cc = col + j;
                if (cc < 32) sB[t][cc] = vv[j];
                else         sC[t][cc - 32] = vv[j];
            }
        }
    }
    __syncthreads();
    const bool s4b = (l5 & 1) != 0;    // s bit4
    const bool s0b = (l5 & 2) != 0;    // s bit0
    const bool s1b = (l5 & 4) != 0;    // s bit1
    const bool s2b = (l5 & 8) != 0;    // s bit2
    const bool s3b = (l5 & 16) != 0;   // s bit3
    const int diA = di0 + g, diB = di0 + 8 + g;
    const int chA = b * DI + diA, chB = b * DI + diB;
    const float Ads2A = -expf(A_log[diA * DS + s]) * 1.44269504f;
    const float Ads2B = -expf(A_log[diB * DS + s]) * 1.44269504f;
    const float DvA = Dvec[diA], DvB = Dvec[diB];
    const float* dpA = deltaT + (size_t)chA * Tt + c * CL;
    const float* upA = xpT + (size_t)chA * Tt + c * CL;
    const float* rpA = resT + (size_t)chA * Tt + c * CL;
    const float* dpB = deltaT + (size_t)chB * Tt + c * CL;
    const float* upB = xpT + (size_t)chB * Tt + c * CL;
    const float* rpB = resT + (size_t)chB * Tt + c * CL;
    float hA = hE[(size_t)c * NLANE + (size_t)chA * DS + s];
    float hB = hE[(size_t)c * NLANE + (size_t)chB * DS + s];
    #pragma unroll 1
    for (int t0 = 0; t0 < CL; t0 += 32) {
        float bufA[16] = {}, bufB[16] = {};
        #pragma unroll
        for (int tq = 0; tq < 8; ++tq) {
            const int tb = t0 + tq * 4;
            float4 dA4 = *(const float4*)(dpA + tb);
            float4 uA4 = *(const float4*)(upA + tb);
            float4 dB4 = *(const float4*)(dpB + tb);
            float4 uB4 = *(const float4*)(upB + tb);
            const float dvA[4] = {dA4.x, dA4.y, dA4.z, dA4.w};
            const float uvA[4] = {uA4.x, uA4.y, uA4.z, uA4.w};
            const float dvB[4] = {dB4.x, dB4.y, dB4.z, dB4.w};
            const float uvB[4] = {uB4.x, uB4.y, uB4.z, uB4.w};
            #pragma unroll
            for (int q = 0; q < 4; ++q) {
                const int t  = tb + q;
                const int tl = tq * 4 + q;
                const float Bv = sB[t][s];
                const float Cv = sC[t][s];
                hA = fmaf(__builtin_amdgcn_exp2f(dvA[q] * Ads2A), hA, dvA[q] * uvA[q] * Bv);
                hB = fmaf(__builtin_amdgcn_exp2f(dvB[q] * Ads2B), hB, dvB[q] * uvB[q] * Bv);
                const float psA = hA * Cv;
                const float psB = hB * Cv;
                const float prA = psA + qperm<0xB1>(psA);      // s^16 pair-sum, VALU
                const float prB = psB + qperm<0xB1>(psB);
                const bool keep = ((tl & 16) != 0) == s4b;
                bufA[tl & 15] = keep ? prA : bufA[tl & 15];
                bufB[tl & 15] = keep ? prB : bufB[tl & 15];
            }
        }
        // transposed butterfly; stage order s^1 (quad DPP), s^2, s^4, s^8
        #pragma unroll
        for (int i = 0; i < 16; ++i) bufA[i] += qperm<0x4E>(bufA[i]);
        #pragma unroll
        for (int i = 0; i < 16; ++i) bufB[i] += qperm<0x4E>(bufB[i]);
        float rA[8], rB[8];
        #pragma unroll
        for (int i = 0; i < 8; ++i) {
            rA[i] = s0b ? bufA[2 * i + 1] : bufA[2 * i];
            rB[i] = s0b ? bufB[2 * i + 1] : bufB[2 * i];
        }
        #pragma unroll
        for (int i = 0; i < 8; ++i) { rA[i] += swz<0x101F>(rA[i]); rB[i] += swz<0x101F>(rB[i]); }
        float wA[4], wB[4];
        #pragma unroll
        for (int i = 0; i < 4; ++i) {
            wA[i] = s1b ? rA[2 * i + 1] : rA[2 * i];
            wB[i] = s1b ? rB[2 * i + 1] : rB[2 * i];
        }
        #pragma unroll
        for (int i = 0; i < 4; ++i) { wA[i] += swz<0x201F>(wA[i]); wB[i] += swz<0x201F>(wB[i]); }
        float vA[2], vB[2];
        vA[0] = s2b ? wA[1] : wA[0];
        vA[1] = s2b ? wA[3] : wA[2];
        vB[0] = s2b ? wB[1] : wB[0];
        vB[1] = s2b ? wB[3] : wB[2];
        vA[0] += swz<0x401F>(vA[0]);
        vA[1] += swz<0x401F>(vA[1]);
        vB[0] += swz<0x401F>(vB[0]);
        vB[1] += swz<0x401F>(vB[1]);
        const float yvA = s3b ? vA[1] : vA[0];
        const float yvB = s3b ? vB[1] : vB[0];
        ylds[t0 + s][g]     = fmaf(upA[t0 + s], DvA, yvA) * silu_fast(rpA[t0 + s]);
        ylds[t0 + s][8 + g] = fmaf(upB[t0 + s], DvB, yvB) * silu_fast(rpB[t0 + s]);
    }
    __syncthreads();
    const int row = tid >> 2;
    const int q4 = (tid & 3) << 2;
    uint4 o;
    o.x = packf(ylds[row][q4 + 0]);
    o.y = packf(ylds[row][q4 + 1]);
    o.z = packf(ylds[row][q4 + 2]);
    o.w = packf(ylds[row][q4 + 3]);
    *(uint4*)(y_pk + ((size_t)b * Tt + c * CL + row) * DI + di0 + q4) = o;
}

// ---------------- classifier ---------------------------------------------------
__global__ __launch_bounds__(256) void cls_kernel(
    const float* __restrict__ pooled, const float* __restrict__ w_cls,
    const float* __restrict__ b_cls, float* __restrict__ out)
{
    const int idx = blockIdx.x * 256 + threadIdx.x;
    if (idx >= Bb * NC) return;
    const int b = idx / NC, c = idx % NC;
    float acc = b_cls[c];
    for (int t = 0; t < DM; ++t)
        acc = fmaf(pooled[b * DM + t], w_cls[t * NC + c], acc);
    out[idx] = acc;
}

extern "C" void kernel_launch(void* const* d_in, const int* in_sizes, int n_in,
                              void* d_out, int out_size, void* d_ws, size_t ws_size,
                              hipStream_t stream) {
    const float* x      = (const float*)d_in[0];
    const float* w_proj = (const float*)d_in[1];
    const float* b_proj = (const float*)d_in[2];
    const float* rms_w  = (const float*)d_in[3];
    const float* w_in   = (const float*)d_in[4];
    const float* conv_w = (const float*)d_in[5];
    const float* conv_b = (const float*)d_in[6];
    const float* w_xprj = (const float*)d_in[7];
    const float* w_dt   = (const float*)d_in[8];
    const float* b_dt   = (const float*)d_in[9];
    const float* A_log  = (const float*)d_in[10];
    const float* Dvec   = (const float*)d_in[11];
    const float* w_out  = (const float*)d_in[12];
    const float* w_cls  = (const float*)d_in[13];
    const float* b_cls  = (const float*)d_in[14];
    float* out = (float*)d_out;

    float* ws = (float*)d_ws;
    float* h0     = ws;
    float* xn     = h0 + (size_t)BT * DM;          // holds xn_pk (uint)
    float* xr     = xn + (size_t)BT * DM;
    float* xpT    = xr + (size_t)BT * 2 * DI;
    float* resT   = xpT + (size_t)Bb * DI * Tt;
    float* xdbl   = resT + (size_t)Bb * DI * Tt;
    float* pooled = xdbl + (size_t)BT * 96;
    float* hE     = pooled + 4096;
    float* Pp     = hE + (size_t)NCH * NLANE;
    float* deltaT = xr;                            // alias: xr dead after conv_tr
    uint_t* y_pk  = (uint_t*)(xr + (size_t)Bb * DI * Tt);  // upper half of xr
    uint_t* xn_pk = (uint_t*)xn;

    // weight splits (bf16 hi/lo, transposed to [n][k]):
    ushort_t* w_in_hi  = (ushort_t*)Pp;            // Pp written only in passA (after gemm3)
    ushort_t* w_in_lo  = w_in_hi + (size_t)(2 * DI) * DM;
    ushort_t* w_out_hi = (ushort_t*)deltaT;        // written after passC (deltaT dead)
    ushort_t* w_out_lo = w_out_hi + (size_t)DM * DI;

    // 0) zero xdbl (split-K atomics) + pooled (atomic row sums) — contiguous
    zero4_kernel<<<(BT * 96 + 4096) / 1024, 256, 0, stream>>>(
        (float4*)xdbl, (BT * 96 + 4096) / 4);
    // 0b) split+transpose w_in (512,2048) -> [2048][512] bf16 hi/lo
    split_tr_kernel<<<dim3(2 * DI / 32, DM / 32), 256, 0, stream>>>(
        w_in, w_in_hi, w_in_lo, DM, 2 * DI);
    // 1) h0 = x @ w_proj + b_proj
    gemm64<1,0><<<dim3(DM / 64, BT / 64), 256, 0, stream>>>(
        x, NM, w_proj, b_proj, h0, BT, DM, NM);
    // 2) xn_pk = pack(rmsnorm(h0) * rms_w); pooled += rowsum(h0)/DM
    rms_kernel<<<BT, 256, 0, stream>>>(h0, rms_w, xn_pk, pooled);
    // 3) xr = xn @ w_in    (split-bf16 MFMA, packed A)
    gemm_mfma_pk<128,128,0><<<dim3(2 * DI / 128, BT / 128), 256, 0, stream>>>(
        xn_pk, DM, w_in_hi, w_in_lo, xr, nullptr, 0.f, 2 * DI, DM);
    // 4) xpT = silu(causal_dwconv(xr[:, :DI]))^T ; resT = xr[:, DI:]^T
    conv_tr_kernel<<<dim3(DI / 64, Tt / 64, Bb), 256, 0, stream>>>(
        xr, conv_w, conv_b, xpT, resT);
    // 5) xdbl += xp @ w_xproj   (split-K=4, atomic accumulate)
    gemm_at_sk<4><<<dim3(2, BT / 64, 4), 256, 0, stream>>>(
        xpT, w_xprj, xdbl, 96, DI);
    // 6) deltaT = softplus(dt @ w_dt + b_dt)^T
    gemm64<2,1><<<dim3(DI / 64, BT / 64), 256, 0, stream>>>(
        xdbl, 96, w_dt, b_dt, deltaT, BT, DI, DR);
    // 7) chunked selective scan
    scan_passA<<<Bb * (DI / 16) * NCH, 256, 0, stream>>>(
        deltaT, xdbl, xpT, A_log, hE, Pp);
    scan_passB<<<NLANE / 256, 256, 0, stream>>>(hE, Pp);
    scan_passC<<<Bb * (DI / 16) * NCH, 256, 0, stream>>>(
        deltaT, xdbl, xpT, resT, A_log, Dvec, hE, y_pk);
    // 7b) split+transpose w_out (1024,512) -> [512][1024] bf16 hi/lo
    split_tr_kernel<<<dim3(DM / 32, DI / 32), 256, 0, stream>>>(
        w_out, w_out_hi, w_out_lo, DI, DM);
    // 8) pooled += rowsum(y @ w_out)/DM   (MFMA + fused mean-pool, no C write)
    gemm_mfma_pk<64,64,1><<<dim3(DM / 64, BT / 64), 256, 0, stream>>>(
        y_pk, DI, w_out_hi, w_out_lo, nullptr, pooled, 1.0f / DM, DM, DI);
    // 9) out = pooled @ w_cls + b_cls
    cls_kernel<<<(Bb * NC + 255) / 256, 256, 0, stream>>>(pooled, w_cls, b_cls, out);
}

// Round 8
// 352.838 us; speedup vs baseline: 1.4644x; 1.0318x over previous
//
#include <hip/hip_runtime.h>
#include <hip/hip_bf16.h>
#include <cstddef>

#define Bb 8
#define Tt 512
#define NM 128
#define DM 512
#define DI 1024
#define DS 32
#define DR 32
#define DC 4
#define NC 100
#define BT (Bb*Tt)     // 4096
#define NCH 8          // scan chunks
#define CL  64         // chunk length
#define NLANE (Bb*DI*DS)  // 262144

typedef unsigned short ushort_t;
typedef unsigned int uint_t;
typedef __attribute__((ext_vector_type(8))) short bf8;    // 8 bf16 in 4 VGPRs
typedef __attribute__((ext_vector_type(4))) float f4;

__device__ __forceinline__ float softplus_f(float x) {
    return fmaxf(x, 0.f) + log1pf(expf(-fabsf(x)));
}
__device__ __forceinline__ float silu_fast(float x) {
    return __fdividef(x, 1.f + __expf(-x));
}
__device__ __forceinline__ ushort_t bf16_rne(float x) {
    uint_t u = __float_as_uint(x);
    uint_t r = u + 0x7FFFu + ((u >> 16) & 1u);
    return (ushort_t)(r >> 16);
}
__device__ __forceinline__ float bf16_tof(ushort_t h) {
    return __uint_as_float(((uint_t)h) << 16);
}
// pack fp32 -> {hi bf16 in [31:16], lo bf16 in [15:0]}
__device__ __forceinline__ uint_t packf(float v) {
    ushort_t h = bf16_rne(v);
    ushort_t l = bf16_rne(v - bf16_tof(h));
    return ((uint_t)h << 16) | (uint_t)l;
}
// cross-lane: quad_perm DPP (VALU pipe) and ds_swizzle (DS pipe)
template<int CTRL>
__device__ __forceinline__ float qperm(float x) {
    return __int_as_float(__builtin_amdgcn_mov_dpp(__float_as_int(x), CTRL, 0xF, 0xF, true));
}
template<int PAT>
__device__ __forceinline__ float swz(float x) {
    return __int_as_float(__builtin_amdgcn_ds_swizzle(__float_as_int(x), PAT));
}

// ---------------- zero-init (xdbl + pooled region) ----------------------------
__global__ __launch_bounds__(256) void zero4_kernel(float4* __restrict__ p, int n4)
{
    const int i = blockIdx.x * 256 + threadIdx.x;
    if (i < n4) p[i] = make_float4(0.f, 0.f, 0.f, 0.f);
}

// ---- split fp32 (K,N) row-major into bf16 hi/lo, TRANSPOSED to (N,K) --------
__global__ __launch_bounds__(256) void split_tr_kernel(
    const float* __restrict__ src, ushort_t* __restrict__ hi,
    ushort_t* __restrict__ lo, int K, int N)
{
    __shared__ ushort_t th[32][34], tl[32][34];
    const int k0 = blockIdx.y * 32, n0 = blockIdx.x * 32;
    #pragma unroll
    for (int it = 0; it < 4; ++it) {
        const int idx = it * 256 + threadIdx.x;
        const int r = idx >> 5, c = idx & 31;
        const float v = src[(size_t)(k0 + r) * N + n0 + c];
        const ushort_t h = bf16_rne(v);
        th[c][r] = h;
        tl[c][r] = bf16_rne(v - bf16_tof(h));
    }
    __syncthreads();
    #pragma unroll
    for (int it = 0; it < 4; ++it) {
        const int idx = it * 256 + threadIdx.x;
        const int r = idx >> 5, c = idx & 31;
        hi[(size_t)(n0 + r) * K + k0 + c] = th[r][c];
        lo[(size_t)(n0 + r) * K + k0 + c] = tl[r][c];
    }
}

// ---- split-bf16 MFMA GEMM, A pre-packed {hi,lo} uint (M,K), B pre-split -----
// POOL=0: C[m*N+n] = acc. POOL=1: no C write; atomicAdd row-sums*pscale into pooled.
template<int BM, int BN, int POOL>
__global__ __launch_bounds__(256) void gemm_mfma_pk(
    const uint_t* __restrict__ Apk, int lda,
    const ushort_t* __restrict__ Bhi, const ushort_t* __restrict__ Blo,
    float* __restrict__ C, float* __restrict__ pooled, float pscale,
    int N, int K)
{
    constexpr int FM = BM / 32, FN = BN / 32;
    constexpr int AIT = BM * 32 / 1024;   // uint4 A loads/thread
    constexpr int BIT = BN * 32 / 2048;   // uint4 loads/thread per B plane
    __shared__ ushort_t sA[2][BM][40];
    __shared__ ushort_t sB[2][BN][40];
    const int tid = threadIdx.x;
    const int wid = tid >> 6, l = tid & 63, l15 = l & 15, g = l >> 4;
    const int wm = (wid >> 1) * (BM / 2), wn = (wid & 1) * (BN / 2);
    const int bm0 = blockIdx.y * BM, bn0 = blockIdx.x * BN;

    f4 acc[FM][FN] = {};
    uint4 aR[AIT], bRh[BIT], bRl[BIT];

    auto loadG = [&](int k0) {
        #pragma unroll
        for (int r = 0; r < AIT; ++r) {
            const int idx = r * 1024 + tid * 4;
            const int m = idx >> 5, k = idx & 31;
            aR[r] = *(const uint4*)(Apk + (size_t)(bm0 + m) * lda + k0 + k);
        }
        #pragma unroll
        for (int r = 0; r < BIT; ++r) {
            const int idx = r * 2048 + tid * 8;
            const int n = idx >> 5, k = idx & 31;
            const size_t o = (size_t)(bn0 + n) * K + k0 + k;
            bRh[r] = *(const uint4*)(Bhi + o);
            bRl[r] = *(const uint4*)(Blo + o);
        }
    };
    auto stoL = [&]() {
        #pragma unroll
        for (int r = 0; r < AIT; ++r) {
            const int idx = r * 1024 + tid * 4;
            const int m = idx >> 5, k = idx & 31;
            const uint_t u0 = aR[r].x, u1 = aR[r].y, u2 = aR[r].z, u3 = aR[r].w;
            uint2 hh, ll;
            hh.x = (u0 >> 16) | (u1 & 0xFFFF0000u);
            hh.y = (u2 >> 16) | (u3 & 0xFFFF0000u);
            ll.x = (u0 & 0xFFFFu) | (u1 << 16);
            ll.y = (u2 & 0xFFFFu) | (u3 << 16);
            *(uint2*)&sA[0][m][k] = hh;
            *(uint2*)&sA[1][m][k] = ll;
        }
        #pragma unroll
        for (int r = 0; r < BIT; ++r) {
            const int idx = r * 2048 + tid * 8;
            const int n = idx >> 5, k = idx & 31;
            *(uint4*)&sB[0][n][k] = bRh[r];
            *(uint4*)&sB[1][n][k] = bRl[r];
        }
    };

    loadG(0);
    for (int k0 = 0; k0 < K; k0 += 32) {
        stoL();
        __syncthreads();
        if (k0 + 32 < K) loadG(k0 + 32);
        bf8 ah[FM], al_[FM], bh[FN], bl_[FN];
        #pragma unroll
        for (int i = 0; i < FM; ++i) {
            ah[i]  = *(bf8*)&sA[0][wm + i * 16 + l15][g * 8];
            al_[i] = *(bf8*)&sA[1][wm + i * 16 + l15][g * 8];
        }
        #pragma unroll
        for (int j = 0; j < FN; ++j) {
            bh[j]  = *(bf8*)&sB[0][wn + j * 16 + l15][g * 8];
            bl_[j] = *(bf8*)&sB[1][wn + j * 16 + l15][g * 8];
        }
        #pragma unroll
        for (int i = 0; i < FM; ++i)
            #pragma unroll
            for (int j = 0; j < FN; ++j)
                acc[i][j] = __builtin_amdgcn_mfma_f32_16x16x32_bf16(ah[i], bh[j], acc[i][j], 0, 0, 0);
        #pragma unroll
        for (int i = 0; i < FM; ++i)
            #pragma unroll
            for (int j = 0; j < FN; ++j)
                acc[i][j] = __builtin_amdgcn_mfma_f32_16x16x32_bf16(al_[i], bh[j], acc[i][j], 0, 0, 0);
        #pragma unroll
        for (int i = 0; i < FM; ++i)
            #pragma unroll
            for (int j = 0; j < FN; ++j)
                acc[i][j] = __builtin_amdgcn_mfma_f32_16x16x32_bf16(ah[i], bl_[j], acc[i][j], 0, 0, 0);
        __syncthreads();
    }
    if (POOL == 0) {
        #pragma unroll
        for (int i = 0; i < FM; ++i)
            #pragma unroll
            for (int j = 0; j < FN; ++j)
                #pragma unroll
                for (int r = 0; r < 4; ++r) {
                    const int m = bm0 + wm + i * 16 + g * 4 + r;
                    const int n = bn0 + wn + j * 16 + l15;
                    C[(size_t)m * N + n] = acc[i][j][r];
                }
    } else {
        #pragma unroll
        for (int i = 0; i < FM; ++i)
            #pragma unroll
            for (int r = 0; r < 4; ++r) {
                float sum = acc[i][0][r];
                #pragma unroll
                for (int j = 1; j < FN; ++j) sum += acc[i][j][r];
                sum += __shfl_xor(sum, 1);
                sum += __shfl_xor(sum, 2);
                sum += __shfl_xor(sum, 4);
                sum += __shfl_xor(sum, 8);
                if (l15 == 0)
                    unsafeAtomicAdd(pooled + bm0 + wm + i * 16 + g * 4 + r, sum * pscale);
            }
    }
}

// ---------------- generic 64x64 tiled fp32 GEMM: C = epi(A@B) -----------------
// EPI: 1 +bias[n], 2 softplus(+bias[n]). TSTORE: 0 normal; 1 per-batch transposed.
template<int EPI, int TSTORE>
__global__ __launch_bounds__(256) void gemm64(
    const float* __restrict__ A, int lda,
    const float* __restrict__ B,
    const float* __restrict__ bias,
    float* __restrict__ C,
    int M, int N, int K)
{
    __shared__ float As[16][68];
    __shared__ float Bs[16][64];
    const int tid = threadIdx.x;
    const int bm = blockIdx.y * 64;
    const int bn = blockIdx.x * 64;
    const int tx = tid & 15;
    const int ty = tid >> 4;
    const int la_m = tid >> 2;
    const int la_k = (tid & 3) << 2;
    const int lb_k = tid >> 4;
    const int lb_n = (tid & 15) << 2;

    float acc[4][4] = {};
    for (int k0 = 0; k0 < K; k0 += 16) {
        float4 av = *(const float4*)(A + (size_t)(bm + la_m) * lda + k0 + la_k);
        As[la_k + 0][la_m] = av.x;
        As[la_k + 1][la_m] = av.y;
        As[la_k + 2][la_m] = av.z;
        As[la_k + 3][la_m] = av.w;
        const int gn = bn + lb_n;
        const float* bp = B + (size_t)(k0 + lb_k) * N + gn;
        float4 bv = *(const float4*)bp;
        *(float4*)&Bs[lb_k][lb_n] = bv;
        __syncthreads();
        #pragma unroll
        for (int k = 0; k < 16; ++k) {
            float4 a = *(const float4*)&As[k][ty << 2];
            float4 b = *(const float4*)&Bs[k][tx << 2];
            float ar[4] = {a.x, a.y, a.z, a.w};
            float br[4] = {b.x, b.y, b.z, b.w};
            #pragma unroll
            for (int i = 0; i < 4; ++i)
                #pragma unroll
                for (int j = 0; j < 4; ++j)
                    acc[i][j] = fmaf(ar[i], br[j], acc[i][j]);
        }
        __syncthreads();
    }
    if (TSTORE == 0) {
        #pragma unroll
        for (int i = 0; i < 4; ++i) {
            const int gm = bm + (ty << 2) + i;
            #pragma unroll
            for (int j = 0; j < 4; ++j) {
                const int gn = bn + (tx << 2) + j;
                float v = acc[i][j];
                if (EPI == 1) v += bias[gn];
                else if (EPI == 2) v = softplus_f(v + bias[gn]);
                C[(size_t)gm * N + gn] = v;
            }
        }
    } else {
        const int bq = bm >> 9;
        const int tt0 = (bm & (Tt - 1)) + (ty << 2);
        #pragma unroll
        for (int j = 0; j < 4; ++j) {
            const int gn = bn + (tx << 2) + j;
            float4 v;
            float* vv = (float*)&v;
            #pragma unroll
            for (int i = 0; i < 4; ++i) {
                float t = acc[i][j];
                if (EPI == 2) t = softplus_f(t + bias[gn]);
                vv[i] = t;
            }
            *(float4*)(C + ((size_t)bq * N + gn) * Tt + tt0) = v;
        }
    }
}

// --------- split-K GEMM, per-batch-transposed A, atomic accumulate ------------
template<int KS>
__global__ __launch_bounds__(256) void gemm_at_sk(
    const float* __restrict__ A_T,
    const float* __restrict__ B,
    float* __restrict__ C,
    int N, int K)
{
    __shared__ float As[16][68];
    __shared__ float Bs[16][64];
    const int tid = threadIdx.x;
    const int bm = blockIdx.y * 64;
    const int bn = blockIdx.x * 64;
    const int tx = tid & 15;
    const int ty = tid >> 4;
    const int lb_k = tid >> 4;
    const int lb_n = (tid & 15) << 2;
    const int bq = bm >> 9;
    const int tt0 = bm & (Tt - 1);
    const int kseg = K / KS;
    const int kbeg = blockIdx.z * kseg;

    float acc[4][4] = {};
    for (int k0 = kbeg; k0 < kbeg + kseg; k0 += 16) {
        float4 av = *(const float4*)(A_T + ((size_t)bq * K + k0 + lb_k) * Tt + tt0 + lb_n);
        *(float4*)&As[lb_k][lb_n] = av;
        const int gn = bn + lb_n;
        const float* bp = B + (size_t)(k0 + lb_k) * N + gn;
        float4 bv;
        if (gn + 3 < N) {
            bv = *(const float4*)bp;
        } else {
            bv.x = (gn + 0 < N) ? bp[0] : 0.f;
            bv.y = (gn + 1 < N) ? bp[1] : 0.f;
            bv.z = (gn + 2 < N) ? bp[2] : 0.f;
            bv.w = (gn + 3 < N) ? bp[3] : 0.f;
        }
        *(float4*)&Bs[lb_k][lb_n] = bv;
        __syncthreads();
        #pragma unroll
        for (int k = 0; k < 16; ++k) {
            float4 a = *(const float4*)&As[k][ty << 2];
            float4 b = *(const float4*)&Bs[k][tx << 2];
            float ar[4] = {a.x, a.y, a.z, a.w};
            float br[4] = {b.x, b.y, b.z, b.w};
            #pragma unroll
            for (int i = 0; i < 4; ++i)
                #pragma unroll
                for (int j = 0; j < 4; ++j)
                    acc[i][j] = fmaf(ar[i], br[j], acc[i][j]);
        }
        __syncthreads();
    }
    #pragma unroll
    for (int i = 0; i < 4; ++i) {
        const int gm = bm + (ty << 2) + i;
        #pragma unroll
        for (int j = 0; j < 4; ++j) {
            const int gn = bn + (tx << 2) + j;
            if (gn < N)
                unsafeAtomicAdd(&C[(size_t)gm * N + gn], acc[i][j]);
        }
    }
}

// ------- RMSNorm: writes packed hi/lo bf16 xn; adds h0 row-sums to pooled -----
__global__ __launch_bounds__(256) void rms_kernel(
    const float* __restrict__ h0, const float* __restrict__ w,
    uint_t* __restrict__ xn_pk, float* __restrict__ pooled)
{
    const int row = blockIdx.x;
    const float* p = h0 + (size_t)row * DM;
    const int tid = threadIdx.x;
    float v0 = p[tid], v1 = p[tid + 256];
    float ss = v0 * v0 + v1 * v1;
    float sm = v0 + v1;
    #pragma unroll
    for (int m = 32; m; m >>= 1) {
        ss += __shfl_xor(ss, m);
        sm += __shfl_xor(sm, m);
    }
    __shared__ float wss[4], wsm[4];
    if ((tid & 63) == 0) { wss[tid >> 6] = ss; wsm[tid >> 6] = sm; }
    __syncthreads();
    const float tot = wss[0] + wss[1] + wss[2] + wss[3];
    if (tid == 0)
        unsafeAtomicAdd(pooled + row, (wsm[0] + wsm[1] + wsm[2] + wsm[3]) * (1.0f / DM));
    const float scale = rsqrtf(tot * (1.0f / DM) + 1e-5f);
    xn_pk[(size_t)row * DM + tid]       = packf(v0 * scale * w[tid]);
    xn_pk[(size_t)row * DM + tid + 256] = packf(v1 * scale * w[tid + 256]);
}

// -------- causal depthwise conv (DC=4) + SiLU, outputs TRANSPOSED (b,di,t) ----
__global__ __launch_bounds__(256) void conv_tr_kernel(
    const float* __restrict__ xr, const float* __restrict__ cw,
    const float* __restrict__ cb, float* __restrict__ xpT, float* __restrict__ resT)
{
    __shared__ float tp[64][65];
    __shared__ float tr[64][65];
    const int di0 = blockIdx.x * 64;
    const int t0  = blockIdx.y * 64;
    const int b   = blockIdx.z;
    const int c  = threadIdx.x & 63;
    const int r4 = threadIdx.x >> 6;
    const int di = di0 + c;
    const float bias = cb[di];
    float w0 = cw[di * DC + 0], w1 = cw[di * DC + 1],
          w2 = cw[di * DC + 2], w3 = cw[di * DC + 3];
    #pragma unroll
    for (int rr = 0; rr < 64; rr += 4) {
        const int t = t0 + rr + r4;
        const int bt = b * Tt + t;
        float acc = bias;
        if (t >= 3) {
            acc = fmaf(w0, xr[(size_t)(bt - 3) * (2 * DI) + di], acc);
            acc = fmaf(w1, xr[(size_t)(bt - 2) * (2 * DI) + di], acc);
            acc = fmaf(w2, xr[(size_t)(bt - 1) * (2 * DI) + di], acc);
        } else {
            if (t >= 1) acc = fmaf(w2, xr[(size_t)(bt - 1) * (2 * DI) + di], acc);
            if (t >= 2) acc = fmaf(w1, xr[(size_t)(bt - 2) * (2 * DI) + di], acc);
        }
        acc = fmaf(w3, xr[(size_t)bt * (2 * DI) + di], acc);
        tp[rr + r4][c] = silu_fast(acc);
        tr[rr + r4][c] = xr[(size_t)bt * (2 * DI) + DI + di];
    }
    __syncthreads();
    #pragma unroll
    for (int dd = 0; dd < 64; dd += 4) {
        const int dw = dd + r4;
        const size_t o = ((size_t)b * DI + di0 + dw) * Tt + t0 + c;
        xpT[o]  = tp[c][dw];
        resT[o] = tr[c][dw];
    }
}

// ============= chunked selective scan ==========================================
// Pass A: per chunk from h=0: local h_end and decay product. 16 di / block,
// two di-chains per lane; all inner-loop operands staged in LDS.
__global__ __launch_bounds__(256) void scan_passA(
    const float* __restrict__ deltaT, const float* __restrict__ xdbl,
    const float* __restrict__ xpT, const float* __restrict__ A_log,
    float* __restrict__ hE, float* __restrict__ Pp)
{
    __shared__ float sBT[DS][CL + 1];   // B transposed: [s][t]
    __shared__ float sD[16][CL];
    __shared__ float sU[16][CL];
    const int tid = threadIdx.x;
    const int g = tid >> 5;
    const int s = tid & 31;
    const int c = blockIdx.x & (NCH - 1);
    const int cg = blockIdx.x >> 3;
    const int b = cg >> 6;
    const int di0 = (cg & 63) << 4;
    // stage: d,u (one float4/thread each) + B transposed
    {
        const int dl = tid >> 4;             // 0..15
        const int t4 = (tid & 15) << 2;      // 0..60
        const size_t rb = ((size_t)(b * DI + di0 + dl)) * Tt + c * CL + t4;
        *(float4*)&sD[dl][t4] = *(const float4*)(deltaT + rb);
        *(float4*)&sU[dl][t4] = *(const float4*)(xpT + rb);
        const float* src = xdbl + ((size_t)b * Tt + c * CL) * 96 + 32;
        #pragma unroll
        for (int it = 0; it < 2; ++it) {
            const int t = (tid >> 3) + it * 32;
            const int col = (tid & 7) << 2;
            float4 v = *(const float4*)(src + (size_t)t * 96 + col);
            sBT[col + 0][t] = v.x;
            sBT[col + 1][t] = v.y;
            sBT[col + 2][t] = v.z;
            sBT[col + 3][t] = v.w;
        }
    }
    __syncthreads();
    const int diA = di0 + g, diB = di0 + 8 + g;
    const float Ads2A = -expf(A_log[diA * DS + s]) * 1.44269504f;
    const float Ads2B = -expf(A_log[diB * DS + s]) * 1.44269504f;
    float hA = 0.f, dtsA = 0.f, hB = 0.f, dtsB = 0.f;
    #pragma unroll
    for (int tq = 0; tq < 16; ++tq) {
        const float4 bv4 = *(const float4*)&sBT[s][tq * 4];
        const float4 dA4 = *(const float4*)&sD[g][tq * 4];
        const float4 uA4 = *(const float4*)&sU[g][tq * 4];
        const float4 dB4 = *(const float4*)&sD[8 + g][tq * 4];
        const float4 uB4 = *(const float4*)&sU[8 + g][tq * 4];
        const float Bv[4] = {bv4.x, bv4.y, bv4.z, bv4.w};
        const float dvA[4] = {dA4.x, dA4.y, dA4.z, dA4.w};
        const float uvA[4] = {uA4.x, uA4.y, uA4.z, uA4.w};
        const float dvB[4] = {dB4.x, dB4.y, dB4.z, dB4.w};
        const float uvB[4] = {uB4.x, uB4.y, uB4.z, uB4.w};
        #pragma unroll
        for (int q = 0; q < 4; ++q) {
            hA = fmaf(__builtin_amdgcn_exp2f(dvA[q] * Ads2A), hA, dvA[q] * uvA[q] * Bv[q]);
            dtsA += dvA[q];
            hB = fmaf(__builtin_amdgcn_exp2f(dvB[q] * Ads2B), hB, dvB[q] * uvB[q] * Bv[q]);
            dtsB += dvB[q];
        }
    }
    const size_t laneA = (size_t)c * NLANE + (size_t)(b * DI + diA) * DS + s;
    const size_t laneB = (size_t)c * NLANE + (size_t)(b * DI + diB) * DS + s;
    hE[laneA] = hA;
    Pp[laneA] = __builtin_amdgcn_exp2f(Ads2A * dtsA);
    hE[laneB] = hB;
    Pp[laneB] = __builtin_amdgcn_exp2f(Ads2B * dtsB);
}

// Pass B: carry propagation; hE[c][lane] is overwritten with h_start(c)
__global__ __launch_bounds__(256) void scan_passB(
    float* __restrict__ hE, const float* __restrict__ Pp)
{
    const int lane = blockIdx.x * 256 + threadIdx.x;
    float h = 0.f;
    #pragma unroll
    for (int c = 0; c < NCH; ++c) {
        const float he = hE[(size_t)c * NLANE + lane];
        const float p  = Pp[(size_t)c * NLANE + lane];
        hE[(size_t)c * NLANE + lane] = h;
        h = fmaf(p, h, he);
    }
}

// Pass C: recompute with correct h_start. 16 di/block, two chains/lane,
// all inner-loop operands in LDS (B/C transposed per-lane rows, d/u broadcast
// rows), DPP butterfly reduce; writes y packed {hi,lo} bf16 row-major.
__global__ __launch_bounds__(256) void scan_passC(
    const float* __restrict__ deltaT, const float* __restrict__ xdbl,
    const float* __restrict__ xpT, const float* __restrict__ resT,
    const float* __restrict__ A_log, const float* __restrict__ Dvec,
    const float* __restrict__ hE, uint_t* __restrict__ y_pk)
{
    __shared__ float sBT[DS][CL + 1];   // [s][t]
    __shared__ float sCT[DS][CL + 1];
    __shared__ float sD[16][CL];
    __shared__ float sU[16][CL];
    __shared__ float ylds[CL][17];
    const int tid = threadIdx.x;
    const int g = tid >> 5;
    const int l5 = tid & 31;
    const int s = ((l5 & 1) << 4) | (l5 >> 1);   // lane remap: s^16 <-> l^1 (quad DPP)
    const int c = blockIdx.x & (NCH - 1);
    const int cg = blockIdx.x >> 3;
    const int b = cg >> 6;
    const int di0 = (cg & 63) << 4;
    {
        const int dl = tid >> 4;
        const int t4 = (tid & 15) << 2;
        const size_t rb = ((size_t)(b * DI + di0 + dl)) * Tt + c * CL + t4;
        *(float4*)&sD[dl][t4] = *(const float4*)(deltaT + rb);
        *(float4*)&sU[dl][t4] = *(const float4*)(xpT + rb);
        const float* src = xdbl + ((size_t)b * Tt + c * CL) * 96 + 32;
        #pragma unroll
        for (int it = 0; it < 4; ++it) {
            const int t = (tid >> 4) + it * 16;
            const int col = (tid & 15) << 2;
            float4 v = *(const float4*)(src + (size_t)t * 96 + col);
            const float vv[4] = {v.x, v.y, v.z, v.w};
            #pragma unroll
            for (int j = 0; j < 4; ++j) {
                const int cc = col + j;
                if (cc < 32) sBT[cc][t] = vv[j];
                else         sCT[cc - 32][t] = vv[j];
            }
        }
    }
    __syncthreads();
    const bool s4b = (l5 & 1) != 0;    // s bit4
    const bool s0b = (l5 & 2) != 0;    // s bit0
    const bool s1b = (l5 & 4) != 0;    // s bit1
    const bool s2b = (l5 & 8) != 0;    // s bit2
    const bool s3b = (l5 & 16) != 0;   // s bit3
    const int diA = di0 + g, diB = di0 + 8 + g;
    const int chA = b * DI + diA, chB = b * DI + diB;
    const float Ads2A = -expf(A_log[diA * DS + s]) * 1.44269504f;
    const float Ads2B = -expf(A_log[diB * DS + s]) * 1.44269504f;
    const float DvA = Dvec[diA], DvB = Dvec[diB];
    const float* rpA = resT + (size_t)chA * Tt + c * CL;
    const float* rpB = resT + (size_t)chB * Tt + c * CL;
    float hA = hE[(size_t)c * NLANE + (size_t)chA * DS + s];
    float hB = hE[(size_t)c * NLANE + (size_t)chB * DS + s];
    #pragma unroll 1
    for (int t0 = 0; t0 < CL; t0 += 32) {
        float bufA[16] = {}, bufB[16] = {};
        #pragma unroll
        for (int tq = 0; tq < 8; ++tq) {
            const int tb = t0 + tq * 4;
            const float4 bv4 = *(const float4*)&sBT[s][tb];
            const float4 cv4 = *(const float4*)&sCT[s][tb];
            const float4 dA4 = *(const float4*)&sD[g][tb];
            const float4 uA4 = *(const float4*)&sU[g][tb];
            const float4 dB4 = *(const float4*)&sD[8 + g][tb];
            const float4 uB4 = *(const float4*)&sU[8 + g][tb];
            const float Bvv[4] = {bv4.x, bv4.y, bv4.z, bv4.w};
            const float Cvv[4] = {cv4.x, cv4.y, cv4.z, cv4.w};
            const float dvA[4] = {dA4.x, dA4.y, dA4.z, dA4.w};
            const float uvA[4] = {uA4.x, uA4.y, uA4.z, uA4.w};
            const float dvB[4] = {dB4.x, dB4.y, dB4.z, dB4.w};
            const float uvB[4] = {uB4.x, uB4.y, uB4.z, uB4.w};
            #pragma unroll
            for (int q = 0; q < 4; ++q) {
                const int tl = tq * 4 + q;
                hA = fmaf(__builtin_amdgcn_exp2f(dvA[q] * Ads2A), hA, dvA[q] * uvA[q] * Bvv[q]);
                hB = fmaf(__builtin_amdgcn_exp2f(dvB[q] * Ads2B), hB, dvB[q] * uvB[q] * Bvv[q]);
                const float psA = hA * Cvv[q];
                const float psB = hB * Cvv[q];
                const float prA = psA + qperm<0xB1>(psA);      // s^16 pair-sum, VALU
                const float prB = psB + qperm<0xB1>(psB);
                const bool keep = ((tl & 16) != 0) == s4b;
                bufA[tl & 15] = keep ? prA : bufA[tl & 15];
                bufB[tl & 15] = keep ? prB : bufB[tl & 15];
            }
        }
        // transposed butterfly; stage order s^1 (quad DPP), s^2, s^4, s^8
        #pragma unroll
        for (int i = 0; i < 16; ++i) bufA[i] += qperm<0x4E>(bufA[i]);
        #pragma unroll
        for (int i = 0; i < 16; ++i) bufB[i] += qperm<0x4E>(bufB[i]);
        float rA[8], rB[8];
        #pragma unroll
        for (int i = 0; i < 8; ++i) {
            rA[i] = s0b ? bufA[2 * i + 1] : bufA[2 * i];
            rB[i] = s0b ? bufB[2 * i + 1] : bufB[2 * i];
        }
        #pragma unroll
        for (int i = 0; i < 8; ++i) { rA[i] += swz<0x101F>(rA[i]); rB[i] += swz<0x101F>(rB[i]); }
        float wA[4], wB[4];
        #pragma unroll
        for (int i = 0; i < 4; ++i) {
            wA[i] = s1b ? rA[2 * i + 1] : rA[2 * i];
            wB[i] = s1b ? rB[2 * i + 1] : rB[2 * i];
        }
        #pragma unroll
        for (int i = 0; i < 4; ++i) { wA[i] += swz<0x201F>(wA[i]); wB[i] += swz<0x201F>(wB[i]); }
        float vA[2], vB[2];
        vA[0] = s2b ? wA[1] : wA[0];
        vA[1] = s2b ? wA[3] : wA[2];
        vB[0] = s2b ? wB[1] : wB[0];
        vB[1] = s2b ? wB[3] : wB[2];
        vA[0] += swz<0x401F>(vA[0]);
        vA[1] += swz<0x401F>(vA[1]);
        vB[0] += swz<0x401F>(vB[0]);
        vB[1] += swz<0x401F>(vB[1]);
        const float yvA = s3b ? vA[1] : vA[0];
        const float yvB = s3b ? vB[1] : vB[0];
        ylds[t0 + s][g]     = fmaf(sU[g][t0 + s], DvA, yvA) * silu_fast(rpA[t0 + s]);
        ylds[t0 + s][8 + g] = fmaf(sU[8 + g][t0 + s], DvB, yvB) * silu_fast(rpB[t0 + s]);
    }
    __syncthreads();
    const int row = tid >> 2;
    const int q4 = (tid & 3) << 2;
    uint4 o;
    o.x = packf(ylds[row][q4 + 0]);
    o.y = packf(ylds[row][q4 + 1]);
    o.z = packf(ylds[row][q4 + 2]);
    o.w = packf(ylds[row][q4 + 3]);
    *(uint4*)(y_pk + ((size_t)b * Tt + c * CL + row) * DI + di0 + q4) = o;
}

// ---------------- classifier ---------------------------------------------------
__global__ __launch_bounds__(256) void cls_kernel(
    const float* __restrict__ pooled, const float* __restrict__ w_cls,
    const float* __restrict__ b_cls, float* __restrict__ out)
{
    const int idx = blockIdx.x * 256 + threadIdx.x;
    if (idx >= Bb * NC) return;
    const int b = idx / NC, c = idx % NC;
    float acc = b_cls[c];
    for (int t = 0; t < DM; ++t)
        acc = fmaf(pooled[b * DM + t], w_cls[t * NC + c], acc);
    out[idx] = acc;
}

extern "C" void kernel_launch(void* const* d_in, const int* in_sizes, int n_in,
                              void* d_out, int out_size, void* d_ws, size_t ws_size,
                              hipStream_t stream) {
    const float* x      = (const float*)d_in[0];
    const float* w_proj = (const float*)d_in[1];
    const float* b_proj = (const float*)d_in[2];
    const float* rms_w  = (const float*)d_in[3];
    const float* w_in   = (const float*)d_in[4];
    const float* conv_w = (const float*)d_in[5];
    const float* conv_b = (const float*)d_in[6];
    const float* w_xprj = (const float*)d_in[7];
    const float* w_dt   = (const float*)d_in[8];
    const float* b_dt   = (const float*)d_in[9];
    const float* A_log  = (const float*)d_in[10];
    const float* Dvec   = (const float*)d_in[11];
    const float* w_out  = (const float*)d_in[12];
    const float* w_cls  = (const float*)d_in[13];
    const float* b_cls  = (const float*)d_in[14];
    float* out = (float*)d_out;

    float* ws = (float*)d_ws;
    float* h0     = ws;
    float* xn     = h0 + (size_t)BT * DM;          // holds xn_pk (uint)
    float* xr     = xn + (size_t)BT * DM;
    float* xpT    = xr + (size_t)BT * 2 * DI;
    float* resT   = xpT + (size_t)Bb * DI * Tt;
    float* xdbl   = resT + (size_t)Bb * DI * Tt;
    float* pooled = xdbl + (size_t)BT * 96;
    float* hE     = pooled + 4096;
    float* Pp     = hE + (size_t)NCH * NLANE;
    float* deltaT = xr;                            // alias: xr dead after conv_tr
    uint_t* y_pk  = (uint_t*)(xr + (size_t)Bb * DI * Tt);  // upper half of xr
    uint_t* xn_pk = (uint_t*)xn;

    // weight splits (bf16 hi/lo, transposed to [n][k]):
    ushort_t* w_in_hi  = (ushort_t*)Pp;            // Pp written only in passA (after gemm3)
    ushort_t* w_in_lo  = w_in_hi + (size_t)(2 * DI) * DM;
    ushort_t* w_out_hi = (ushort_t*)deltaT;        // written after passC (deltaT dead)
    ushort_t* w_out_lo = w_out_hi + (size_t)DM * DI;

    // 0) zero xdbl (split-K atomics) + pooled (atomic row sums) — contiguous
    zero4_kernel<<<(BT * 96 + 4096) / 1024, 256, 0, stream>>>(
        (float4*)xdbl, (BT * 96 + 4096) / 4);
    // 0b) split+transpose w_in (512,2048) -> [2048][512] bf16 hi/lo
    split_tr_kernel<<<dim3(2 * DI / 32, DM / 32), 256, 0, stream>>>(
        w_in, w_in_hi, w_in_lo, DM, 2 * DI);
    // 1) h0 = x @ w_proj + b_proj
    gemm64<1,0><<<dim3(DM / 64, BT / 64), 256, 0, stream>>>(
        x, NM, w_proj, b_proj, h0, BT, DM, NM);
    // 2) xn_pk = pack(rmsnorm(h0) * rms_w); pooled += rowsum(h0)/DM
    rms_kernel<<<BT, 256, 0, stream>>>(h0, rms_w, xn_pk, pooled);
    // 3) xr = xn @ w_in    (split-bf16 MFMA, packed A)
    gemm_mfma_pk<128,128,0><<<dim3(2 * DI / 128, BT / 128), 256, 0, stream>>>(
        xn_pk, DM, w_in_hi, w_in_lo, xr, nullptr, 0.f, 2 * DI, DM);
    // 4) xpT = silu(causal_dwconv(xr[:, :DI]))^T ; resT = xr[:, DI:]^T
    conv_tr_kernel<<<dim3(DI / 64, Tt / 64, Bb), 256, 0, stream>>>(
        xr, conv_w, conv_b, xpT, resT);
    // 5) xdbl += xp @ w_xproj   (split-K=4, atomic accumulate)
    gemm_at_sk<4><<<dim3(2, BT / 64, 4), 256, 0, stream>>>(
        xpT, w_xprj, xdbl, 96, DI);
    // 6) deltaT = softplus(dt @ w_dt + b_dt)^T
    gemm64<2,1><<<dim3(DI / 64, BT / 64), 256, 0, stream>>>(
        xdbl, 96, w_dt, b_dt, deltaT, BT, DI, DR);
    // 7) chunked selective scan
    scan_passA<<<Bb * (DI / 16) * NCH, 256, 0, stream>>>(
        deltaT, xdbl, xpT, A_log, hE, Pp);
    scan_passB<<<NLANE / 256, 256, 0, stream>>>(hE, Pp);
    scan_passC<<<Bb * (DI / 16) * NCH, 256, 0, stream>>>(
        deltaT, xdbl, xpT, resT, A_log, Dvec, hE, y_pk);
    // 7b) split+transpose w_out (1024,512) -> [512][1024] bf16 hi/lo
    split_tr_kernel<<<dim3(DM / 32, DI / 32), 256, 0, stream>>>(
        w_out, w_out_hi, w_out_lo, DI, DM);
    // 8) pooled += rowsum(y @ w_out)/DM   (MFMA + fused mean-pool, no C write)
    gemm_mfma_pk<64,64,1><<<dim3(DM / 64, BT / 64), 256, 0, stream>>>(
        y_pk, DI, w_out_hi, w_out_lo, nullptr, pooled, 1.0f / DM, DM, DI);
    // 9) out = pooled @ w_cls + b_cls
    cls_kernel<<<(Bb * NC + 255) / 256, 256, 0, stream>>>(pooled, w_cls, b_cls, out);
}

// Round 9
// 327.315 us; speedup vs baseline: 1.5786x; 1.0780x over previous
//
#include <hip/hip_runtime.h>
#include <hip/hip_bf16.h>
#include <cstddef>

#define Bb 8
#define Tt 512
#define NM 128
#define DM 512
#define DI 1024
#define DS 32
#define DR 32
#define DC 4
#define NC 100
#define BT (Bb*Tt)     // 4096
#define NCH 8          // scan chunks
#define CL  64         // chunk length

typedef unsigned short ushort_t;
typedef unsigned int uint_t;
typedef __attribute__((ext_vector_type(8))) short bf8;    // 8 bf16 in 4 VGPRs
typedef __attribute__((ext_vector_type(4))) float f4;

__device__ __forceinline__ float softplus_f(float x) {
    return fmaxf(x, 0.f) + log1pf(expf(-fabsf(x)));
}
__device__ __forceinline__ float silu_fast(float x) {
    return __fdividef(x, 1.f + __expf(-x));
}
__device__ __forceinline__ ushort_t bf16_rne(float x) {
    uint_t u = __float_as_uint(x);
    uint_t r = u + 0x7FFFu + ((u >> 16) & 1u);
    return (ushort_t)(r >> 16);
}
__device__ __forceinline__ float bf16_tof(ushort_t h) {
    return __uint_as_float(((uint_t)h) << 16);
}
// pack fp32 -> {hi bf16 in [31:16], lo bf16 in [15:0]}
__device__ __forceinline__ uint_t packf(float v) {
    ushort_t h = bf16_rne(v);
    ushort_t l = bf16_rne(v - bf16_tof(h));
    return ((uint_t)h << 16) | (uint_t)l;
}
// cross-lane: quad_perm DPP (VALU pipe) and ds_swizzle (DS pipe)
template<int CTRL>
__device__ __forceinline__ float qperm(float x) {
    return __int_as_float(__builtin_amdgcn_mov_dpp(__float_as_int(x), CTRL, 0xF, 0xF, true));
}
template<int PAT>
__device__ __forceinline__ float swz(float x) {
    return __int_as_float(__builtin_amdgcn_ds_swizzle(__float_as_int(x), PAT));
}

// ---------------- zero-init (xdbl + pooled region) ----------------------------
__global__ __launch_bounds__(256) void zero4_kernel(float4* __restrict__ p, int n4)
{
    const int i = blockIdx.x * 256 + threadIdx.x;
    if (i < n4) p[i] = make_float4(0.f, 0.f, 0.f, 0.f);
}

// ---- split fp32 (K,N) row-major into bf16 hi/lo, TRANSPOSED to (N,K) --------
__global__ __launch_bounds__(256) void split_tr_kernel(
    const float* __restrict__ src, ushort_t* __restrict__ hi,
    ushort_t* __restrict__ lo, int K, int N)
{
    __shared__ ushort_t th[32][34], tl[32][34];
    const int k0 = blockIdx.y * 32, n0 = blockIdx.x * 32;
    #pragma unroll
    for (int it = 0; it < 4; ++it) {
        const int idx = it * 256 + threadIdx.x;
        const int r = idx >> 5, c = idx & 31;
        const float v = src[(size_t)(k0 + r) * N + n0 + c];
        const ushort_t h = bf16_rne(v);
        th[c][r] = h;
        tl[c][r] = bf16_rne(v - bf16_tof(h));
    }
    __syncthreads();
    #pragma unroll
    for (int it = 0; it < 4; ++it) {
        const int idx = it * 256 + threadIdx.x;
        const int r = idx >> 5, c = idx & 31;
        hi[(size_t)(n0 + r) * K + k0 + c] = th[r][c];
        lo[(size_t)(n0 + r) * K + k0 + c] = tl[r][c];
    }
}

// ---- split-bf16 MFMA GEMM, A pre-packed {hi,lo} uint (M,K), B pre-split -----
// POOL=0: C[m*N+n] = acc. POOL=1: no C write; atomicAdd row-sums*pscale into pooled.
template<int BM, int BN, int POOL>
__global__ __launch_bounds__(256) void gemm_mfma_pk(
    const uint_t* __restrict__ Apk, int lda,
    const ushort_t* __restrict__ Bhi, const ushort_t* __restrict__ Blo,
    float* __restrict__ C, float* __restrict__ pooled, float pscale,
    int N, int K)
{
    constexpr int FM = BM / 32, FN = BN / 32;
    constexpr int AIT = BM * 32 / 1024;   // uint4 A loads/thread
    constexpr int BIT = BN * 32 / 2048;   // uint4 loads/thread per B plane
    __shared__ ushort_t sA[2][BM][40];
    __shared__ ushort_t sB[2][BN][40];
    const int tid = threadIdx.x;
    const int wid = tid >> 6, l = tid & 63, l15 = l & 15, g = l >> 4;
    const int wm = (wid >> 1) * (BM / 2), wn = (wid & 1) * (BN / 2);
    const int bm0 = blockIdx.y * BM, bn0 = blockIdx.x * BN;

    f4 acc[FM][FN] = {};
    uint4 aR[AIT], bRh[BIT], bRl[BIT];

    auto loadG = [&](int k0) {
        #pragma unroll
        for (int r = 0; r < AIT; ++r) {
            const int idx = r * 1024 + tid * 4;
            const int m = idx >> 5, k = idx & 31;
            aR[r] = *(const uint4*)(Apk + (size_t)(bm0 + m) * lda + k0 + k);
        }
        #pragma unroll
        for (int r = 0; r < BIT; ++r) {
            const int idx = r * 2048 + tid * 8;
            const int n = idx >> 5, k = idx & 31;
            const size_t o = (size_t)(bn0 + n) * K + k0 + k;
            bRh[r] = *(const uint4*)(Bhi + o);
            bRl[r] = *(const uint4*)(Blo + o);
        }
    };
    auto stoL = [&]() {
        #pragma unroll
        for (int r = 0; r < AIT; ++r) {
            const int idx = r * 1024 + tid * 4;
            const int m = idx >> 5, k = idx & 31;
            const uint_t u0 = aR[r].x, u1 = aR[r].y, u2 = aR[r].z, u3 = aR[r].w;
            uint2 hh, ll;
            hh.x = (u0 >> 16) | (u1 & 0xFFFF0000u);
            hh.y = (u2 >> 16) | (u3 & 0xFFFF0000u);
            ll.x = (u0 & 0xFFFFu) | (u1 << 16);
            ll.y = (u2 & 0xFFFFu) | (u3 << 16);
            *(uint2*)&sA[0][m][k] = hh;
            *(uint2*)&sA[1][m][k] = ll;
        }
        #pragma unroll
        for (int r = 0; r < BIT; ++r) {
            const int idx = r * 2048 + tid * 8;
            const int n = idx >> 5, k = idx & 31;
            *(uint4*)&sB[0][n][k] = bRh[r];
            *(uint4*)&sB[1][n][k] = bRl[r];
        }
    };

    loadG(0);
    for (int k0 = 0; k0 < K; k0 += 32) {
        stoL();
        __syncthreads();
        if (k0 + 32 < K) loadG(k0 + 32);
        bf8 ah[FM], al_[FM], bh[FN], bl_[FN];
        #pragma unroll
        for (int i = 0; i < FM; ++i) {
            ah[i]  = *(bf8*)&sA[0][wm + i * 16 + l15][g * 8];
            al_[i] = *(bf8*)&sA[1][wm + i * 16 + l15][g * 8];
        }
        #pragma unroll
        for (int j = 0; j < FN; ++j) {
            bh[j]  = *(bf8*)&sB[0][wn + j * 16 + l15][g * 8];
            bl_[j] = *(bf8*)&sB[1][wn + j * 16 + l15][g * 8];
        }
        #pragma unroll
        for (int i = 0; i < FM; ++i)
            #pragma unroll
            for (int j = 0; j < FN; ++j)
                acc[i][j] = __builtin_amdgcn_mfma_f32_16x16x32_bf16(ah[i], bh[j], acc[i][j], 0, 0, 0);
        #pragma unroll
        for (int i = 0; i < FM; ++i)
            #pragma unroll
            for (int j = 0; j < FN; ++j)
                acc[i][j] = __builtin_amdgcn_mfma_f32_16x16x32_bf16(al_[i], bh[j], acc[i][j], 0, 0, 0);
        #pragma unroll
        for (int i = 0; i < FM; ++i)
            #pragma unroll
            for (int j = 0; j < FN; ++j)
                acc[i][j] = __builtin_amdgcn_mfma_f32_16x16x32_bf16(ah[i], bl_[j], acc[i][j], 0, 0, 0);
        __syncthreads();
    }
    if (POOL == 0) {
        #pragma unroll
        for (int i = 0; i < FM; ++i)
            #pragma unroll
            for (int j = 0; j < FN; ++j)
                #pragma unroll
                for (int r = 0; r < 4; ++r) {
                    const int m = bm0 + wm + i * 16 + g * 4 + r;
                    const int n = bn0 + wn + j * 16 + l15;
                    C[(size_t)m * N + n] = acc[i][j][r];
                }
    } else {
        #pragma unroll
        for (int i = 0; i < FM; ++i)
            #pragma unroll
            for (int r = 0; r < 4; ++r) {
                float sum = acc[i][0][r];
                #pragma unroll
                for (int j = 1; j < FN; ++j) sum += acc[i][j][r];
                sum += __shfl_xor(sum, 1);
                sum += __shfl_xor(sum, 2);
                sum += __shfl_xor(sum, 4);
                sum += __shfl_xor(sum, 8);
                if (l15 == 0)
                    unsafeAtomicAdd(pooled + bm0 + wm + i * 16 + g * 4 + r, sum * pscale);
            }
    }
}

// ---------------- generic 64x64 tiled fp32 GEMM: C = epi(A@B) -----------------
// EPI: 1 +bias[n], 2 softplus(+bias[n]). TSTORE: 0 normal; 1 per-batch transposed.
template<int EPI, int TSTORE>
__global__ __launch_bounds__(256) void gemm64(
    const float* __restrict__ A, int lda,
    const float* __restrict__ B,
    const float* __restrict__ bias,
    float* __restrict__ C,
    int M, int N, int K)
{
    __shared__ float As[16][68];
    __shared__ float Bs[16][64];
    const int tid = threadIdx.x;
    const int bm = blockIdx.y * 64;
    const int bn = blockIdx.x * 64;
    const int tx = tid & 15;
    const int ty = tid >> 4;
    const int la_m = tid >> 2;
    const int la_k = (tid & 3) << 2;
    const int lb_k = tid >> 4;
    const int lb_n = (tid & 15) << 2;

    float acc[4][4] = {};
    for (int k0 = 0; k0 < K; k0 += 16) {
        float4 av = *(const float4*)(A + (size_t)(bm + la_m) * lda + k0 + la_k);
        As[la_k + 0][la_m] = av.x;
        As[la_k + 1][la_m] = av.y;
        As[la_k + 2][la_m] = av.z;
        As[la_k + 3][la_m] = av.w;
        const int gn = bn + lb_n;
        const float* bp = B + (size_t)(k0 + lb_k) * N + gn;
        float4 bv = *(const float4*)bp;
        *(float4*)&Bs[lb_k][lb_n] = bv;
        __syncthreads();
        #pragma unroll
        for (int k = 0; k < 16; ++k) {
            float4 a = *(const float4*)&As[k][ty << 2];
            float4 b = *(const float4*)&Bs[k][tx << 2];
            float ar[4] = {a.x, a.y, a.z, a.w};
            float br[4] = {b.x, b.y, b.z, b.w};
            #pragma unroll
            for (int i = 0; i < 4; ++i)
                #pragma unroll
                for (int j = 0; j < 4; ++j)
                    acc[i][j] = fmaf(ar[i], br[j], acc[i][j]);
        }
        __syncthreads();
    }
    if (TSTORE == 0) {
        #pragma unroll
        for (int i = 0; i < 4; ++i) {
            const int gm = bm + (ty << 2) + i;
            #pragma unroll
            for (int j = 0; j < 4; ++j) {
                const int gn = bn + (tx << 2) + j;
                float v = acc[i][j];
                if (EPI == 1) v += bias[gn];
                else if (EPI == 2) v = softplus_f(v + bias[gn]);
                C[(size_t)gm * N + gn] = v;
            }
        }
    } else {
        const int bq = bm >> 9;
        const int tt0 = (bm & (Tt - 1)) + (ty << 2);
        #pragma unroll
        for (int j = 0; j < 4; ++j) {
            const int gn = bn + (tx << 2) + j;
            float4 v;
            float* vv = (float*)&v;
            #pragma unroll
            for (int i = 0; i < 4; ++i) {
                float t = acc[i][j];
                if (EPI == 2) t = softplus_f(t + bias[gn]);
                vv[i] = t;
            }
            *(float4*)(C + ((size_t)bq * N + gn) * Tt + tt0) = v;
        }
    }
}

// --------- split-K GEMM, per-batch-transposed A, atomic accumulate ------------
template<int KS>
__global__ __launch_bounds__(256) void gemm_at_sk(
    const float* __restrict__ A_T,
    const float* __restrict__ B,
    float* __restrict__ C,
    int N, int K)
{
    __shared__ float As[16][68];
    __shared__ float Bs[16][64];
    const int tid = threadIdx.x;
    const int bm = blockIdx.y * 64;
    const int bn = blockIdx.x * 64;
    const int tx = tid & 15;
    const int ty = tid >> 4;
    const int lb_k = tid >> 4;
    const int lb_n = (tid & 15) << 2;
    const int bq = bm >> 9;
    const int tt0 = bm & (Tt - 1);
    const int kseg = K / KS;
    const int kbeg = blockIdx.z * kseg;

    float acc[4][4] = {};
    for (int k0 = kbeg; k0 < kbeg + kseg; k0 += 16) {
        float4 av = *(const float4*)(A_T + ((size_t)bq * K + k0 + lb_k) * Tt + tt0 + lb_n);
        *(float4*)&As[lb_k][lb_n] = av;
        const int gn = bn + lb_n;
        const float* bp = B + (size_t)(k0 + lb_k) * N + gn;
        float4 bv;
        if (gn + 3 < N) {
            bv = *(const float4*)bp;
        } else {
            bv.x = (gn + 0 < N) ? bp[0] : 0.f;
            bv.y = (gn + 1 < N) ? bp[1] : 0.f;
            bv.z = (gn + 2 < N) ? bp[2] : 0.f;
            bv.w = (gn + 3 < N) ? bp[3] : 0.f;
        }
        *(float4*)&Bs[lb_k][lb_n] = bv;
        __syncthreads();
        #pragma unroll
        for (int k = 0; k < 16; ++k) {
            float4 a = *(const float4*)&As[k][ty << 2];
            float4 b = *(const float4*)&Bs[k][tx << 2];
            float ar[4] = {a.x, a.y, a.z, a.w};
            float br[4] = {b.x, b.y, b.z, b.w};
            #pragma unroll
            for (int i = 0; i < 4; ++i)
                #pragma unroll
                for (int j = 0; j < 4; ++j)
                    acc[i][j] = fmaf(ar[i], br[j], acc[i][j]);
        }
        __syncthreads();
    }
    #pragma unroll
    for (int i = 0; i < 4; ++i) {
        const int gm = bm + (ty << 2) + i;
        #pragma unroll
        for (int j = 0; j < 4; ++j) {
            const int gn = bn + (tx << 2) + j;
            if (gn < N)
                unsafeAtomicAdd(&C[(size_t)gm * N + gn], acc[i][j]);
        }
    }
}

// ------- RMSNorm: writes packed hi/lo bf16 xn; adds h0 row-sums to pooled -----
__global__ __launch_bounds__(256) void rms_kernel(
    const float* __restrict__ h0, const float* __restrict__ w,
    uint_t* __restrict__ xn_pk, float* __restrict__ pooled)
{
    const int row = blockIdx.x;
    const float* p = h0 + (size_t)row * DM;
    const int tid = threadIdx.x;
    float v0 = p[tid], v1 = p[tid + 256];
    float ss = v0 * v0 + v1 * v1;
    float sm = v0 + v1;
    #pragma unroll
    for (int m = 32; m; m >>= 1) {
        ss += __shfl_xor(ss, m);
        sm += __shfl_xor(sm, m);
    }
    __shared__ float wss[4], wsm[4];
    if ((tid & 63) == 0) { wss[tid >> 6] = ss; wsm[tid >> 6] = sm; }
    __syncthreads();
    const float tot = wss[0] + wss[1] + wss[2] + wss[3];
    if (tid == 0)
        unsafeAtomicAdd(pooled + row, (wsm[0] + wsm[1] + wsm[2] + wsm[3]) * (1.0f / DM));
    const float scale = rsqrtf(tot * (1.0f / DM) + 1e-5f);
    xn_pk[(size_t)row * DM + tid]       = packf(v0 * scale * w[tid]);
    xn_pk[(size_t)row * DM + tid + 256] = packf(v1 * scale * w[tid + 256]);
}

// -------- causal depthwise conv (DC=4) + SiLU, outputs TRANSPOSED (b,di,t) ----
__global__ __launch_bounds__(256) void conv_tr_kernel(
    const float* __restrict__ xr, const float* __restrict__ cw,
    const float* __restrict__ cb, float* __restrict__ xpT, float* __restrict__ resT)
{
    __shared__ float tp[64][65];
    __shared__ float tr[64][65];
    const int di0 = blockIdx.x * 64;
    const int t0  = blockIdx.y * 64;
    const int b   = blockIdx.z;
    const int c  = threadIdx.x & 63;
    const int r4 = threadIdx.x >> 6;
    const int di = di0 + c;
    const float bias = cb[di];
    float w0 = cw[di * DC + 0], w1 = cw[di * DC + 1],
          w2 = cw[di * DC + 2], w3 = cw[di * DC + 3];
    #pragma unroll
    for (int rr = 0; rr < 64; rr += 4) {
        const int t = t0 + rr + r4;
        const int bt = b * Tt + t;
        float acc = bias;
        if (t >= 3) {
            acc = fmaf(w0, xr[(size_t)(bt - 3) * (2 * DI) + di], acc);
            acc = fmaf(w1, xr[(size_t)(bt - 2) * (2 * DI) + di], acc);
            acc = fmaf(w2, xr[(size_t)(bt - 1) * (2 * DI) + di], acc);
        } else {
            if (t >= 1) acc = fmaf(w2, xr[(size_t)(bt - 1) * (2 * DI) + di], acc);
            if (t >= 2) acc = fmaf(w1, xr[(size_t)(bt - 2) * (2 * DI) + di], acc);
        }
        acc = fmaf(w3, xr[(size_t)bt * (2 * DI) + di], acc);
        tp[rr + r4][c] = silu_fast(acc);
        tr[rr + r4][c] = xr[(size_t)bt * (2 * DI) + DI + di];
    }
    __syncthreads();
    #pragma unroll
    for (int dd = 0; dd < 64; dd += 4) {
        const int dw = dd + r4;
        const size_t o = ((size_t)b * DI + di0 + dw) * Tt + t0 + c;
        xpT[o]  = tp[c][dw];
        resT[o] = tr[c][dw];
    }
}

// ============= fused single-pass selective scan ================================
// One block per (b, 16-di group) = 512 blocks (2/CU). All 8 chunks processed
// sequentially; h carried in registers. Double-buffered LDS staging: global
// loads for chunk c+1 issued before compute of chunk c (reg-staged), LDS
// writes after compute. Two di-chains/lane, DPP butterfly reduce, y packed.
__global__ __launch_bounds__(256) void scan_fused(
    const float* __restrict__ deltaT, const float* __restrict__ xdbl,
    const float* __restrict__ xpT, const float* __restrict__ resT,
    const float* __restrict__ A_log, const float* __restrict__ Dvec,
    uint_t* __restrict__ y_pk)
{
    __shared__ float sBT[2][DS][CL + 1];   // [buf][s][t]
    __shared__ float sCT[2][DS][CL + 1];
    __shared__ float sD[2][16][CL];
    __shared__ float sU[2][16][CL];
    __shared__ float sR[2][16][CL];
    __shared__ float ylds[CL][17];
    const int tid = threadIdx.x;
    const int g = tid >> 5;
    const int l5 = tid & 31;
    const int s = ((l5 & 1) << 4) | (l5 >> 1);   // lane remap: s^16 <-> l^1 (quad DPP)
    const int b = blockIdx.x >> 6;
    const int di0 = (blockIdx.x & 63) << 4;
    const int dl = tid >> 4;             // staging: di lane 0..15
    const int t4 = (tid & 15) << 2;      // staging: t quad
    const int bt_t = tid >> 4;           // B/C staging row base
    const int bt_c = (tid & 15) << 2;

    float4 rd4, ru4, rr4, rBC[4];
    auto stage_regs = [&](int c) {
        const size_t rb = ((size_t)(b * DI + di0 + dl)) * Tt + c * CL + t4;
        rd4 = *(const float4*)(deltaT + rb);
        ru4 = *(const float4*)(xpT + rb);
        rr4 = *(const float4*)(resT + rb);
        const float* src = xdbl + ((size_t)b * Tt + c * CL) * 96 + 32;
        #pragma unroll
        for (int it = 0; it < 4; ++it)
            rBC[it] = *(const float4*)(src + (size_t)(bt_t + it * 16) * 96 + bt_c);
    };
    auto write_lds = [&](int bb) {
        *(float4*)&sD[bb][dl][t4] = rd4;
        *(float4*)&sU[bb][dl][t4] = ru4;
        *(float4*)&sR[bb][dl][t4] = rr4;
        #pragma unroll
        for (int it = 0; it < 4; ++it) {
            const int t = bt_t + it * 16;
            const float vv[4] = {rBC[it].x, rBC[it].y, rBC[it].z, rBC[it].w};
            #pragma unroll
            for (int j = 0; j < 4; ++j) {
                const int cc = bt_c + j;
                if (cc < 32) sBT[bb][cc][t] = vv[j];
                else         sCT[bb][cc - 32][t] = vv[j];
            }
        }
    };

    const bool s4b = (l5 & 1) != 0;    // s bit4
    const bool s0b = (l5 & 2) != 0;    // s bit0
    const bool s1b = (l5 & 4) != 0;    // s bit1
    const bool s2b = (l5 & 8) != 0;    // s bit2
    const bool s3b = (l5 & 16) != 0;   // s bit3
    const int diA = di0 + g, diB = di0 + 8 + g;
    const float Ads2A = -expf(A_log[diA * DS + s]) * 1.44269504f;
    const float Ads2B = -expf(A_log[diB * DS + s]) * 1.44269504f;
    const float DvA = Dvec[diA], DvB = Dvec[diB];
    float hA = 0.f, hB = 0.f;

    stage_regs(0);
    write_lds(0);
    #pragma unroll 1
    for (int c = 0; c < NCH; ++c) {
        const int bb = c & 1;
        __syncthreads();                       // buf[bb] visible; ylds free
        if (c < NCH - 1) stage_regs(c + 1);    // global loads hide under compute
        #pragma unroll 1
        for (int t0 = 0; t0 < CL; t0 += 32) {
            float bufA[16] = {}, bufB[16] = {};
            #pragma unroll
            for (int tq = 0; tq < 8; ++tq) {
                const int tb = t0 + tq * 4;
                const float4 bv4 = *(const float4*)&sBT[bb][s][tb];
                const float4 cv4 = *(const float4*)&sCT[bb][s][tb];
                const float4 dA4 = *(const float4*)&sD[bb][g][tb];
                const float4 uA4 = *(const float4*)&sU[bb][g][tb];
                const float4 dB4 = *(const float4*)&sD[bb][8 + g][tb];
                const float4 uB4 = *(const float4*)&sU[bb][8 + g][tb];
                const float Bvv[4] = {bv4.x, bv4.y, bv4.z, bv4.w};
                const float Cvv[4] = {cv4.x, cv4.y, cv4.z, cv4.w};
                const float dvA[4] = {dA4.x, dA4.y, dA4.z, dA4.w};
                const float uvA[4] = {uA4.x, uA4.y, uA4.z, uA4.w};
                const float dvB[4] = {dB4.x, dB4.y, dB4.z, dB4.w};
                const float uvB[4] = {uB4.x, uB4.y, uB4.z, uB4.w};
                #pragma unroll
                for (int q = 0; q < 4; ++q) {
                    const int tl = tq * 4 + q;
                    hA = fmaf(__builtin_amdgcn_exp2f(dvA[q] * Ads2A), hA, dvA[q] * uvA[q] * Bvv[q]);
                    hB = fmaf(__builtin_amdgcn_exp2f(dvB[q] * Ads2B), hB, dvB[q] * uvB[q] * Bvv[q]);
                    const float psA = hA * Cvv[q];
                    const float psB = hB * Cvv[q];
                    const float prA = psA + qperm<0xB1>(psA);      // s^16 pair-sum, VALU
                    const float prB = psB + qperm<0xB1>(psB);
                    const bool keep = ((tl & 16) != 0) == s4b;
                    bufA[tl & 15] = keep ? prA : bufA[tl & 15];
                    bufB[tl & 15] = keep ? prB : bufB[tl & 15];
                }
            }
            // transposed butterfly; stage order s^1 (quad DPP), s^2, s^4, s^8
            #pragma unroll
            for (int i = 0; i < 16; ++i) bufA[i] += qperm<0x4E>(bufA[i]);
            #pragma unroll
            for (int i = 0; i < 16; ++i) bufB[i] += qperm<0x4E>(bufB[i]);
            float rA[8], rB[8];
            #pragma unroll
            for (int i = 0; i < 8; ++i) {
                rA[i] = s0b ? bufA[2 * i + 1] : bufA[2 * i];
                rB[i] = s0b ? bufB[2 * i + 1] : bufB[2 * i];
            }
            #pragma unroll
            for (int i = 0; i < 8; ++i) { rA[i] += swz<0x101F>(rA[i]); rB[i] += swz<0x101F>(rB[i]); }
            float wA[4], wB[4];
            #pragma unroll
            for (int i = 0; i < 4; ++i) {
                wA[i] = s1b ? rA[2 * i + 1] : rA[2 * i];
                wB[i] = s1b ? rB[2 * i + 1] : rB[2 * i];
            }
            #pragma unroll
            for (int i = 0; i < 4; ++i) { wA[i] += swz<0x201F>(wA[i]); wB[i] += swz<0x201F>(wB[i]); }
            float vA[2], vB[2];
            vA[0] = s2b ? wA[1] : wA[0];
            vA[1] = s2b ? wA[3] : wA[2];
            vB[0] = s2b ? wB[1] : wB[0];
            vB[1] = s2b ? wB[3] : wB[2];
            vA[0] += swz<0x401F>(vA[0]);
            vA[1] += swz<0x401F>(vA[1]);
            vB[0] += swz<0x401F>(vB[0]);
            vB[1] += swz<0x401F>(vB[1]);
            const float yvA = s3b ? vA[1] : vA[0];
            const float yvB = s3b ? vB[1] : vB[0];
            ylds[t0 + s][g]     = fmaf(sU[bb][g][t0 + s], DvA, yvA) * silu_fast(sR[bb][g][t0 + s]);
            ylds[t0 + s][8 + g] = fmaf(sU[bb][8 + g][t0 + s], DvB, yvB) * silu_fast(sR[bb][8 + g][t0 + s]);
        }
        __syncthreads();                       // ylds complete
        {
            const int row = tid >> 2;
            const int q4 = (tid & 3) << 2;
            uint4 o;
            o.x = packf(ylds[row][q4 + 0]);
            o.y = packf(ylds[row][q4 + 1]);
            o.z = packf(ylds[row][q4 + 2]);
            o.w = packf(ylds[row][q4 + 3]);
            *(uint4*)(y_pk + ((size_t)b * Tt + c * CL + row) * DI + di0 + q4) = o;
        }
        if (c < NCH - 1) write_lds(bb ^ 1);    // other buffer; safe post-barrier
    }
}

// ---------------- classifier ---------------------------------------------------
__global__ __launch_bounds__(256) void cls_kernel(
    const float* __restrict__ pooled, const float* __restrict__ w_cls,
    const float* __restrict__ b_cls, float* __restrict__ out)
{
    const int idx = blockIdx.x * 256 + threadIdx.x;
    if (idx >= Bb * NC) return;
    const int b = idx / NC, c = idx % NC;
    float acc = b_cls[c];
    for (int t = 0; t < DM; ++t)
        acc = fmaf(pooled[b * DM + t], w_cls[t * NC + c], acc);
    out[idx] = acc;
}

extern "C" void kernel_launch(void* const* d_in, const int* in_sizes, int n_in,
                              void* d_out, int out_size, void* d_ws, size_t ws_size,
                              hipStream_t stream) {
    const float* x      = (const float*)d_in[0];
    const float* w_proj = (const float*)d_in[1];
    const float* b_proj = (const float*)d_in[2];
    const float* rms_w  = (const float*)d_in[3];
    const float* w_in   = (const float*)d_in[4];
    const float* conv_w = (const float*)d_in[5];
    const float* conv_b = (const float*)d_in[6];
    const float* w_xprj = (const float*)d_in[7];
    const float* w_dt   = (const float*)d_in[8];
    const float* b_dt   = (const float*)d_in[9];
    const float* A_log  = (const float*)d_in[10];
    const float* Dvec   = (const float*)d_in[11];
    const float* w_out  = (const float*)d_in[12];
    const float* w_cls  = (const float*)d_in[13];
    const float* b_cls  = (const float*)d_in[14];
    float* out = (float*)d_out;

    float* ws = (float*)d_ws;
    float* h0     = ws;
    float* xn     = h0 + (size_t)BT * DM;          // holds xn_pk (uint)
    float* xr     = xn + (size_t)BT * DM;
    float* xpT    = xr + (size_t)BT * 2 * DI;
    float* resT   = xpT + (size_t)Bb * DI * Tt;
    float* xdbl   = resT + (size_t)Bb * DI * Tt;
    float* pooled = xdbl + (size_t)BT * 96;
    float* wsplit = pooled + 4096;                 // weight-split区 (was hE/Pp)
    float* deltaT = xr;                            // alias: xr dead after conv_tr
    uint_t* y_pk  = (uint_t*)(xr + (size_t)Bb * DI * Tt);  // upper half of xr
    uint_t* xn_pk = (uint_t*)xn;

    // weight splits (bf16 hi/lo, transposed to [n][k]):
    ushort_t* w_in_hi  = (ushort_t*)wsplit;        // own scratch region
    ushort_t* w_in_lo  = w_in_hi + (size_t)(2 * DI) * DM;
    ushort_t* w_out_hi = (ushort_t*)deltaT;        // written after scan (deltaT dead)
    ushort_t* w_out_lo = w_out_hi + (size_t)DM * DI;

    // 0) zero xdbl (split-K atomics) + pooled (atomic row sums) — contiguous
    zero4_kernel<<<(BT * 96 + 4096) / 1024, 256, 0, stream>>>(
        (float4*)xdbl, (BT * 96 + 4096) / 4);
    // 0b) split+transpose w_in (512,2048) -> [2048][512] bf16 hi/lo
    split_tr_kernel<<<dim3(2 * DI / 32, DM / 32), 256, 0, stream>>>(
        w_in, w_in_hi, w_in_lo, DM, 2 * DI);
    // 1) h0 = x @ w_proj + b_proj
    gemm64<1,0><<<dim3(DM / 64, BT / 64), 256, 0, stream>>>(
        x, NM, w_proj, b_proj, h0, BT, DM, NM);
    // 2) xn_pk = pack(rmsnorm(h0) * rms_w); pooled += rowsum(h0)/DM
    rms_kernel<<<BT, 256, 0, stream>>>(h0, rms_w, xn_pk, pooled);
    // 3) xr = xn @ w_in    (split-bf16 MFMA, packed A)
    gemm_mfma_pk<128,128,0><<<dim3(2 * DI / 128, BT / 128), 256, 0, stream>>>(
        xn_pk, DM, w_in_hi, w_in_lo, xr, nullptr, 0.f, 2 * DI, DM);
    // 4) xpT = silu(causal_dwconv(xr[:, :DI]))^T ; resT = xr[:, DI:]^T
    conv_tr_kernel<<<dim3(DI / 64, Tt / 64, Bb), 256, 0, stream>>>(
        xr, conv_w, conv_b, xpT, resT);
    // 5) xdbl += xp @ w_xproj   (split-K=4, atomic accumulate)
    gemm_at_sk<4><<<dim3(2, BT / 64, 4), 256, 0, stream>>>(
        xpT, w_xprj, xdbl, 96, DI);
    // 6) deltaT = softplus(dt @ w_dt + b_dt)^T
    gemm64<2,1><<<dim3(DI / 64, BT / 64), 256, 0, stream>>>(
        xdbl, 96, w_dt, b_dt, deltaT, BT, DI, DR);
    // 7) fused single-pass selective scan (h in registers across chunks)
    scan_fused<<<Bb * (DI / 16), 256, 0, stream>>>(
        deltaT, xdbl, xpT, resT, A_log, Dvec, y_pk);
    // 7b) split+transpose w_out (1024,512) -> [512][1024] bf16 hi/lo
    split_tr_kernel<<<dim3(DM / 32, DI / 32), 256, 0, stream>>>(
        w_out, w_out_hi, w_out_lo, DI, DM);
    // 8) pooled += rowsum(y @ w_out)/DM   (MFMA + fused mean-pool, no C write)
    gemm_mfma_pk<64,64,1><<<dim3(DM / 64, BT / 64), 256, 0, stream>>>(
        y_pk, DI, w_out_hi, w_out_lo, nullptr, pooled, 1.0f / DM, DM, DI);
    // 9) out = pooled @ w_cls + b_cls
    cls_kernel<<<(Bb * NC + 255) / 256, 256, 0, stream>>>(pooled, w_cls, b_cls, out);
}

// Round 10
// 307.957 us; speedup vs baseline: 1.6778x; 1.0629x over previous
//
#include <hip/hip_runtime.h>
#include <hip/hip_bf16.h>
#include <cstddef>

#define Bb 8
#define Tt 512
#define NM 128
#define DM 512
#define DI 1024
#define DS 32
#define DR 32
#define DC 4
#define NC 100
#define BT (Bb*Tt)     // 4096
#define NCH 8          // scan chunks
#define CL  64         // chunk length

typedef unsigned short ushort_t;
typedef unsigned int uint_t;
typedef __attribute__((ext_vector_type(8))) short bf8;    // 8 bf16 in 4 VGPRs
typedef __attribute__((ext_vector_type(4))) float f4;
typedef __attribute__((ext_vector_type(4))) unsigned short us4;

__device__ __forceinline__ float softplus_f(float x) {
    return fmaxf(x, 0.f) + log1pf(expf(-fabsf(x)));
}
__device__ __forceinline__ float silu_fast(float x) {
    return __fdividef(x, 1.f + __expf(-x));
}
__device__ __forceinline__ ushort_t bf16_rne(float x) {
    uint_t u = __float_as_uint(x);
    uint_t r = u + 0x7FFFu + ((u >> 16) & 1u);
    return (ushort_t)(r >> 16);
}
__device__ __forceinline__ float bf16_tof(ushort_t h) {
    return __uint_as_float(((uint_t)h) << 16);
}
// pack fp32 -> {hi bf16 in [31:16], lo bf16 in [15:0]}
__device__ __forceinline__ uint_t packf(float v) {
    ushort_t h = bf16_rne(v);
    ushort_t l = bf16_rne(v - bf16_tof(h));
    return ((uint_t)h << 16) | (uint_t)l;
}
// cross-lane: quad_perm DPP (VALU pipe) and ds_swizzle (DS pipe)
template<int CTRL>
__device__ __forceinline__ float qperm(float x) {
    return __int_as_float(__builtin_amdgcn_mov_dpp(__float_as_int(x), CTRL, 0xF, 0xF, true));
}
template<int PAT>
__device__ __forceinline__ float swz(float x) {
    return __int_as_float(__builtin_amdgcn_ds_swizzle(__float_as_int(x), PAT));
}

// ---------------- zero-init (xdbl + pooled region) ----------------------------
__global__ __launch_bounds__(256) void zero4_kernel(float4* __restrict__ p, int n4)
{
    const int i = blockIdx.x * 256 + threadIdx.x;
    if (i < n4) p[i] = make_float4(0.f, 0.f, 0.f, 0.f);
}

// ---- split fp32 (K,N) row-major into bf16 hi/lo, TRANSPOSED to (N,K) --------
__global__ __launch_bounds__(256) void split_tr_kernel(
    const float* __restrict__ src, ushort_t* __restrict__ hi,
    ushort_t* __restrict__ lo, int K, int N)
{
    __shared__ ushort_t th[32][34], tl[32][34];
    const int k0 = blockIdx.y * 32, n0 = blockIdx.x * 32;
    #pragma unroll
    for (int it = 0; it < 4; ++it) {
        const int idx = it * 256 + threadIdx.x;
        const int r = idx >> 5, c = idx & 31;
        const float v = src[(size_t)(k0 + r) * N + n0 + c];
        const ushort_t h = bf16_rne(v);
        th[c][r] = h;
        tl[c][r] = bf16_rne(v - bf16_tof(h));
    }
    __syncthreads();
    #pragma unroll
    for (int it = 0; it < 4; ++it) {
        const int idx = it * 256 + threadIdx.x;
        const int r = idx >> 5, c = idx & 31;
        hi[(size_t)(n0 + r) * K + k0 + c] = th[r][c];
        lo[(size_t)(n0 + r) * K + k0 + c] = tl[r][c];
    }
}

// ---- split-bf16 MFMA GEMM, A pre-packed {hi,lo} uint (M,K), B pre-split -----
// POOL=0: C[m*N+n] = acc. POOL=1: no C write; atomicAdd row-sums*pscale into pooled.
template<int BM, int BN, int POOL>
__global__ __launch_bounds__(256) void gemm_mfma_pk(
    const uint_t* __restrict__ Apk, int lda,
    const ushort_t* __restrict__ Bhi, const ushort_t* __restrict__ Blo,
    float* __restrict__ C, float* __restrict__ pooled, float pscale,
    int N, int K)
{
    constexpr int FM = BM / 32, FN = BN / 32;
    constexpr int AIT = BM * 32 / 1024;   // uint4 A loads/thread
    constexpr int BIT = BN * 32 / 2048;   // uint4 loads/thread per B plane
    __shared__ ushort_t sA[2][BM][40];
    __shared__ ushort_t sB[2][BN][40];
    const int tid = threadIdx.x;
    const int wid = tid >> 6, l = tid & 63, l15 = l & 15, g = l >> 4;
    const int wm = (wid >> 1) * (BM / 2), wn = (wid & 1) * (BN / 2);
    const int bm0 = blockIdx.y * BM, bn0 = blockIdx.x * BN;

    f4 acc[FM][FN] = {};
    uint4 aR[AIT], bRh[BIT], bRl[BIT];

    auto loadG = [&](int k0) {
        #pragma unroll
        for (int r = 0; r < AIT; ++r) {
            const int idx = r * 1024 + tid * 4;
            const int m = idx >> 5, k = idx & 31;
            aR[r] = *(const uint4*)(Apk + (size_t)(bm0 + m) * lda + k0 + k);
        }
        #pragma unroll
        for (int r = 0; r < BIT; ++r) {
            const int idx = r * 2048 + tid * 8;
            const int n = idx >> 5, k = idx & 31;
            const size_t o = (size_t)(bn0 + n) * K + k0 + k;
            bRh[r] = *(const uint4*)(Bhi + o);
            bRl[r] = *(const uint4*)(Blo + o);
        }
    };
    auto stoL = [&]() {
        #pragma unroll
        for (int r = 0; r < AIT; ++r) {
            const int idx = r * 1024 + tid * 4;
            const int m = idx >> 5, k = idx & 31;
            const uint_t u0 = aR[r].x, u1 = aR[r].y, u2 = aR[r].z, u3 = aR[r].w;
            uint2 hh, ll;
            hh.x = (u0 >> 16) | (u1 & 0xFFFF0000u);
            hh.y = (u2 >> 16) | (u3 & 0xFFFF0000u);
            ll.x = (u0 & 0xFFFFu) | (u1 << 16);
            ll.y = (u2 & 0xFFFFu) | (u3 << 16);
            *(uint2*)&sA[0][m][k] = hh;
            *(uint2*)&sA[1][m][k] = ll;
        }
        #pragma unroll
        for (int r = 0; r < BIT; ++r) {
            const int idx = r * 2048 + tid * 8;
            const int n = idx >> 5, k = idx & 31;
            *(uint4*)&sB[0][n][k] = bRh[r];
            *(uint4*)&sB[1][n][k] = bRl[r];
        }
    };

    loadG(0);
    for (int k0 = 0; k0 < K; k0 += 32) {
        stoL();
        __syncthreads();
        if (k0 + 32 < K) loadG(k0 + 32);
        bf8 ah[FM], al_[FM], bh[FN], bl_[FN];
        #pragma unroll
        for (int i = 0; i < FM; ++i) {
            ah[i]  = *(bf8*)&sA[0][wm + i * 16 + l15][g * 8];
            al_[i] = *(bf8*)&sA[1][wm + i * 16 + l15][g * 8];
        }
        #pragma unroll
        for (int j = 0; j < FN; ++j) {
            bh[j]  = *(bf8*)&sB[0][wn + j * 16 + l15][g * 8];
            bl_[j] = *(bf8*)&sB[1][wn + j * 16 + l15][g * 8];
        }
        #pragma unroll
        for (int i = 0; i < FM; ++i)
            #pragma unroll
            for (int j = 0; j < FN; ++j)
                acc[i][j] = __builtin_amdgcn_mfma_f32_16x16x32_bf16(ah[i], bh[j], acc[i][j], 0, 0, 0);
        #pragma unroll
        for (int i = 0; i < FM; ++i)
            #pragma unroll
            for (int j = 0; j < FN; ++j)
                acc[i][j] = __builtin_amdgcn_mfma_f32_16x16x32_bf16(al_[i], bh[j], acc[i][j], 0, 0, 0);
        #pragma unroll
        for (int i = 0; i < FM; ++i)
            #pragma unroll
            for (int j = 0; j < FN; ++j)
                acc[i][j] = __builtin_amdgcn_mfma_f32_16x16x32_bf16(ah[i], bl_[j], acc[i][j], 0, 0, 0);
        __syncthreads();
    }
    if (POOL == 0) {
        #pragma unroll
        for (int i = 0; i < FM; ++i)
            #pragma unroll
            for (int j = 0; j < FN; ++j)
                #pragma unroll
                for (int r = 0; r < 4; ++r) {
                    const int m = bm0 + wm + i * 16 + g * 4 + r;
                    const int n = bn0 + wn + j * 16 + l15;
                    C[(size_t)m * N + n] = acc[i][j][r];
                }
    } else {
        #pragma unroll
        for (int i = 0; i < FM; ++i)
            #pragma unroll
            for (int r = 0; r < 4; ++r) {
                float sum = acc[i][0][r];
                #pragma unroll
                for (int j = 1; j < FN; ++j) sum += acc[i][j][r];
                sum += __shfl_xor(sum, 1);
                sum += __shfl_xor(sum, 2);
                sum += __shfl_xor(sum, 4);
                sum += __shfl_xor(sum, 8);
                if (l15 == 0)
                    unsafeAtomicAdd(pooled + bm0 + wm + i * 16 + g * 4 + r, sum * pscale);
            }
    }
}

// ---------------- generic 64x64 tiled fp32 GEMM: C = epi(A@B) -----------------
// EPI: 1 +bias[n], 2 softplus(+bias[n]). TSTORE: 0 normal; 1 per-batch transposed.
template<int EPI, int TSTORE>
__global__ __launch_bounds__(256) void gemm64(
    const float* __restrict__ A, int lda,
    const float* __restrict__ B,
    const float* __restrict__ bias,
    float* __restrict__ C,
    int M, int N, int K)
{
    __shared__ float As[16][68];
    __shared__ float Bs[16][64];
    const int tid = threadIdx.x;
    const int bm = blockIdx.y * 64;
    const int bn = blockIdx.x * 64;
    const int tx = tid & 15;
    const int ty = tid >> 4;
    const int la_m = tid >> 2;
    const int la_k = (tid & 3) << 2;
    const int lb_k = tid >> 4;
    const int lb_n = (tid & 15) << 2;

    float acc[4][4] = {};
    for (int k0 = 0; k0 < K; k0 += 16) {
        float4 av = *(const float4*)(A + (size_t)(bm + la_m) * lda + k0 + la_k);
        As[la_k + 0][la_m] = av.x;
        As[la_k + 1][la_m] = av.y;
        As[la_k + 2][la_m] = av.z;
        As[la_k + 3][la_m] = av.w;
        const int gn = bn + lb_n;
        const float* bp = B + (size_t)(k0 + lb_k) * N + gn;
        float4 bv = *(const float4*)bp;
        *(float4*)&Bs[lb_k][lb_n] = bv;
        __syncthreads();
        #pragma unroll
        for (int k = 0; k < 16; ++k) {
            float4 a = *(const float4*)&As[k][ty << 2];
            float4 b = *(const float4*)&Bs[k][tx << 2];
            float ar[4] = {a.x, a.y, a.z, a.w};
            float br[4] = {b.x, b.y, b.z, b.w};
            #pragma unroll
            for (int i = 0; i < 4; ++i)
                #pragma unroll
                for (int j = 0; j < 4; ++j)
                    acc[i][j] = fmaf(ar[i], br[j], acc[i][j]);
        }
        __syncthreads();
    }
    if (TSTORE == 0) {
        #pragma unroll
        for (int i = 0; i < 4; ++i) {
            const int gm = bm + (ty << 2) + i;
            #pragma unroll
            for (int j = 0; j < 4; ++j) {
                const int gn = bn + (tx << 2) + j;
                float v = acc[i][j];
                if (EPI == 1) v += bias[gn];
                else if (EPI == 2) v = softplus_f(v + bias[gn]);
                C[(size_t)gm * N + gn] = v;
            }
        }
    } else {
        const int bq = bm >> 9;
        const int tt0 = (bm & (Tt - 1)) + (ty << 2);
        #pragma unroll
        for (int j = 0; j < 4; ++j) {
            const int gn = bn + (tx << 2) + j;
            float4 v;
            float* vv = (float*)&v;
            #pragma unroll
            for (int i = 0; i < 4; ++i) {
                float t = acc[i][j];
                if (EPI == 2) t = softplus_f(t + bias[gn]);
                vv[i] = t;
            }
            *(float4*)(C + ((size_t)bq * N + gn) * Tt + tt0) = v;
        }
    }
}

// --------- split-K GEMM, per-batch-transposed A, atomic accumulate ------------
template<int KS>
__global__ __launch_bounds__(256) void gemm_at_sk(
    const float* __restrict__ A_T,
    const float* __restrict__ B,
    float* __restrict__ C,
    int N, int K)
{
    __shared__ float As[16][68];
    __shared__ float Bs[16][64];
    const int tid = threadIdx.x;
    const int bm = blockIdx.y * 64;
    const int bn = blockIdx.x * 64;
    const int tx = tid & 15;
    const int ty = tid >> 4;
    const int lb_k = tid >> 4;
    const int lb_n = (tid & 15) << 2;
    const int bq = bm >> 9;
    const int tt0 = bm & (Tt - 1);
    const int kseg = K / KS;
    const int kbeg = blockIdx.z * kseg;

    float acc[4][4] = {};
    for (int k0 = kbeg; k0 < kbeg + kseg; k0 += 16) {
        float4 av = *(const float4*)(A_T + ((size_t)bq * K + k0 + lb_k) * Tt + tt0 + lb_n);
        *(float4*)&As[lb_k][lb_n] = av;
        const int gn = bn + lb_n;
        const float* bp = B + (size_t)(k0 + lb_k) * N + gn;
        float4 bv;
        if (gn + 3 < N) {
            bv = *(const float4*)bp;
        } else {
            bv.x = (gn + 0 < N) ? bp[0] : 0.f;
            bv.y = (gn + 1 < N) ? bp[1] : 0.f;
            bv.z = (gn + 2 < N) ? bp[2] : 0.f;
            bv.w = (gn + 3 < N) ? bp[3] : 0.f;
        }
        *(float4*)&Bs[lb_k][lb_n] = bv;
        __syncthreads();
        #pragma unroll
        for (int k = 0; k < 16; ++k) {
            float4 a = *(const float4*)&As[k][ty << 2];
            float4 b = *(const float4*)&Bs[k][tx << 2];
            float ar[4] = {a.x, a.y, a.z, a.w};
            float br[4] = {b.x, b.y, b.z, b.w};
            #pragma unroll
            for (int i = 0; i < 4; ++i)
                #pragma unroll
                for (int j = 0; j < 4; ++j)
                    acc[i][j] = fmaf(ar[i], br[j], acc[i][j]);
        }
        __syncthreads();
    }
    #pragma unroll
    for (int i = 0; i < 4; ++i) {
        const int gm = bm + (ty << 2) + i;
        #pragma unroll
        for (int j = 0; j < 4; ++j) {
            const int gn = bn + (tx << 2) + j;
            if (gn < N)
                unsafeAtomicAdd(&C[(size_t)gm * N + gn], acc[i][j]);
        }
    }
}

// ------- RMSNorm: writes packed hi/lo bf16 xn; adds h0 row-sums to pooled -----
__global__ __launch_bounds__(256) void rms_kernel(
    const float* __restrict__ h0, const float* __restrict__ w,
    uint_t* __restrict__ xn_pk, float* __restrict__ pooled)
{
    const int row = blockIdx.x;
    const float* p = h0 + (size_t)row * DM;
    const int tid = threadIdx.x;
    float v0 = p[tid], v1 = p[tid + 256];
    float ss = v0 * v0 + v1 * v1;
    float sm = v0 + v1;
    #pragma unroll
    for (int m = 32; m; m >>= 1) {
        ss += __shfl_xor(ss, m);
        sm += __shfl_xor(sm, m);
    }
    __shared__ float wss[4], wsm[4];
    if ((tid & 63) == 0) { wss[tid >> 6] = ss; wsm[tid >> 6] = sm; }
    __syncthreads();
    const float tot = wss[0] + wss[1] + wss[2] + wss[3];
    if (tid == 0)
        unsafeAtomicAdd(pooled + row, (wsm[0] + wsm[1] + wsm[2] + wsm[3]) * (1.0f / DM));
    const float scale = rsqrtf(tot * (1.0f / DM) + 1e-5f);
    xn_pk[(size_t)row * DM + tid]       = packf(v0 * scale * w[tid]);
    xn_pk[(size_t)row * DM + tid + 256] = packf(v1 * scale * w[tid + 256]);
}

// -------- causal depthwise conv (DC=4) + SiLU, outputs TRANSPOSED (b,di,t) ----
__global__ __launch_bounds__(256) void conv_tr_kernel(
    const float* __restrict__ xr, const float* __restrict__ cw,
    const float* __restrict__ cb, float* __restrict__ xpT, float* __restrict__ resT)
{
    __shared__ float tp[64][65];
    __shared__ float tr[64][65];
    const int di0 = blockIdx.x * 64;
    const int t0  = blockIdx.y * 64;
    const int b   = blockIdx.z;
    const int c  = threadIdx.x & 63;
    const int r4 = threadIdx.x >> 6;
    const int di = di0 + c;
    const float bias = cb[di];
    float w0 = cw[di * DC + 0], w1 = cw[di * DC + 1],
          w2 = cw[di * DC + 2], w3 = cw[di * DC + 3];
    #pragma unroll
    for (int rr = 0; rr < 64; rr += 4) {
        const int t = t0 + rr + r4;
        const int bt = b * Tt + t;
        float acc = bias;
        if (t >= 3) {
            acc = fmaf(w0, xr[(size_t)(bt - 3) * (2 * DI) + di], acc);
            acc = fmaf(w1, xr[(size_t)(bt - 2) * (2 * DI) + di], acc);
            acc = fmaf(w2, xr[(size_t)(bt - 1) * (2 * DI) + di], acc);
        } else {
            if (t >= 1) acc = fmaf(w2, xr[(size_t)(bt - 1) * (2 * DI) + di], acc);
            if (t >= 2) acc = fmaf(w1, xr[(size_t)(bt - 2) * (2 * DI) + di], acc);
        }
        acc = fmaf(w3, xr[(size_t)bt * (2 * DI) + di], acc);
        tp[rr + r4][c] = silu_fast(acc);
        tr[rr + r4][c] = xr[(size_t)bt * (2 * DI) + DI + di];
    }
    __syncthreads();
    #pragma unroll
    for (int dd = 0; dd < 64; dd += 4) {
        const int dw = dd + r4;
        const size_t o = ((size_t)b * DI + di0 + dw) * Tt + t0 + c;
        xpT[o]  = tp[c][dw];
        resT[o] = tr[c][dw];
    }
}

// ============= fused single-pass selective scan (512 thr, 1 chain/lane) =======
// Block = (b, 16-di group), 512 blocks x 8 waves = 16 waves/CU (4/SIMD).
// h carried in registers across all 8 chunks. Double-buffered bf16 LDS staging
// (d stays fp32 to protect exp argument); ds_read_b64 inner loop; DPP butterfly.
__global__ __launch_bounds__(512) void scan_fused(
    const float* __restrict__ deltaT, const float* __restrict__ xdbl,
    const float* __restrict__ xpT, const float* __restrict__ resT,
    const float* __restrict__ A_log, const float* __restrict__ Dvec,
    uint_t* __restrict__ y_pk)
{
    __shared__ ushort_t sBT[2][DS][68];   // [buf][s][t] bf16
    __shared__ ushort_t sCT[2][DS][68];
    __shared__ float    sD [2][16][68];   // fp32 (exponent path)
    __shared__ ushort_t sU [2][16][68];
    __shared__ ushort_t sR [2][16][68];
    __shared__ float ylds[CL][17];
    const int tid = threadIdx.x;
    const int grp = tid >> 5;            // 0..15 : di within block
    const int l5 = tid & 31;
    const int s = ((l5 & 1) << 4) | (l5 >> 1);   // lane remap: s^16 <-> l^1 (quad DPP)
    const int b = blockIdx.x >> 6;
    const int di0 = (blockIdx.x & 63) << 4;
    // staging assignments
    const int sd_r = (tid & 255) >> 4;   // 0..15
    const int sd_t = (tid & 15) << 2;    // 0..60
    const bool lowH = tid < 256;
    const int bc_t = tid >> 3;           // 0..63
    const int bc_c = (tid & 7) << 2;     // 0..28

    float4 rdu4, rr4, rB4, rC4;
    auto stage_regs = [&](int c) {
        const size_t rb = ((size_t)(b * DI + di0 + sd_r)) * Tt + c * CL + sd_t;
        if (lowH) {
            rdu4 = *(const float4*)(deltaT + rb);
        } else {
            rdu4 = *(const float4*)(xpT + rb);
            rr4  = *(const float4*)(resT + rb);
        }
        const float* src = xdbl + ((size_t)b * Tt + c * CL) * 96;
        rB4 = *(const float4*)(src + (size_t)bc_t * 96 + 32 + bc_c);
        rC4 = *(const float4*)(src + (size_t)bc_t * 96 + 64 + bc_c);
    };
    auto write_lds = [&](int bb) {
        if (lowH) {
            *(float4*)&sD[bb][sd_r][sd_t] = rdu4;
        } else {
            us4 uu, rr;
            const float uv[4] = {rdu4.x, rdu4.y, rdu4.z, rdu4.w};
            const float rv[4] = {rr4.x, rr4.y, rr4.z, rr4.w};
            #pragma unroll
            for (int q = 0; q < 4; ++q) { uu[q] = bf16_rne(uv[q]); rr[q] = bf16_rne(rv[q]); }
            *(us4*)&sU[bb][sd_r][sd_t] = uu;
            *(us4*)&sR[bb][sd_r][sd_t] = rr;
        }
        const float bv[4] = {rB4.x, rB4.y, rB4.z, rB4.w};
        const float cv[4] = {rC4.x, rC4.y, rC4.z, rC4.w};
        #pragma unroll
        for (int j = 0; j < 4; ++j) {
            sBT[bb][bc_c + j][bc_t] = bf16_rne(bv[j]);
            sCT[bb][bc_c + j][bc_t] = bf16_rne(cv[j]);
        }
    };

    const bool s4b = (l5 & 1) != 0;    // s bit4
    const bool s0b = (l5 & 2) != 0;    // s bit0
    const bool s1b = (l5 & 4) != 0;    // s bit1
    const bool s2b = (l5 & 8) != 0;    // s bit2
    const bool s3b = (l5 & 16) != 0;   // s bit3
    const int di = di0 + grp;
    const float Ads2 = -expf(A_log[di * DS + s]) * 1.44269504f;
    const float Dv = Dvec[di];
    float h = 0.f;

    stage_regs(0);
    write_lds(0);
    #pragma unroll 1
    for (int c = 0; c < NCH; ++c) {
        const int bb = c & 1;
        __syncthreads();                       // buf[bb] visible; ylds free
        if (c < NCH - 1) stage_regs(c + 1);    // global loads hide under compute
        #pragma unroll 1
        for (int t0 = 0; t0 < CL; t0 += 32) {
            float buf[16] = {};
            #pragma unroll
            for (int tq = 0; tq < 8; ++tq) {
                const int tb = t0 + tq * 4;
                const us4 bv4 = *(const us4*)&sBT[bb][s][tb];
                const us4 cv4 = *(const us4*)&sCT[bb][s][tb];
                const float4 dv4 = *(const float4*)&sD[bb][grp][tb];
                const us4 uv4 = *(const us4*)&sU[bb][grp][tb];
                const float dv[4] = {dv4.x, dv4.y, dv4.z, dv4.w};
                #pragma unroll
                for (int q = 0; q < 4; ++q) {
                    const int tl = tq * 4 + q;
                    const float Bq = bf16_tof(bv4[q]);
                    const float Cq = bf16_tof(cv4[q]);
                    const float uq = bf16_tof(uv4[q]);
                    h = fmaf(__builtin_amdgcn_exp2f(dv[q] * Ads2), h, dv[q] * uq * Bq);
                    const float ps = h * Cq;
                    const float pr = ps + qperm<0xB1>(ps);     // s^16 pair-sum, VALU
                    const bool keep = ((tl & 16) != 0) == s4b;
                    buf[tl & 15] = keep ? pr : buf[tl & 15];
                }
            }
            // transposed butterfly; stage order s^1 (quad DPP), s^2, s^4, s^8
            #pragma unroll
            for (int i = 0; i < 16; ++i) buf[i] += qperm<0x4E>(buf[i]);
            float r8[8];
            #pragma unroll
            for (int i = 0; i < 8; ++i) r8[i] = s0b ? buf[2 * i + 1] : buf[2 * i];
            #pragma unroll
            for (int i = 0; i < 8; ++i) r8[i] += swz<0x101F>(r8[i]);
            float w4[4];
            #pragma unroll
            for (int i = 0; i < 4; ++i) w4[i] = s1b ? r8[2 * i + 1] : r8[2 * i];
            #pragma unroll
            for (int i = 0; i < 4; ++i) w4[i] += swz<0x201F>(w4[i]);
            float v2[2];
            v2[0] = s2b ? w4[1] : w4[0];
            v2[1] = s2b ? w4[3] : w4[2];
            v2[0] += swz<0x401F>(v2[0]);
            v2[1] += swz<0x401F>(v2[1]);
            const float yv = s3b ? v2[1] : v2[0];
            const float uself = bf16_tof(sU[bb][grp][t0 + s]);
            const float rself = bf16_tof(sR[bb][grp][t0 + s]);
            ylds[t0 + s][grp] = fmaf(uself, Dv, yv) * silu_fast(rself);
        }
        __syncthreads();                       // ylds complete
        if (tid < 256) {
            const int row = tid >> 2;
            const int q4 = (tid & 3) << 2;
            uint4 o;
            o.x = packf(ylds[row][q4 + 0]);
            o.y = packf(ylds[row][q4 + 1]);
            o.z = packf(ylds[row][q4 + 2]);
            o.w = packf(ylds[row][q4 + 3]);
            *(uint4*)(y_pk + ((size_t)b * Tt + c * CL + row) * DI + di0 + q4) = o;
        }
        if (c < NCH - 1) write_lds(bb ^ 1);    // other buffer; safe post-barrier
    }
}

// ---------------- classifier ---------------------------------------------------
__global__ __launch_bounds__(256) void cls_kernel(
    const float* __restrict__ pooled, const float* __restrict__ w_cls,
    const float* __restrict__ b_cls, float* __restrict__ out)
{
    const int idx = blockIdx.x * 256 + threadIdx.x;
    if (idx >= Bb * NC) return;
    const int b = idx / NC, c = idx % NC;
    float acc = b_cls[c];
    for (int t = 0; t < DM; ++t)
        acc = fmaf(pooled[b * DM + t], w_cls[t * NC + c], acc);
    out[idx] = acc;
}

extern "C" void kernel_launch(void* const* d_in, const int* in_sizes, int n_in,
                              void* d_out, int out_size, void* d_ws, size_t ws_size,
                              hipStream_t stream) {
    const float* x      = (const float*)d_in[0];
    const float* w_proj = (const float*)d_in[1];
    const float* b_proj = (const float*)d_in[2];
    const float* rms_w  = (const float*)d_in[3];
    const float* w_in   = (const float*)d_in[4];
    const float* conv_w = (const float*)d_in[5];
    const float* conv_b = (const float*)d_in[6];
    const float* w_xprj = (const float*)d_in[7];
    const float* w_dt   = (const float*)d_in[8];
    const float* b_dt   = (const float*)d_in[9];
    const float* A_log  = (const float*)d_in[10];
    const float* Dvec   = (const float*)d_in[11];
    const float* w_out  = (const float*)d_in[12];
    const float* w_cls  = (const float*)d_in[13];
    const float* b_cls  = (const float*)d_in[14];
    float* out = (float*)d_out;

    float* ws = (float*)d_ws;
    float* h0     = ws;
    float* xn     = h0 + (size_t)BT * DM;          // holds xn_pk (uint)
    float* xr     = xn + (size_t)BT * DM;
    float* xpT    = xr + (size_t)BT * 2 * DI;
    float* resT   = xpT + (size_t)Bb * DI * Tt;
    float* xdbl   = resT + (size_t)Bb * DI * Tt;
    float* pooled = xdbl + (size_t)BT * 96;
    float* wsplit = pooled + 4096;                 // weight-split scratch
    float* deltaT = xr;                            // alias: xr dead after conv_tr
    uint_t* y_pk  = (uint_t*)(xr + (size_t)Bb * DI * Tt);  // upper half of xr
    uint_t* xn_pk = (uint_t*)xn;

    // weight splits (bf16 hi/lo, transposed to [n][k]):
    ushort_t* w_in_hi  = (ushort_t*)wsplit;        // own scratch region
    ushort_t* w_in_lo  = w_in_hi + (size_t)(2 * DI) * DM;
    ushort_t* w_out_hi = (ushort_t*)deltaT;        // written after scan (deltaT dead)
    ushort_t* w_out_lo = w_out_hi + (size_t)DM * DI;

    // 0) zero xdbl (split-K atomics) + pooled (atomic row sums) — contiguous
    zero4_kernel<<<(BT * 96 + 4096) / 1024, 256, 0, stream>>>(
        (float4*)xdbl, (BT * 96 + 4096) / 4);
    // 0b) split+transpose w_in (512,2048) -> [2048][512] bf16 hi/lo
    split_tr_kernel<<<dim3(2 * DI / 32, DM / 32), 256, 0, stream>>>(
        w_in, w_in_hi, w_in_lo, DM, 2 * DI);
    // 1) h0 = x @ w_proj + b_proj
    gemm64<1,0><<<dim3(DM / 64, BT / 64), 256, 0, stream>>>(
        x, NM, w_proj, b_proj, h0, BT, DM, NM);
    // 2) xn_pk = pack(rmsnorm(h0) * rms_w); pooled += rowsum(h0)/DM
    rms_kernel<<<BT, 256, 0, stream>>>(h0, rms_w, xn_pk, pooled);
    // 3) xr = xn @ w_in    (split-bf16 MFMA, packed A)
    gemm_mfma_pk<128,128,0><<<dim3(2 * DI / 128, BT / 128), 256, 0, stream>>>(
        xn_pk, DM, w_in_hi, w_in_lo, xr, nullptr, 0.f, 2 * DI, DM);
    // 4) xpT = silu(causal_dwconv(xr[:, :DI]))^T ; resT = xr[:, DI:]^T
    conv_tr_kernel<<<dim3(DI / 64, Tt / 64, Bb), 256, 0, stream>>>(
        xr, conv_w, conv_b, xpT, resT);
    // 5) xdbl += xp @ w_xproj   (split-K=4, atomic accumulate)
    gemm_at_sk<4><<<dim3(2, BT / 64, 4), 256, 0, stream>>>(
        xpT, w_xprj, xdbl, 96, DI);
    // 6) deltaT = softplus(dt @ w_dt + b_dt)^T
    gemm64<2,1><<<dim3(DI / 64, BT / 64), 256, 0, stream>>>(
        xdbl, 96, w_dt, b_dt, deltaT, BT, DI, DR);
    // 7) fused single-pass selective scan (h in registers across chunks)
    scan_fused<<<Bb * (DI / 16), 512, 0, stream>>>(
        deltaT, xdbl, xpT, resT, A_log, Dvec, y_pk);
    // 7b) split+transpose w_out (1024,512) -> [512][1024] bf16 hi/lo
    split_tr_kernel<<<dim3(DM / 32, DI / 32), 256, 0, stream>>>(
        w_out, w_out_hi, w_out_lo, DI, DM);
    // 8) pooled += rowsum(y @ w_out)/DM   (MFMA + fused mean-pool, no C write)
    gemm_mfma_pk<64,64,1><<<dim3(DM / 64, BT / 64), 256, 0, stream>>>(
        y_pk, DI, w_out_hi, w_out_lo, nullptr, pooled, 1.0f / DM, DM, DI);
    // 9) out = pooled @ w_cls + b_cls
    cls_kernel<<<(Bb * NC + 255) / 256, 256, 0, stream>>>(pooled, w_cls, b_cls, out);
}